// Round 10
// baseline (736.717 us; speedup 1.0000x reference)
//
#include <hip/hip_runtime.h>
#include <math.h>

#define HW 1024

typedef __attribute__((ext_vector_type(8))) short bf16x8;
typedef __attribute__((ext_vector_type(4))) float floatx4;

__device__ __forceinline__ unsigned short f2bf(float f) {
    unsigned u = __float_as_uint(f);
    u += 0x7FFF + ((u >> 16) & 1);
    return (unsigned short)(u >> 16);
}
__device__ __forceinline__ float bf2f(unsigned short u) {
    return __uint_as_float(((unsigned)u) << 16);
}
__device__ __forceinline__ float bflo(unsigned u) { return __uint_as_float(u << 16); }
__device__ __forceinline__ float bfhi(unsigned u) { return __uint_as_float(u & 0xffff0000u); }

// ---------------------------------------------------------------------------
// DPP wave-64 reductions (VALU-only). Result lands in lane 63.
// ---------------------------------------------------------------------------
template<int CTRL, int RM>
__device__ __forceinline__ float dpp_sum_step(float v) {
    int t = __builtin_amdgcn_update_dpp(0, __float_as_int(v), CTRL, RM, 0xf, true);
    return v + __int_as_float(t);
}
template<int CTRL, int RM>
__device__ __forceinline__ float dpp_max_step(float v) {
    int t = __builtin_amdgcn_update_dpp(__float_as_int(v), __float_as_int(v), CTRL, RM, 0xf, false);
    return fmaxf(v, __int_as_float(t));
}
__device__ __forceinline__ float wave_sum64(float x) {
    x = dpp_sum_step<0x111, 0xf>(x);
    x = dpp_sum_step<0x112, 0xf>(x);
    x = dpp_sum_step<0x114, 0xf>(x);
    x = dpp_sum_step<0x118, 0xf>(x);
    x = dpp_sum_step<0x142, 0xa>(x);
    x = dpp_sum_step<0x143, 0xc>(x);
    return x;
}
__device__ __forceinline__ float wave_max64(float x) {
    x = dpp_max_step<0x111, 0xf>(x);
    x = dpp_max_step<0x112, 0xf>(x);
    x = dpp_max_step<0x114, 0xf>(x);
    x = dpp_max_step<0x118, 0xf>(x);
    x = dpp_max_step<0x142, 0xa>(x);
    x = dpp_max_step<0x143, 0xc>(x);
    return x;
}
__device__ __forceinline__ float bcast_lane63(float x) {
    return __int_as_float(__builtin_amdgcn_readlane(__float_as_int(x), 63));
}

// ---------------------------------------------------------------------------
// Device-scope grid barrier (sense-reversing, monotonic generation).
// Launch grid is sized from a runtime occupancy query so ALL blocks are
// guaranteed co-resident (grid = min(768, maxBlocksPerCU*256)); grid-stride
// loops make any grid size correct. Only bar[0]==0 is required at entry
// (holds after every complete run), so rocprof replays are safe too.
// ---------------------------------------------------------------------------
__device__ __forceinline__ void gbar(unsigned* bar, unsigned nblk) {
    __syncthreads();
    if (threadIdx.x == 0) {
        __threadfence();
        unsigned g = __hip_atomic_load(bar + 1, __ATOMIC_ACQUIRE, __HIP_MEMORY_SCOPE_AGENT);
        unsigned a = __hip_atomic_fetch_add(bar, 1u, __ATOMIC_ACQ_REL, __HIP_MEMORY_SCOPE_AGENT);
        if (a == nblk - 1u) {
            __hip_atomic_store(bar, 0u, __ATOMIC_RELAXED, __HIP_MEMORY_SCOPE_AGENT);
            __hip_atomic_fetch_add(bar + 1, 1u, __ATOMIC_ACQ_REL, __HIP_MEMORY_SCOPE_AGENT);
        } else {
            while (__hip_atomic_load(bar + 1, __ATOMIC_ACQUIRE, __HIP_MEMORY_SCOPE_AGENT) == g) {
                __builtin_amdgcn_s_sleep(4);
            }
        }
        __threadfence();
    }
    __syncthreads();
}

// ---------------------------------------------------------------------------
// Bilinear sample, zero padding, absolute pixel coords (matches reference).
// ---------------------------------------------------------------------------
__device__ __forceinline__ float bilin32(const float* __restrict__ img, float px, float py) {
    float x0f = floorf(px), y0f = floorf(py);
    float wx = px - x0f, wy = py - y0f;
    bool vx0 = (x0f >= 0.f) && (x0f <= 31.f);
    bool vx1 = (x0f >= -1.f) && (x0f <= 30.f);
    bool vy0 = (y0f >= 0.f) && (y0f <= 31.f);
    bool vy1 = (y0f >= -1.f) && (y0f <= 30.f);
    int ix0 = (int)fminf(fmaxf(x0f, 0.f), 31.f);
    int iy0 = (int)fminf(fmaxf(y0f, 0.f), 31.f);
    int ix1 = (int)fminf(fmaxf(x0f + 1.f, 0.f), 31.f);
    int iy1 = (int)fminf(fmaxf(y0f + 1.f, 0.f), 31.f);
    float w00 = (1.f - wx) * (1.f - wy) * ((vx0 && vy0) ? 1.f : 0.f);
    float w01 = wx * (1.f - wy) * ((vx1 && vy0) ? 1.f : 0.f);
    float w10 = (1.f - wx) * wy * ((vx0 && vy1) ? 1.f : 0.f);
    float w11 = wx * wy * ((vx1 && vy1) ? 1.f : 0.f);
    return w00 * img[iy0 * 32 + ix0] + w01 * img[iy0 * 32 + ix1] +
           w10 * img[iy1 * 32 + ix0] + w11 * img[iy1 * 32 + ix1];
}

__device__ __forceinline__ float2 comp_flow(const float* __restrict__ fa,
                                            const float* __restrict__ fb, int pix) {
    int y = pix >> 5, x = pix & 31;
    float fx = fa[pix], fy = fa[HW + pix];
    float px = (float)x + fx, py = (float)y + fy;
    float2 r;
    r.x = fx + bilin32(fb, px, py);
    r.y = fy + bilin32(fb + HW, px, py);
    return r;
}

// ---------------------------------------------------------------------------
// Prep kernel: sections by blockIdx.x (grid 2336). Also zeroes the grid
// barrier cells used by mega_k (b==672, tid==0).
// ---------------------------------------------------------------------------
struct WD { const float* src; int cout, Cin, nCb, wbase, beg; };
struct PrepP {
    const float *x, *f1, *f2, *ff1, *ff2;
    float *fcn2, *fn2c;
    unsigned short *x_pad, *extra_pad, *wgt;
    unsigned* bar;
    WD wd[12];
};

__global__ __launch_bounds__(256) void prep_k(PrepP P) {
    __shared__ float wlds[16 * 288];
    const int b = blockIdx.x, tid = threadIdx.x;
    if (b < 192) {
        int idx = b * 256 + tid;                 // < 1024*48
        int pix = idx / 48, c4 = idx - pix * 48;
        int y = pix >> 5, xx = pix & 31;
        int c0 = c4 * 4;
        ushort4 s;
        s.x = f2bf(P.x[(size_t)(c0 + 0) * HW + pix]);
        s.y = f2bf(P.x[(size_t)(c0 + 1) * HW + pix]);
        s.z = f2bf(P.x[(size_t)(c0 + 2) * HW + pix]);
        s.w = f2bf(P.x[(size_t)(c0 + 3) * HW + pix]);
        *(ushort4*)(&P.x_pad[(size_t)((y + 1) * 34 + xx + 1) * 192 + c0]) = s;
    } else if (b < 672) {
        int idx = (b - 192) * 256 + tid;         // < 1024*120
        int pix = idx / 120, c4 = idx - pix * 120;
        int y = pix >> 5, xx = pix & 31;
        int c0 = c4 * 4;
        float va[4];
        if (c0 < 64) {
#pragma unroll
            for (int k = 0; k < 4; ++k) va[k] = P.x[(size_t)(c0 + k) * HW + pix];
        } else if (c0 < 448) {
            int grp = (c0 - 64) >> 6;
            int c = (c0 - 64) & 63;
            const float* src; float fx, fy;
            if (grp == 0)      { src = P.x + 64 * HW;  fx = P.f1[pix];  fy = P.f1[HW + pix]; }
            else if (grp == 1) { src = P.x + 128 * HW; float2 r = comp_flow(P.f1, P.f2, pix);  fx = r.x; fy = r.y; }
            else if (grp == 2) { src = P.x;            fx = P.ff1[pix]; fy = P.ff1[HW + pix]; }
            else if (grp == 3) { src = P.x + 128 * HW; fx = P.f2[pix];  fy = P.f2[HW + pix]; }
            else if (grp == 4) { src = P.x + 64 * HW;  fx = P.ff2[pix]; fy = P.ff2[HW + pix]; }
            else               { src = P.x;            float2 r = comp_flow(P.ff2, P.ff1, pix); fx = r.x; fy = r.y; }
            float px = (float)xx + fx, py = (float)y + fy;
            float x0f = floorf(px), y0f = floorf(py);
            float wx = px - x0f, wy = py - y0f;
            bool vx0 = (x0f >= 0.f) && (x0f <= 31.f);
            bool vx1 = (x0f >= -1.f) && (x0f <= 30.f);
            bool vy0 = (y0f >= 0.f) && (y0f <= 31.f);
            bool vy1 = (y0f >= -1.f) && (y0f <= 30.f);
            int ix0 = (int)fminf(fmaxf(x0f, 0.f), 31.f);
            int iy0 = (int)fminf(fmaxf(y0f, 0.f), 31.f);
            int ix1 = (int)fminf(fmaxf(x0f + 1.f, 0.f), 31.f);
            int iy1 = (int)fminf(fmaxf(y0f + 1.f, 0.f), 31.f);
            float w00 = (1.f - wx) * (1.f - wy) * ((vx0 && vy0) ? 1.f : 0.f);
            float w01 = wx * (1.f - wy) * ((vx1 && vy0) ? 1.f : 0.f);
            float w10 = (1.f - wx) * wy * ((vx0 && vy1) ? 1.f : 0.f);
            float w11 = wx * wy * ((vx1 && vy1) ? 1.f : 0.f);
            int p00 = iy0 * 32 + ix0, p01 = iy0 * 32 + ix1;
            int p10 = iy1 * 32 + ix0, p11 = iy1 * 32 + ix1;
            const float* im = src + (size_t)c * HW;
#pragma unroll
            for (int k = 0; k < 4; ++k) {
                va[k] = w00 * im[p00] + w01 * im[p01] + w10 * im[p10] + w11 * im[p11];
                im += HW;
            }
        } else {
#pragma unroll
            for (int k = 0; k < 4; ++k) {
                int ch = c0 + k;
                float v = 0.f;
                if (ch < 460) {
                    int fc = ch - 448;
                    int which = fc >> 1, comp = fc & 1;
                    if (which == 0)      v = P.f1[comp * HW + pix];
                    else if (which == 1) { float2 r = comp_flow(P.f1, P.f2, pix);  v = comp ? r.y : r.x; }
                    else if (which == 2) v = P.ff1[comp * HW + pix];
                    else if (which == 3) v = P.f2[comp * HW + pix];
                    else if (which == 4) v = P.ff2[comp * HW + pix];
                    else                 { float2 r = comp_flow(P.ff2, P.ff1, pix); v = comp ? r.y : r.x; }
                }
                va[k] = v;
            }
        }
        ushort4 s;
        s.x = f2bf(va[0]); s.y = f2bf(va[1]); s.z = f2bf(va[2]); s.w = f2bf(va[3]);
        *(ushort4*)(&P.extra_pad[(size_t)((y + 1) * 34 + xx + 1) * 480 + c0]) = s;
    } else if (b < 688) {
        int idx = (b - 672) * 256 + tid;
        if (b == 672 && tid == 0) { P.bar[0] = 0u; P.bar[1] = 0u; }
        if (idx < 1024) {
            float2 r = comp_flow(P.f1, P.f2, idx);
            P.fcn2[idx] = r.x; P.fcn2[HW + idx] = r.y;
        } else if (idx < 2048) {
            int pix = idx - 1024;
            float2 r = comp_flow(P.ff2, P.ff1, pix);
            P.fn2c[pix] = r.x; P.fn2c[HW + pix] = r.y;
        }
    } else if (b < 704) {
        const int chans[9] = {192, 192, 480, 64, 64, 64, 64, 192, 192};
        size_t offs[9]; size_t a = 0;
        for (int i = 0; i < 9; ++i) { offs[i] = a; a += (size_t)1156 * chans[i]; }
        int bb = b - 688;
        for (int item = bb; item < 9 * 132; item += 16) {
            int buf = item / 132, i = item - buf * 132;
            int py, px;
            if (i < 34) { py = 0; px = i; }
            else if (i < 68) { py = 33; px = i - 34; }
            else { int j = i - 68; py = 1 + (j >> 1); px = (j & 1) ? 33 : 0; }
            int C = chans[buf];
            unsigned short* p = P.x_pad + offs[buf] + (size_t)(py * 34 + px) * C;
            for (int c = tid; c < C; c += 256) p[c] = 0;
        }
    } else {
        int blk = b - 704;                       // < 1632
        int di = 0;
        while (di < 11 && blk >= P.wd[di + 1].beg) ++di;
        WD w = P.wd[di];
        int local = blk - w.beg;
        int co16 = local / w.nCb, cb = local - co16 * w.nCb;
        int cr0 = co16 * 16, ci0 = cb * 32;
        for (int i = tid; i < 16 * 288; i += 256) {
            int cr = i / 288, o = i - cr * 288;
            int crg = cr0 + cr, ci = ci0 + o / 9;
            float v = (crg < w.cout && ci < w.Cin)
                ? w.src[((size_t)crg * w.Cin + ci0) * 9 + o] : 0.f;
            wlds[i] = v;
        }
        __syncthreads();
        for (int e = tid; e < 9 * 512; e += 256) {
            int t = e >> 9, idx = e & 511;
            int j = idx & 7, lane = idx >> 3, q = lane >> 4, mm = lane & 15;
            P.wgt[((size_t)w.wbase + ((size_t)co16 * 9 + t) * w.nCb + cb) * 512 + idx] =
                f2bf(wlds[mm * 288 + (q * 8 + j) * 9 + t]);
        }
    }
}

// ---------------------------------------------------------------------------
// Conv phase structs (multi-descriptor) — shared by the mega kernel phases.
// ---------------------------------------------------------------------------
struct CDesc {
    const unsigned short* in;
    const unsigned short* wgt;
    const float* bias;
    void* out;
    const float* residual;
    int Cpad, nCb, Cout, mode, cmod, relu, Mblocks;
};
struct CParam { CDesc d[4]; };
struct L4Desc {
    const unsigned short* in;
    const unsigned short* wgt;
    const float* bias;
    void* out;
    int mode, cmod, Mblocks;
};
struct L4Param { L4Desc d[2]; };

// conv phase, PIXROWS=4 COBLK=16. item = by*NX + bx. blds 8160, wlds 4608 shorts.
__device__ void conv_phase(const CParam& P, int item, int NX, int tid,
                           unsigned short* blds, unsigned short* wlds) {
    constexpr int TROWS = 6, TC = TROWS * 34 * 4, ITRIPS = 4;
    constexpr int NTY = 1, NACC = 2, MT = 1, WN = 576, WTRIPS = 3;

    int bx = item % NX;
    const int by = item / NX;
    int di = 0;
    while (bx >= P.d[di].Mblocks) { bx -= P.d[di].Mblocks; ++di; }
    const CDesc d = P.d[di];

    const int w = tid >> 6, lane = tid & 63;
    const int lq = lane >> 4, ln = lane & 15;
    const int co0 = bx * 16;
    const int y0 = by * 4;
    const unsigned short* __restrict__ in = d.in;
    const unsigned short* __restrict__ wg = d.wgt;
    const int Cpad = d.Cpad, nCb = d.nCb;

    floatx4 acc[MT][NACC];
#pragma unroll
    for (int mt = 0; mt < MT; ++mt)
#pragma unroll
        for (int nt = 0; nt < NACC; ++nt)
            acc[mt][nt] = (floatx4){0.f, 0.f, 0.f, 0.f};

    bf16x8 ireg[ITRIPS];
    bf16x8 wreg[WTRIPS];

    auto load_regs = [&](int cb) {
        const int ci0 = cb << 5;
#pragma unroll
        for (int k = 0; k < ITRIPS; ++k) {
            int i = tid + k * 256;
            if (i < TC) {
                int r = i / 136, rem = i - r * 136, c = rem >> 2, g = rem & 3;
                ireg[k] = *(const bf16x8*)(in + (size_t)((y0 + r) * 34 + c) * Cpad + ci0 + g * 8);
            }
        }
#pragma unroll
        for (int k = 0; k < WTRIPS; ++k) {
            int i = tid + k * 256;
            if (i < WN) {
                int chunk = i >> 6, l16 = i & 63;
                int mt = chunk / 9, t = chunk - mt * 9;
                wreg[k] = *(const bf16x8*)(wg + ((size_t)(((co0 >> 4) + mt) * 9 + t) * nCb + cb) * 512 + l16 * 8);
            }
        }
    };

    load_regs(0);

    for (int cb = 0; cb < nCb; ++cb) {
        __syncthreads();
#pragma unroll
        for (int k = 0; k < ITRIPS; ++k) {
            int i = tid + k * 256;
            if (i < TC) {
                int r = i / 136, rem = i - r * 136, c = rem >> 2, g = rem & 3;
                *(bf16x8*)(&blds[(r * 34 + c) * 40 + g * 8]) = ireg[k];
            }
        }
#pragma unroll
        for (int k = 0; k < WTRIPS; ++k) {
            int i = tid + k * 256;
            if (i < WN) {
                int chunk = i >> 6, l16 = i & 63;
                *(bf16x8*)(&wlds[chunk * 512 + l16 * 8]) = wreg[k];
            }
        }
        __syncthreads();
        if (cb + 1 < nCb) load_regs(cb + 1);
        for (int t = 0; t < 9; ++t) {
            const int dy = t / 3, dx = t - dy * 3;
            bf16x8 bfr[NACC];
#pragma unroll
            for (int ty = 0; ty < NTY; ++ty)
#pragma unroll
                for (int tx = 0; tx < 2; ++tx) {
                    int yy = w * NTY + ty + dy;
                    int xx = tx * 16 + ln + dx;
                    bfr[ty * 2 + tx] = *(const bf16x8*)(&blds[(yy * 34 + xx) * 40 + lq * 8]);
                }
#pragma unroll
            for (int mt = 0; mt < MT; ++mt) {
                bf16x8 afr = *(const bf16x8*)(&wlds[(mt * 9 + t) * 512 + lane * 8]);
#pragma unroll
                for (int nt = 0; nt < NACC; ++nt)
                    acc[mt][nt] = __builtin_amdgcn_mfma_f32_16x16x32_bf16(afr, bfr[nt], acc[mt][nt], 0, 0, 0);
            }
        }
    }

#pragma unroll
    for (int mt = 0; mt < MT; ++mt) {
        const int co = co0 + mt * 16 + lq * 4;
        if (co >= d.Cout) continue;
        float bv[4];
#pragma unroll
        for (int r = 0; r < 4; ++r) bv[r] = d.bias[co + r];
#pragma unroll
        for (int nt = 0; nt < NACC; ++nt) {
            const int ty = nt >> 1, tx = nt & 1;
            const int pix = by * 128 + (w * NTY + ty) * 32 + tx * 16 + ln;
            float v[4];
#pragma unroll
            for (int r = 0; r < 4; ++r) {
                float vv = acc[mt][nt][r] + bv[r];
                if (d.relu) vv = (vv >= 0.f) ? vv : 0.1f * vv;
                v[r] = vv;
            }
            if (d.mode == 0) {
                float* o = (float*)d.out;
#pragma unroll
                for (int r = 0; r < 4; ++r) {
                    float vv = v[r];
                    if (d.residual) vv += d.residual[(size_t)(co + r) * HW + pix];
                    o[(size_t)(co + r) * HW + pix] = vv;
                }
            } else if (d.mode == 1) {
                int fq = co / d.cmod, cc = co - fq * d.cmod;
                *(float4*)((float*)d.out + ((size_t)fq * HW + pix) * d.cmod + cc) =
                    make_float4(v[0], v[1], v[2], v[3]);
            } else if (d.mode == 2) {
                int fq = co / d.cmod, cc = co - fq * d.cmod;
                ushort4 s4;
                s4.x = f2bf(v[0]); s4.y = f2bf(v[1]); s4.z = f2bf(v[2]); s4.w = f2bf(v[3]);
                *(ushort4*)((unsigned short*)d.out + ((size_t)fq * HW + pix) * d.cmod + cc) = s4;
            } else {
                int yy = (pix >> 5) + 1, xx = (pix & 31) + 1;
                ushort4 s4;
                s4.x = f2bf(v[0]); s4.y = f2bf(v[1]); s4.z = f2bf(v[2]); s4.w = f2bf(v[3]);
                *(ushort4*)((unsigned short*)d.out + (size_t)(yy * 34 + xx) * d.cmod + co) = s4;
            }
        }
    }
}

// L4 phase (read-once weights). blds 13600, wlds 9216 shorts.
// Leading __syncthreads: in the grid-stride loop the previous item's waves
// may still be reading wlds when this item starts writing it.
__device__ void l4_phase(const L4Param& P, int item, int tid,
                         unsigned short* blds, unsigned short* wlds) {
    __syncthreads();
    int bx = item;
    int di = 0;
    if (bx >= P.d[0].Mblocks) { bx -= P.d[0].Mblocks; di = 1; }
    const L4Desc d = P.d[di];

    const int w = tid >> 6, lane = tid & 63;
    const int lq = lane >> 4, ln = lane & 15;
    const int co0 = bx * 16;
    const unsigned short* __restrict__ in = d.in;
    const unsigned short* __restrict__ wg = d.wgt;

    bf16x8 wreg[5];
#pragma unroll
    for (int k = 0; k < 5; ++k) {
        int i = tid + k * 256;
        if (i < 1152) {
            int chunk = i >> 6, l16 = i & 63;
            int t = chunk >> 1, cb = chunk & 1;
            wreg[k] = *(const bf16x8*)(wg + (((size_t)bx * 9 + t) * 2 + cb) * 512 + l16 * 8);
        }
    }

    bf16x8 ireg[6];
    auto load_in = [&](int y0, int cb) {
        const int ci0 = cb << 5;
#pragma unroll
        for (int k = 0; k < 6; ++k) {
            int i = tid + k * 256;
            if (i < 1360) {
                int r = i / 136, rem = i - r * 136, c = rem >> 2, g = rem & 3;
                ireg[k] = *(const bf16x8*)(in + (size_t)((y0 + r) * 34 + c) * 64 + ci0 + g * 8);
            }
        }
    };
    load_in(0, 0);

#pragma unroll
    for (int k = 0; k < 5; ++k) {
        int i = tid + k * 256;
        if (i < 1152) *(bf16x8*)(&wlds[(i >> 6) * 512 + (i & 63) * 8]) = wreg[k];
    }

    floatx4 acc[4];
#pragma unroll
    for (int nt = 0; nt < 4; ++nt) acc[nt] = (floatx4){0.f, 0.f, 0.f, 0.f};

    for (int p = 0; p < 8; ++p) {
        const int y = p >> 1, cb = p & 1;
        __syncthreads();
#pragma unroll
        for (int k = 0; k < 6; ++k) {
            int i = tid + k * 256;
            if (i < 1360) {
                int r = i / 136, rem = i - r * 136, c = rem >> 2, g = rem & 3;
                *(bf16x8*)(&blds[(r * 34 + c) * 40 + g * 8]) = ireg[k];
            }
        }
        __syncthreads();
        if (p < 7) { int pn = p + 1; load_in((pn >> 1) * 8, pn & 1); }
#pragma unroll
        for (int t = 0; t < 9; ++t) {
            const int dy = t / 3, dx = t - dy * 3;
            bf16x8 afr = *(const bf16x8*)(&wlds[(t * 2 + cb) * 512 + lane * 8]);
#pragma unroll
            for (int ty = 0; ty < 2; ++ty)
#pragma unroll
                for (int tx = 0; tx < 2; ++tx) {
                    int yy = w * 2 + ty + dy;
                    int xx = tx * 16 + ln + dx;
                    bf16x8 bfr = *(const bf16x8*)(&blds[(yy * 34 + xx) * 40 + lq * 8]);
                    acc[ty * 2 + tx] =
                        __builtin_amdgcn_mfma_f32_16x16x32_bf16(afr, bfr, acc[ty * 2 + tx], 0, 0, 0);
                }
        }
        if (cb == 1) {
            const int co = co0 + lq * 4;
            float bv[4];
#pragma unroll
            for (int r2 = 0; r2 < 4; ++r2) bv[r2] = d.bias[co + r2];
            int fq = co / d.cmod, cc = co - fq * d.cmod;
#pragma unroll
            for (int nt = 0; nt < 4; ++nt) {
                const int ty = nt >> 1, tx = nt & 1;
                const int pix = y * 256 + (w * 2 + ty) * 32 + tx * 16 + ln;
                float v0 = acc[nt][0] + bv[0], v1 = acc[nt][1] + bv[1];
                float v2 = acc[nt][2] + bv[2], v3 = acc[nt][3] + bv[3];
                if (d.mode == 1) {
                    *(float4*)((float*)d.out + ((size_t)fq * HW + pix) * d.cmod + cc) =
                        make_float4(v0, v1, v2, v3);
                } else {
                    ushort4 s4;
                    s4.x = f2bf(v0); s4.y = f2bf(v1); s4.z = f2bf(v2); s4.w = f2bf(v3);
                    *(ushort4*)((unsigned short*)d.out + ((size_t)fq * HW + pix) * d.cmod + cc) = s4;
                }
                acc[nt] = (floatx4){0.f, 0.f, 0.f, 0.f};
            }
        }
    }
}

// ---------------------------------------------------------------------------
// Mega kernel: L1 -> L2 -> L3 -> L4 -> deform -> op0 -> op1, separated by
// device-scope grid barriers. Grid sized by occupancy query at launch.
// ---------------------------------------------------------------------------
struct MegaP {
    CParam l1, l2, l3, opa, opb;
    L4Param l4;
    const unsigned short* value_b;
    const float* so_t;
    const unsigned short* aw_t;
    const float *f1, *f2, *ff1, *ff2, *fcn2, *fn2c;
    unsigned short* attn_pad;
    unsigned* bar;
};

__device__ void deform_phase(const MegaP& M, int item, int tid,
                             unsigned short (*pwlds)[432]) {
    const int wav = tid >> 6, lane = tid & 63;
    const int m = item & 7, qc = item >> 3;

    const int pp = lane & 15, gq = lane >> 4;
    const int gdy = (gq >> 1) * 2 - 1;
    const int gdx = (gq & 1) * 2 - 1;
    const bool selx = (gq & 1);
    const bool sely = (gq >> 1);

    const unsigned short* __restrict__ vm = M.value_b + (size_t)m * 8192;

    for (int r = 0; r < 8; ++r) {
        const int q = qc * 32 + r * 4 + wav;
        const int f = q >> 10, pix = q & 1023;
        const int y = pix >> 5, x = pix & 31;

        float av[6];
        {
            const unsigned short* awp = M.aw_t + (size_t)q * 2592 + m * 324;
#pragma unroll
            for (int it = 0; it < 6; ++it) {
                int j = lane + it * 64;
                av[it] = (j < 324) ? bf2f(awp[j]) : -1e30f;
            }
        }

        float vmax = -1e30f;
#pragma unroll
        for (int it = 0; it < 6; ++it) vmax = fmaxf(vmax, av[it]);
        vmax = bcast_lane63(wave_max64(vmax));
        float ssum = 0.f;
#pragma unroll
        for (int it = 0; it < 6; ++it) {
            int j = lane + it * 64;
            float e = (j < 324) ? __expf(av[it] - vmax) : 0.f;
            av[it] = e;
            ssum += e;
        }
        ssum = bcast_lane63(wave_sum64(ssum));
        const float inv = 1.f / ssum;

#pragma unroll
        for (int it = 0; it < 6; ++it) {
            int j = lane + it * 64;
            if (j < 324) {
                int pi = j / 9, k = j - pi * 9;
                pwlds[wav][pi * 12 + k] = f2bf(av[it] * inv);
            }
        }

        const float* sop = M.so_t + (size_t)q * 576 + m * 72;
        float2 so2r[3];
#pragma unroll
        for (int pt = 0; pt < 3; ++pt) {
            int pi = pt * 16 + pp;
            if (pi < 36) so2r[pt] = *(const float2*)(sop + pi * 2);
            else { so2r[pt].x = 0.f; so2r[pt].y = 0.f; }
        }

        float flx0 = 0.f, fly0 = 0.f, flx1 = 0.f, fly1 = 0.f, flx2 = 0.f, fly2 = 0.f;
        if (f == 0) {
            flx1 = M.f1[pix];   fly1 = M.f1[HW + pix];
            flx2 = M.fcn2[pix]; fly2 = M.fcn2[HW + pix];
        } else if (f == 1) {
            flx0 = M.ff1[pix];  fly0 = M.ff1[HW + pix];
            flx2 = M.f2[pix];   fly2 = M.f2[HW + pix];
        } else {
            flx0 = M.fn2c[pix]; fly0 = M.fn2c[HW + pix];
            flx1 = M.ff2[pix];  fly1 = M.ff2[HW + pix];
        }

        float acc[8];
#pragma unroll
        for (int dd = 0; dd < 8; ++dd) acc[dd] = 0.f;

#pragma unroll
        for (int pt = 0; pt < 3; ++pt) {
            int pi = pt * 16 + pp;
            if (pi < 36) {
                int l = pi / 12;
                float2 so2 = so2r[pt];
                float fx = (l == 0) ? flx0 : (l == 1) ? flx1 : flx2;
                float fy = (l == 0) ? fly0 : (l == 1) ? fly1 : fly2;
                float bxf = (float)x + so2.x + fx;
                float byf = (float)y + so2.y + fy;
                float x0f = floorf(bxf), y0f = floorf(byf);
                float wx = bxf - x0f, wy = byf - y0f;
                float ax = 1.f - wx, ay = 1.f - wy;
                int x0 = (int)fminf(fmaxf(x0f, -2.f), 34.f);
                int y0 = (int)fminf(fmaxf(y0f, -2.f), 34.f);

                const unsigned short* pr = &pwlds[wav][pi * 12];
                uint2 pv0 = *(const uint2*)(pr);
                uint2 pv1 = *(const uint2*)(pr + 4);
                float a0 = bflo(pv0.x), a1 = bfhi(pv0.x), a2 = bflo(pv0.y);
                float a3 = bfhi(pv0.y), a4 = bflo(pv1.x), a5 = bfhi(pv1.x);
                float a6 = bflo(pv1.y), a7 = bfhi(pv1.y), a8 = bf2f(pr[8]);

                float bs0a, bs0b, bs1a, bs1b, bs2a, bs2b;
                {
                    float b0, b1, b2, b3;
                    b0 = a0 * ax; b1 = a0 * wx + a3 * ax; b2 = a3 * wx + a6 * ax; b3 = a6 * wx;
                    bs0a = selx ? b2 : b0; bs0b = selx ? b3 : b1;
                    b0 = a1 * ax; b1 = a1 * wx + a4 * ax; b2 = a4 * wx + a7 * ax; b3 = a7 * wx;
                    bs1a = selx ? b2 : b0; bs1b = selx ? b3 : b1;
                    b0 = a2 * ax; b1 = a2 * wx + a5 * ax; b2 = a5 * wx + a8 * ax; b3 = a8 * wx;
                    bs2a = selx ? b2 : b0; bs2b = selx ? b3 : b1;
                }
                float c00, c01, c10, c11;
                {
                    float c0 = bs0a * ay, c1 = bs0a * wy + bs1a * ay;
                    float c2 = bs1a * wy + bs2a * ay, c3 = bs2a * wy;
                    c00 = sely ? c2 : c0; c10 = sely ? c3 : c1;
                    c0 = bs0b * ay; c1 = bs0b * wy + bs1b * ay;
                    c2 = bs1b * wy + bs2b * ay; c3 = bs2b * wy;
                    c01 = sely ? c2 : c0; c11 = sely ? c3 : c1;
                }
                float cg[2][2] = {{c00, c01}, {c10, c11}};
                const unsigned short* __restrict__ vl = vm + (size_t)l * 65536;
#pragma unroll
                for (int sy = 0; sy < 2; ++sy) {
#pragma unroll
                    for (int sx = 0; sx < 2; ++sx) {
                        int dy = gdy + sy, dx = gdx + sx;
                        float pyf = y0f + (float)dy, pxf = x0f + (float)dx;
                        bool v = (pxf >= 0.f) && (pxf <= 31.f) && (pyf >= 0.f) && (pyf <= 31.f);
                        int px = min(max(x0 + dx, 0), 31);
                        int py = min(max(y0 + dy, 0), 31);
                        float c = cg[sy][sx] * (v ? 1.f : 0.f);
                        uint4 vv = *(const uint4*)(vl + (size_t)(py * 32 + px) * 8);
                        acc[0] = fmaf(c, bflo(vv.x), acc[0]);
                        acc[1] = fmaf(c, bfhi(vv.x), acc[1]);
                        acc[2] = fmaf(c, bflo(vv.y), acc[2]);
                        acc[3] = fmaf(c, bfhi(vv.y), acc[3]);
                        acc[4] = fmaf(c, bflo(vv.z), acc[4]);
                        acc[5] = fmaf(c, bfhi(vv.z), acc[5]);
                        acc[6] = fmaf(c, bflo(vv.w), acc[6]);
                        acc[7] = fmaf(c, bfhi(vv.w), acc[7]);
                    }
                }
            }
        }

#pragma unroll
        for (int dd = 0; dd < 8; ++dd) acc[dd] = wave_sum64(acc[dd]);
        if (lane == 63) {
            unsigned short* op = M.attn_pad + (size_t)((y + 1) * 34 + x + 1) * 192 + f * 64 + m * 8;
            ushort4 s0, s1;
            s0.x = f2bf(acc[0]); s0.y = f2bf(acc[1]); s0.z = f2bf(acc[2]); s0.w = f2bf(acc[3]);
            s1.x = f2bf(acc[4]); s1.y = f2bf(acc[5]); s1.z = f2bf(acc[6]); s1.w = f2bf(acc[7]);
            *(ushort4*)(op) = s0;
            *(ushort4*)(op + 4) = s1;
        }
    }
}

__global__ __launch_bounds__(256) void mega_k(MegaP M) {
    __shared__ unsigned short SMEM[22816];   // 45632 B = max phase (L4)
    const int tid = threadIdx.x;
    const unsigned nb = gridDim.x;

    for (int it = blockIdx.x; it < 160; it += nb) conv_phase(M.l1, it, 20, tid, SMEM, SMEM + 8160);
    gbar(M.bar, nb);
    for (int it = blockIdx.x; it < 160; it += nb) conv_phase(M.l2, it, 20, tid, SMEM, SMEM + 8160);
    gbar(M.bar, nb);
    for (int it = blockIdx.x; it < 64;  it += nb) conv_phase(M.l3, it, 8,  tid, SMEM, SMEM + 8160);
    gbar(M.bar, nb);
    for (int it = blockIdx.x; it < 594; it += nb) l4_phase(M.l4, it, tid, SMEM, SMEM + 13600);
    gbar(M.bar, nb);
    for (int it = blockIdx.x; it < 768; it += nb)
        deform_phase(M, it, tid, reinterpret_cast<unsigned short(*)[432]>(SMEM));
    gbar(M.bar, nb);
    for (int it = blockIdx.x; it < 96;  it += nb) conv_phase(M.opa, it, 12, tid, SMEM, SMEM + 8160);
    gbar(M.bar, nb);
    for (int it = blockIdx.x; it < 96;  it += nb) conv_phase(M.opb, it, 12, tid, SMEM, SMEM + 8160);
}

// ---------------------------------------------------------------------------
extern "C" void kernel_launch(void* const* d_in, const int* in_sizes, int n_in,
                              void* d_out, int out_size, void* d_ws, size_t ws_size,
                              hipStream_t stream) {
    const float* x      = (const float*)d_in[0];
    const float* flow_1 = (const float*)d_in[1];
    const float* flow_2 = (const float*)d_in[2];
    const float* flip_1 = (const float*)d_in[3];
    const float* flip_2 = (const float*)d_in[4];
    const float* vp0_w = (const float*)d_in[5];  const float* vp0_b = (const float*)d_in[6];
    const float* vp1_w = (const float*)d_in[7];  const float* vp1_b = (const float*)d_in[8];
    const float* so0_w = (const float*)d_in[9];  const float* so0_b = (const float*)d_in[10];
    const float* so1_w = (const float*)d_in[11]; const float* so1_b = (const float*)d_in[12];
    const float* so2_w = (const float*)d_in[13]; const float* so2_b = (const float*)d_in[14];
    const float* so3_w = (const float*)d_in[15]; const float* so3_b = (const float*)d_in[16];
    const float* aw0_w = (const float*)d_in[17]; const float* aw0_b = (const float*)d_in[18];
    const float* aw1_w = (const float*)d_in[19]; const float* aw1_b = (const float*)d_in[20];
    const float* aw2_w = (const float*)d_in[21]; const float* aw2_b = (const float*)d_in[22];
    const float* aw3_w = (const float*)d_in[23]; const float* aw3_b = (const float*)d_in[24];
    const float* op0_w = (const float*)d_in[25]; const float* op0_b = (const float*)d_in[26];
    const float* op1_w = (const float*)d_in[27]; const float* op1_b = (const float*)d_in[28];
    float* out = (float*)d_out;
    (void)ws_size; (void)in_sizes; (void)n_in; (void)out_size;

    // ---- workspace layout ----
    float* fws = (float*)d_ws;
    float* flow_cn2 = fws;
    float* flow_n2c = flow_cn2 + 2048;
    unsigned short* value_b = (unsigned short*)(flow_n2c + 2048);
    float* so_t     = (float*)(value_b + 196608);
    unsigned short* uws = (unsigned short*)(so_t + 1769472);
    unsigned short* x_pad     = uws;
    unsigned short* vp0h      = x_pad + 1156 * 192;
    unsigned short* extra_pad = vp0h + 1156 * 192;
    unsigned short* s1 = extra_pad + 1156 * 480;
    unsigned short* a1 = s1 + 1156 * 64;
    unsigned short* s2 = a1 + 1156 * 64;
    unsigned short* a2 = s2 + 1156 * 64;
    unsigned short* attn_pad = a2 + 1156 * 64;
    unsigned short* op0h     = attn_pad + 1156 * 192;
    unsigned short* aw_t = op0h + 1156 * 192;
    unsigned short* wgt  = aw_t + (size_t)3072 * 2592;
    unsigned* bar = (unsigned*)(wgt + (size_t)14688 * 512);

    // ---- 1. prep (+ barrier zeroing) ----
    PrepP pp;
    pp.x = x; pp.f1 = flow_1; pp.f2 = flow_2; pp.ff1 = flip_1; pp.ff2 = flip_2;
    pp.fcn2 = flow_cn2; pp.fn2c = flow_n2c;
    pp.x_pad = x_pad; pp.extra_pad = extra_pad; pp.wgt = wgt; pp.bar = bar;
    pp.wd[0]  = {vp0_w, 192, 192, 6,     0,    0};
    pp.wd[1]  = {vp1_w, 192, 192, 6,   648,   72};
    pp.wd[2]  = {so0_w,  64, 460, 15, 1296,  144};
    pp.wd[3]  = {aw0_w,  64, 460, 15, 1836,  204};
    pp.wd[4]  = {so1_w,  64,  64, 2,  2376,  264};
    pp.wd[5]  = {aw1_w,  64,  64, 2,  2448,  272};
    pp.wd[6]  = {so2_w,  64,  64, 2,  2520,  280};
    pp.wd[7]  = {aw2_w,  64,  64, 2,  2592,  288};
    pp.wd[8]  = {so3_w, 1728, 64, 2,  2664,  296};
    pp.wd[9]  = {aw3_w, 7776, 64, 2,  4608,  512};
    pp.wd[10] = {op0_w, 192, 192, 6, 13392, 1488};
    pp.wd[11] = {op1_w, 192, 192, 6, 14040, 1560};
    prep_k<<<2336, 256, 0, stream>>>(pp);

    const int BIG = 1 << 30;
    CDesc nul = {nullptr, nullptr, nullptr, nullptr, nullptr, 0, 0, 0, 0, 0, 0, BIG};

    // ---- 2. mega kernel: L1..L4 + deform + op0 + op1, 6 grid barriers ----
    MegaP M;
    M.l1.d[0] = {x_pad,     wgt + (size_t)0 * 512,    vp0_b, vp0h, nullptr, 192, 6,  192, 3, 192, 1, 12};
    M.l1.d[1] = {extra_pad, wgt + (size_t)1296 * 512, so0_b, s1,   nullptr, 480, 15, 64,  3, 64,  1, 4};
    M.l1.d[2] = {extra_pad, wgt + (size_t)1836 * 512, aw0_b, a1,   nullptr, 480, 15, 64,  3, 64,  1, 4};
    M.l1.d[3] = nul;
    M.l2.d[0] = {vp0h, wgt + (size_t)648 * 512,  vp1_b, value_b, nullptr, 192, 6, 192, 2, 8,  0, 12};
    M.l2.d[1] = {s1,   wgt + (size_t)2376 * 512, so1_b, s2,      nullptr, 64,  2, 64,  3, 64, 1, 4};
    M.l2.d[2] = {a1,   wgt + (size_t)2448 * 512, aw1_b, a2,      nullptr, 64,  2, 64,  3, 64, 1, 4};
    M.l2.d[3] = nul;
    M.l3.d[0] = {s2, wgt + (size_t)2520 * 512, so2_b, s1, nullptr, 64, 2, 64, 3, 64, 1, 4};
    M.l3.d[1] = {a2, wgt + (size_t)2592 * 512, aw2_b, a1, nullptr, 64, 2, 64, 3, 64, 1, 4};
    M.l3.d[2] = nul; M.l3.d[3] = nul;
    M.l4.d[0] = {s1, wgt + (size_t)2664 * 512, so3_b, so_t, 1, 576,  108};
    M.l4.d[1] = {a1, wgt + (size_t)4608 * 512, aw3_b, aw_t, 2, 2592, 486};
    M.opa.d[0] = {attn_pad, wgt + (size_t)13392 * 512, op0_b, op0h, nullptr, 192, 6, 192, 3, 192, 1, 12};
    M.opa.d[1] = nul; M.opa.d[2] = nul; M.opa.d[3] = nul;
    M.opb.d[0] = {op0h, wgt + (size_t)14040 * 512, op1_b, out, x, 192, 6, 192, 0, 0, 0, 12};
    M.opb.d[1] = nul; M.opb.d[2] = nul; M.opb.d[3] = nul;
    M.value_b = value_b; M.so_t = so_t; M.aw_t = aw_t;
    M.f1 = flow_1; M.f2 = flow_2; M.ff1 = flip_1; M.ff2 = flip_2;
    M.fcn2 = flow_cn2; M.fn2c = flow_n2c;
    M.attn_pad = attn_pad; M.bar = bar;

    // Grid sized from a runtime occupancy query -> all blocks guaranteed
    // co-resident; barrier cannot deadlock. Grid-stride handles any size.
    int maxb = 0;
    if (hipOccupancyMaxActiveBlocksPerMultiprocessor(&maxb, mega_k, 256, 0) != hipSuccess || maxb < 1)
        maxb = 1;
    if (maxb > 3) maxb = 3;
    int grid = maxb * 256;
    mega_k<<<grid, 256, 0, stream>>>(M);
}

// Round 11
// 260.109 us; speedup vs baseline: 2.8323x; 2.8323x over previous
//
#include <hip/hip_runtime.h>
#include <math.h>

#define HW 1024

typedef __attribute__((ext_vector_type(8))) short bf16x8;
typedef __attribute__((ext_vector_type(4))) float floatx4;

__device__ __forceinline__ unsigned short f2bf(float f) {
    unsigned u = __float_as_uint(f);
    u += 0x7FFF + ((u >> 16) & 1);
    return (unsigned short)(u >> 16);
}
__device__ __forceinline__ float bf2f(unsigned short u) {
    return __uint_as_float(((unsigned)u) << 16);
}
__device__ __forceinline__ float bflo(unsigned u) { return __uint_as_float(u << 16); }
__device__ __forceinline__ float bfhi(unsigned u) { return __uint_as_float(u & 0xffff0000u); }

// ---------------------------------------------------------------------------
// DPP wave-64 reductions: VALU-only. Result lands in lane 63.
// ---------------------------------------------------------------------------
template<int CTRL, int RM>
__device__ __forceinline__ float dpp_sum_step(float v) {
    int t = __builtin_amdgcn_update_dpp(0, __float_as_int(v), CTRL, RM, 0xf, true);
    return v + __int_as_float(t);
}
template<int CTRL, int RM>
__device__ __forceinline__ float dpp_max_step(float v) {
    int t = __builtin_amdgcn_update_dpp(__float_as_int(v), __float_as_int(v), CTRL, RM, 0xf, false);
    return fmaxf(v, __int_as_float(t));
}
__device__ __forceinline__ float wave_sum64(float x) {
    x = dpp_sum_step<0x111, 0xf>(x);   // row_shr:1
    x = dpp_sum_step<0x112, 0xf>(x);   // row_shr:2
    x = dpp_sum_step<0x114, 0xf>(x);   // row_shr:4
    x = dpp_sum_step<0x118, 0xf>(x);   // row_shr:8
    x = dpp_sum_step<0x142, 0xa>(x);   // row_bcast:15 -> rows 1,3
    x = dpp_sum_step<0x143, 0xc>(x);   // row_bcast:31 -> rows 2,3
    return x;
}
__device__ __forceinline__ float wave_max64(float x) {
    x = dpp_max_step<0x111, 0xf>(x);
    x = dpp_max_step<0x112, 0xf>(x);
    x = dpp_max_step<0x114, 0xf>(x);
    x = dpp_max_step<0x118, 0xf>(x);
    x = dpp_max_step<0x142, 0xa>(x);
    x = dpp_max_step<0x143, 0xc>(x);
    return x;
}
__device__ __forceinline__ float bcast_lane63(float x) {
    return __int_as_float(__builtin_amdgcn_readlane(__float_as_int(x), 63));
}

// ---------------------------------------------------------------------------
// Bilinear sample, zero padding, absolute pixel coords (matches reference).
// ---------------------------------------------------------------------------
__device__ __forceinline__ float bilin32(const float* __restrict__ img, float px, float py) {
    float x0f = floorf(px), y0f = floorf(py);
    float wx = px - x0f, wy = py - y0f;
    bool vx0 = (x0f >= 0.f) && (x0f <= 31.f);
    bool vx1 = (x0f >= -1.f) && (x0f <= 30.f);
    bool vy0 = (y0f >= 0.f) && (y0f <= 31.f);
    bool vy1 = (y0f >= -1.f) && (y0f <= 30.f);
    int ix0 = (int)fminf(fmaxf(x0f, 0.f), 31.f);
    int iy0 = (int)fminf(fmaxf(y0f, 0.f), 31.f);
    int ix1 = (int)fminf(fmaxf(x0f + 1.f, 0.f), 31.f);
    int iy1 = (int)fminf(fmaxf(y0f + 1.f, 0.f), 31.f);
    float w00 = (1.f - wx) * (1.f - wy) * ((vx0 && vy0) ? 1.f : 0.f);
    float w01 = wx * (1.f - wy) * ((vx1 && vy0) ? 1.f : 0.f);
    float w10 = (1.f - wx) * wy * ((vx0 && vy1) ? 1.f : 0.f);
    float w11 = wx * wy * ((vx1 && vy1) ? 1.f : 0.f);
    return w00 * img[iy0 * 32 + ix0] + w01 * img[iy0 * 32 + ix1] +
           w10 * img[iy1 * 32 + ix0] + w11 * img[iy1 * 32 + ix1];
}

__device__ __forceinline__ float2 comp_flow(const float* __restrict__ fa,
                                            const float* __restrict__ fb, int pix) {
    int y = pix >> 5, x = pix & 31;
    float fx = fa[pix], fy = fa[HW + pix];
    float px = (float)x + fx, py = (float)y + fy;
    float2 r;
    r.x = fx + bilin32(fb, px, py);
    r.y = fy + bilin32(fb + HW, px, py);
    return r;
}

// ---------------------------------------------------------------------------
// Prep kernel: sections by blockIdx.x (grid 2336).
//  [0,192)     xpad: x -> x_pad bf16 [34*34][192]
//  [192,672)   build_extra, 4 channels/thread (shared bilinear coords)
//  [672,688)   flow_cn2 / flow_n2c fp32
//  [688,704)   border zeroing of the 9 padded bf16 buffers
//  [704,2336)  wxform: all 12 weight tensors -> bf16 MFMA fragment order
// ---------------------------------------------------------------------------
struct WD { const float* src; int cout, Cin, nCb, wbase, beg; };
struct PrepP {
    const float *x, *f1, *f2, *ff1, *ff2;
    float *fcn2, *fn2c;
    unsigned short *x_pad, *extra_pad, *wgt;
    WD wd[12];
};

__global__ __launch_bounds__(256) void prep_k(PrepP P) {
    __shared__ float wlds[16 * 288];
    const int b = blockIdx.x, tid = threadIdx.x;
    if (b < 192) {
        int idx = b * 256 + tid;                 // < 1024*48
        int pix = idx / 48, c4 = idx - pix * 48;
        int y = pix >> 5, xx = pix & 31;
        int c0 = c4 * 4;
        ushort4 s;
        s.x = f2bf(P.x[(size_t)(c0 + 0) * HW + pix]);
        s.y = f2bf(P.x[(size_t)(c0 + 1) * HW + pix]);
        s.z = f2bf(P.x[(size_t)(c0 + 2) * HW + pix]);
        s.w = f2bf(P.x[(size_t)(c0 + 3) * HW + pix]);
        *(ushort4*)(&P.x_pad[(size_t)((y + 1) * 34 + xx + 1) * 192 + c0]) = s;
    } else if (b < 672) {
        int idx = (b - 192) * 256 + tid;         // < 1024*120
        int pix = idx / 120, c4 = idx - pix * 120;
        int y = pix >> 5, xx = pix & 31;
        int c0 = c4 * 4;
        float va[4];
        if (c0 < 64) {
#pragma unroll
            for (int k = 0; k < 4; ++k) va[k] = P.x[(size_t)(c0 + k) * HW + pix];
        } else if (c0 < 448) {
            int grp = (c0 - 64) >> 6;
            int c = (c0 - 64) & 63;
            const float* src; float fx, fy;
            if (grp == 0)      { src = P.x + 64 * HW;  fx = P.f1[pix];  fy = P.f1[HW + pix]; }
            else if (grp == 1) { src = P.x + 128 * HW; float2 r = comp_flow(P.f1, P.f2, pix);  fx = r.x; fy = r.y; }
            else if (grp == 2) { src = P.x;            fx = P.ff1[pix]; fy = P.ff1[HW + pix]; }
            else if (grp == 3) { src = P.x + 128 * HW; fx = P.f2[pix];  fy = P.f2[HW + pix]; }
            else if (grp == 4) { src = P.x + 64 * HW;  fx = P.ff2[pix]; fy = P.ff2[HW + pix]; }
            else               { src = P.x;            float2 r = comp_flow(P.ff2, P.ff1, pix); fx = r.x; fy = r.y; }
            float px = (float)xx + fx, py = (float)y + fy;
            float x0f = floorf(px), y0f = floorf(py);
            float wx = px - x0f, wy = py - y0f;
            bool vx0 = (x0f >= 0.f) && (x0f <= 31.f);
            bool vx1 = (x0f >= -1.f) && (x0f <= 30.f);
            bool vy0 = (y0f >= 0.f) && (y0f <= 31.f);
            bool vy1 = (y0f >= -1.f) && (y0f <= 30.f);
            int ix0 = (int)fminf(fmaxf(x0f, 0.f), 31.f);
            int iy0 = (int)fminf(fmaxf(y0f, 0.f), 31.f);
            int ix1 = (int)fminf(fmaxf(x0f + 1.f, 0.f), 31.f);
            int iy1 = (int)fminf(fmaxf(y0f + 1.f, 0.f), 31.f);
            float w00 = (1.f - wx) * (1.f - wy) * ((vx0 && vy0) ? 1.f : 0.f);
            float w01 = wx * (1.f - wy) * ((vx1 && vy0) ? 1.f : 0.f);
            float w10 = (1.f - wx) * wy * ((vx0 && vy1) ? 1.f : 0.f);
            float w11 = wx * wy * ((vx1 && vy1) ? 1.f : 0.f);
            int p00 = iy0 * 32 + ix0, p01 = iy0 * 32 + ix1;
            int p10 = iy1 * 32 + ix0, p11 = iy1 * 32 + ix1;
            const float* im = src + (size_t)c * HW;
#pragma unroll
            for (int k = 0; k < 4; ++k) {
                va[k] = w00 * im[p00] + w01 * im[p01] + w10 * im[p10] + w11 * im[p11];
                im += HW;
            }
        } else {
#pragma unroll
            for (int k = 0; k < 4; ++k) {
                int ch = c0 + k;
                float v = 0.f;
                if (ch < 460) {
                    int fc = ch - 448;
                    int which = fc >> 1, comp = fc & 1;
                    if (which == 0)      v = P.f1[comp * HW + pix];
                    else if (which == 1) { float2 r = comp_flow(P.f1, P.f2, pix);  v = comp ? r.y : r.x; }
                    else if (which == 2) v = P.ff1[comp * HW + pix];
                    else if (which == 3) v = P.f2[comp * HW + pix];
                    else if (which == 4) v = P.ff2[comp * HW + pix];
                    else                 { float2 r = comp_flow(P.ff2, P.ff1, pix); v = comp ? r.y : r.x; }
                }
                va[k] = v;
            }
        }
        ushort4 s;
        s.x = f2bf(va[0]); s.y = f2bf(va[1]); s.z = f2bf(va[2]); s.w = f2bf(va[3]);
        *(ushort4*)(&P.extra_pad[(size_t)((y + 1) * 34 + xx + 1) * 480 + c0]) = s;
    } else if (b < 688) {
        int idx = (b - 672) * 256 + tid;
        if (idx < 1024) {
            float2 r = comp_flow(P.f1, P.f2, idx);
            P.fcn2[idx] = r.x; P.fcn2[HW + idx] = r.y;
        } else if (idx < 2048) {
            int pix = idx - 1024;
            float2 r = comp_flow(P.ff2, P.ff1, pix);
            P.fn2c[pix] = r.x; P.fn2c[HW + pix] = r.y;
        }
    } else if (b < 704) {
        const int chans[9] = {192, 192, 480, 64, 64, 64, 64, 192, 192};
        size_t offs[9]; size_t a = 0;
        for (int i = 0; i < 9; ++i) { offs[i] = a; a += (size_t)1156 * chans[i]; }
        int bb = b - 688;
        for (int item = bb; item < 9 * 132; item += 16) {
            int buf = item / 132, i = item - buf * 132;
            int py, px;
            if (i < 34) { py = 0; px = i; }
            else if (i < 68) { py = 33; px = i - 34; }
            else { int j = i - 68; py = 1 + (j >> 1); px = (j & 1) ? 33 : 0; }
            int C = chans[buf];
            unsigned short* p = P.x_pad + offs[buf] + (size_t)(py * 34 + px) * C;
            for (int c = tid; c < C; c += 256) p[c] = 0;
        }
    } else {
        int blk = b - 704;                       // < 1632
        int di = 0;
        while (di < 11 && blk >= P.wd[di + 1].beg) ++di;
        WD w = P.wd[di];
        int local = blk - w.beg;
        int co16 = local / w.nCb, cb = local - co16 * w.nCb;
        int cr0 = co16 * 16, ci0 = cb * 32;
        for (int i = tid; i < 16 * 288; i += 256) {
            int cr = i / 288, o = i - cr * 288;
            int crg = cr0 + cr, ci = ci0 + o / 9;
            float v = (crg < w.cout && ci < w.Cin)
                ? w.src[((size_t)crg * w.Cin + ci0) * 9 + o] : 0.f;
            wlds[i] = v;
        }
        __syncthreads();
        for (int e = tid; e < 9 * 512; e += 256) {
            int t = e >> 9, idx = e & 511;
            int j = idx & 7, lane = idx >> 3, q = lane >> 4, mm = lane & 15;
            P.wgt[((size_t)w.wbase + ((size_t)co16 * 9 + t) * w.nCb + cb) * 512 + idx] =
                f2bf(wlds[mm * 288 + (q * 8 + j) * 9 + t]);
        }
    }
}

// ---------------------------------------------------------------------------
// MFMA 3x3 conv, multi-descriptor, register-prefetch double-buffered.
// ---------------------------------------------------------------------------
struct CDesc {
    const unsigned short* in;
    const unsigned short* wgt;
    const float* bias;
    void* out;
    const float* residual;
    int Cpad, nCb, Cout, mode, cmod, relu, Mblocks;
};
struct CParam { CDesc d[4]; };

template<int PIXROWS, int COBLK>
__global__ __launch_bounds__(256) void conv_mfma_k(CParam P) {
    constexpr int TROWS = PIXROWS + 2;
    constexpr int TC = TROWS * 34 * 4;
    constexpr int ITRIPS = (TC + 255) / 256;
    constexpr int NTY = PIXROWS / 4;
    constexpr int NACC = NTY * 2;
    constexpr int MT = COBLK / 16;
    constexpr int WN = MT * 9 * 64;
    constexpr int WTRIPS = (WN + 255) / 256;
    __shared__ unsigned short blds[TROWS * 34 * 40];
    __shared__ unsigned short wlds[MT * 9 * 512];

    int bx = blockIdx.x;
    int di = 0;
    while (bx >= P.d[di].Mblocks) { bx -= P.d[di].Mblocks; ++di; }
    const CDesc d = P.d[di];

    const int tid = threadIdx.x;
    const int w = tid >> 6, lane = tid & 63;
    const int lq = lane >> 4, ln = lane & 15;
    const int co0 = bx * COBLK;
    const int by = blockIdx.y, y0 = by * PIXROWS;
    const unsigned short* __restrict__ in = d.in;
    const unsigned short* __restrict__ wg = d.wgt;
    const int Cpad = d.Cpad, nCb = d.nCb;

    floatx4 acc[MT][NACC];
#pragma unroll
    for (int mt = 0; mt < MT; ++mt)
#pragma unroll
        for (int nt = 0; nt < NACC; ++nt)
            acc[mt][nt] = (floatx4){0.f, 0.f, 0.f, 0.f};

    bf16x8 ireg[ITRIPS];
    bf16x8 wreg[WTRIPS];

    auto load_regs = [&](int cb) {
        const int ci0 = cb << 5;
#pragma unroll
        for (int k = 0; k < ITRIPS; ++k) {
            int i = tid + k * 256;
            if (i < TC) {
                int r = i / 136, rem = i - r * 136, c = rem >> 2, g = rem & 3;
                ireg[k] = *(const bf16x8*)(in + (size_t)((y0 + r) * 34 + c) * Cpad + ci0 + g * 8);
            }
        }
#pragma unroll
        for (int k = 0; k < WTRIPS; ++k) {
            int i = tid + k * 256;
            if (i < WN) {
                int chunk = i >> 6, l16 = i & 63;
                int mt = chunk / 9, t = chunk - mt * 9;
                wreg[k] = *(const bf16x8*)(wg + ((size_t)(((co0 >> 4) + mt) * 9 + t) * nCb + cb) * 512 + l16 * 8);
            }
        }
    };

    load_regs(0);

    for (int cb = 0; cb < nCb; ++cb) {
        __syncthreads();
#pragma unroll
        for (int k = 0; k < ITRIPS; ++k) {
            int i = tid + k * 256;
            if (i < TC) {
                int r = i / 136, rem = i - r * 136, c = rem >> 2, g = rem & 3;
                *(bf16x8*)(&blds[(r * 34 + c) * 40 + g * 8]) = ireg[k];
            }
        }
#pragma unroll
        for (int k = 0; k < WTRIPS; ++k) {
            int i = tid + k * 256;
            if (i < WN) {
                int chunk = i >> 6, l16 = i & 63;
                *(bf16x8*)(&wlds[chunk * 512 + l16 * 8]) = wreg[k];
            }
        }
        __syncthreads();
        if (cb + 1 < nCb) load_regs(cb + 1);
        for (int t = 0; t < 9; ++t) {
            const int dy = t / 3, dx = t - dy * 3;
            bf16x8 bfr[NACC];
#pragma unroll
            for (int ty = 0; ty < NTY; ++ty)
#pragma unroll
                for (int tx = 0; tx < 2; ++tx) {
                    int yy = w * NTY + ty + dy;
                    int xx = tx * 16 + ln + dx;
                    bfr[ty * 2 + tx] = *(const bf16x8*)(&blds[(yy * 34 + xx) * 40 + lq * 8]);
                }
#pragma unroll
            for (int mt = 0; mt < MT; ++mt) {
                bf16x8 afr = *(const bf16x8*)(&wlds[(mt * 9 + t) * 512 + lane * 8]);
#pragma unroll
                for (int nt = 0; nt < NACC; ++nt)
                    acc[mt][nt] = __builtin_amdgcn_mfma_f32_16x16x32_bf16(afr, bfr[nt], acc[mt][nt], 0, 0, 0);
            }
        }
    }

#pragma unroll
    for (int mt = 0; mt < MT; ++mt) {
        const int co = co0 + mt * 16 + lq * 4;
        if (co >= d.Cout) continue;
        float bv[4];
#pragma unroll
        for (int r = 0; r < 4; ++r) bv[r] = d.bias[co + r];
#pragma unroll
        for (int nt = 0; nt < NACC; ++nt) {
            const int ty = nt >> 1, tx = nt & 1;
            const int pix = by * (PIXROWS * 32) + (w * NTY + ty) * 32 + tx * 16 + ln;
            float v[4];
#pragma unroll
            for (int r = 0; r < 4; ++r) {
                float vv = acc[mt][nt][r] + bv[r];
                if (d.relu) vv = (vv >= 0.f) ? vv : 0.1f * vv;
                v[r] = vv;
            }
            if (d.mode == 0) {
                float* o = (float*)d.out;
#pragma unroll
                for (int r = 0; r < 4; ++r) {
                    float vv = v[r];
                    if (d.residual) vv += d.residual[(size_t)(co + r) * HW + pix];
                    o[(size_t)(co + r) * HW + pix] = vv;
                }
            } else if (d.mode == 1) {
                int fq = co / d.cmod, cc = co - fq * d.cmod;
                *(float4*)((float*)d.out + ((size_t)fq * HW + pix) * d.cmod + cc) =
                    make_float4(v[0], v[1], v[2], v[3]);
            } else if (d.mode == 2) {
                int fq = co / d.cmod, cc = co - fq * d.cmod;
                ushort4 s4;
                s4.x = f2bf(v[0]); s4.y = f2bf(v[1]); s4.z = f2bf(v[2]); s4.w = f2bf(v[3]);
                *(ushort4*)((unsigned short*)d.out + ((size_t)fq * HW + pix) * d.cmod + cc) = s4;
            } else {
                int yy = (pix >> 5) + 1, xx = (pix & 31) + 1;
                ushort4 s4;
                s4.x = f2bf(v[0]); s4.y = f2bf(v[1]); s4.z = f2bf(v[2]); s4.w = f2bf(v[3]);
                *(ushort4*)((unsigned short*)d.out + (size_t)(yy * 34 + xx) * d.cmod + co) = s4;
            }
        }
    }
}

// ---------------------------------------------------------------------------
// L4 conv (so3 + aw3): weight-dominant layer (10.9 MB weights, Cin=64).
// Each block owns 16 output channels for the WHOLE image: both cb weight
// slices loaded to LDS exactly once, then 4 y-strips x 2 cb with register-
// prefetched input staging. LDS 45632 B -> 3 blocks/CU. Grid 594.
// ---------------------------------------------------------------------------
struct L4Desc {
    const unsigned short* in;
    const unsigned short* wgt;
    const float* bias;
    void* out;
    int mode, cmod, Mblocks;   // mode 1 = f32 strided, 2 = bf16 strided
};
struct L4Param { L4Desc d[2]; };

__global__ __launch_bounds__(256) void conv_l4_k(L4Param P) {
    __shared__ unsigned short blds[10 * 34 * 40];   // 27200 B (one cb slice)
    __shared__ unsigned short wlds[9 * 2 * 512];    // 18432 B (both cb slices)

    int bx = blockIdx.x;
    int di = 0;
    if (bx >= P.d[0].Mblocks) { bx -= P.d[0].Mblocks; di = 1; }
    const L4Desc d = P.d[di];

    const int tid = threadIdx.x;
    const int w = tid >> 6, lane = tid & 63;
    const int lq = lane >> 4, ln = lane & 15;
    const int co0 = bx * 16;
    const unsigned short* __restrict__ in = d.in;
    const unsigned short* __restrict__ wg = d.wgt;

    bf16x8 wreg[5];
#pragma unroll
    for (int k = 0; k < 5; ++k) {
        int i = tid + k * 256;
        if (i < 1152) {
            int chunk = i >> 6, l16 = i & 63;
            int t = chunk >> 1, cb = chunk & 1;
            wreg[k] = *(const bf16x8*)(wg + (((size_t)bx * 9 + t) * 2 + cb) * 512 + l16 * 8);
        }
    }

    bf16x8 ireg[6];
    auto load_in = [&](int y0, int cb) {
        const int ci0 = cb << 5;
#pragma unroll
        for (int k = 0; k < 6; ++k) {
            int i = tid + k * 256;
            if (i < 1360) {
                int r = i / 136, rem = i - r * 136, c = rem >> 2, g = rem & 3;
                ireg[k] = *(const bf16x8*)(in + (size_t)((y0 + r) * 34 + c) * 64 + ci0 + g * 8);
            }
        }
    };
    load_in(0, 0);

#pragma unroll
    for (int k = 0; k < 5; ++k) {
        int i = tid + k * 256;
        if (i < 1152) *(bf16x8*)(&wlds[(i >> 6) * 512 + (i & 63) * 8]) = wreg[k];
    }

    floatx4 acc[4];
#pragma unroll
    for (int nt = 0; nt < 4; ++nt) acc[nt] = (floatx4){0.f, 0.f, 0.f, 0.f};

    for (int p = 0; p < 8; ++p) {
        const int y = p >> 1, cb = p & 1;
        __syncthreads();
#pragma unroll
        for (int k = 0; k < 6; ++k) {
            int i = tid + k * 256;
            if (i < 1360) {
                int r = i / 136, rem = i - r * 136, c = rem >> 2, g = rem & 3;
                *(bf16x8*)(&blds[(r * 34 + c) * 40 + g * 8]) = ireg[k];
            }
        }
        __syncthreads();
        if (p < 7) { int pn = p + 1; load_in((pn >> 1) * 8, pn & 1); }
#pragma unroll
        for (int t = 0; t < 9; ++t) {
            const int dy = t / 3, dx = t - dy * 3;
            bf16x8 afr = *(const bf16x8*)(&wlds[(t * 2 + cb) * 512 + lane * 8]);
#pragma unroll
            for (int ty = 0; ty < 2; ++ty)
#pragma unroll
                for (int tx = 0; tx < 2; ++tx) {
                    int yy = w * 2 + ty + dy;
                    int xx = tx * 16 + ln + dx;
                    bf16x8 bfr = *(const bf16x8*)(&blds[(yy * 34 + xx) * 40 + lq * 8]);
                    acc[ty * 2 + tx] =
                        __builtin_amdgcn_mfma_f32_16x16x32_bf16(afr, bfr, acc[ty * 2 + tx], 0, 0, 0);
                }
        }
        if (cb == 1) {
            const int co = co0 + lq * 4;
            float bv[4];
#pragma unroll
            for (int r2 = 0; r2 < 4; ++r2) bv[r2] = d.bias[co + r2];
            int fq = co / d.cmod, cc = co - fq * d.cmod;
#pragma unroll
            for (int nt = 0; nt < 4; ++nt) {
                const int ty = nt >> 1, tx = nt & 1;
                const int pix = y * 256 + (w * 2 + ty) * 32 + tx * 16 + ln;
                float v0 = acc[nt][0] + bv[0], v1 = acc[nt][1] + bv[1];
                float v2 = acc[nt][2] + bv[2], v3 = acc[nt][3] + bv[3];
                if (d.mode == 1) {
                    *(float4*)((float*)d.out + ((size_t)fq * HW + pix) * d.cmod + cc) =
                        make_float4(v0, v1, v2, v3);
                } else {
                    ushort4 s4;
                    s4.x = f2bf(v0); s4.y = f2bf(v1); s4.z = f2bf(v2); s4.w = f2bf(v3);
                    *(ushort4*)((unsigned short*)d.out + ((size_t)fq * HW + pix) * d.cmod + cc) = s4;
                }
                acc[nt] = (floatx4){0.f, 0.f, 0.f, 0.f};
            }
        }
    }
}

// ---------------------------------------------------------------------------
// Deformable attention, no-LDS-value variant (round-8 best, + so2 loads moved
// into the gather loop: frees ~6 VGPRs; so_t rows are L1-hot so the re-read
// is cheap. If the allocator lands <=64 VGPR the 8-waves/SIMD occupancy comes
// for free; otherwise identical perf to round 8). DPP reductions; lane 63
// stores. value_b layout [l][m][pix][8ch]: level stride 65536, head m*8192.
// ---------------------------------------------------------------------------
__global__ __launch_bounds__(256) void deform_attn_k(
    const unsigned short* __restrict__ value_b, const float* __restrict__ so_t,
    const unsigned short* __restrict__ aw_t,
    const float* __restrict__ flow_1, const float* __restrict__ flow_2,
    const float* __restrict__ flip_flow_1, const float* __restrict__ flip_flow_2,
    const float* __restrict__ flow_cn2, const float* __restrict__ flow_n2c,
    unsigned short* __restrict__ attn_pad)
{
    __shared__ unsigned short pwlds[4][432];
    const int tid = threadIdx.x;
    const int wav = tid >> 6, lane = tid & 63;
    const int m = blockIdx.x & 7, qc = blockIdx.x >> 3;

    const int pp = lane & 15, gq = lane >> 4;
    const int gdy = (gq >> 1) * 2 - 1;
    const int gdx = (gq & 1) * 2 - 1;
    const bool selx = (gq & 1);
    const bool sely = (gq >> 1);

    // per-head base of the value image ([l][m][pix][8]: head offset m*8192)
    const unsigned short* __restrict__ vm = value_b + (size_t)m * 8192;

    for (int r = 0; r < 8; ++r) {
        const int q = qc * 32 + r * 4 + wav;
        const int f = q >> 10, pix = q & 1023;
        const int y = pix >> 5, x = pix & 31;

        // logits for this query
        float av[6];
        {
            const unsigned short* awp = aw_t + (size_t)q * 2592 + m * 324;
#pragma unroll
            for (int it = 0; it < 6; ++it) {
                int j = lane + it * 64;
                av[it] = (j < 324) ? bf2f(awp[j]) : -1e30f;
            }
        }

        float vmax = -1e30f;
#pragma unroll
        for (int it = 0; it < 6; ++it) vmax = fmaxf(vmax, av[it]);
        vmax = bcast_lane63(wave_max64(vmax));
        float ssum = 0.f;
#pragma unroll
        for (int it = 0; it < 6; ++it) {
            int j = lane + it * 64;
            float e = (j < 324) ? __expf(av[it] - vmax) : 0.f;
            av[it] = e;
            ssum += e;
        }
        ssum = bcast_lane63(wave_sum64(ssum));
        const float inv = 1.f / ssum;

#pragma unroll
        for (int it = 0; it < 6; ++it) {
            int j = lane + it * 64;
            if (j < 324) {
                int pi = j / 9, k = j - pi * 9;
                pwlds[wav][pi * 12 + k] = f2bf(av[it] * inv);
            }
        }

        const float* sop = so_t + (size_t)q * 576 + m * 72;

        float flx0 = 0.f, fly0 = 0.f, flx1 = 0.f, fly1 = 0.f, flx2 = 0.f, fly2 = 0.f;
        if (f == 0) {
            flx1 = flow_1[pix];      fly1 = flow_1[HW + pix];
            flx2 = flow_cn2[pix];    fly2 = flow_cn2[HW + pix];
        } else if (f == 1) {
            flx0 = flip_flow_1[pix]; fly0 = flip_flow_1[HW + pix];
            flx2 = flow_2[pix];      fly2 = flow_2[HW + pix];
        } else {
            flx0 = flow_n2c[pix];    fly0 = flow_n2c[HW + pix];
            flx1 = flip_flow_2[pix]; fly1 = flip_flow_2[HW + pix];
        }

        float acc[8];
#pragma unroll
        for (int dd = 0; dd < 8; ++dd) acc[dd] = 0.f;

#pragma unroll
        for (int pt = 0; pt < 3; ++pt) {
            int pi = pt * 16 + pp;
            if (pi < 36) {
                int l = pi / 12;
                // so-offset loaded here (not cached across the loop): L1-hot
                float2 so2 = *(const float2*)(sop + pi * 2);
                float fx = (l == 0) ? flx0 : (l == 1) ? flx1 : flx2;
                float fy = (l == 0) ? fly0 : (l == 1) ? fly1 : fly2;
                float bxf = (float)x + so2.x + fx;
                float byf = (float)y + so2.y + fy;
                float x0f = floorf(bxf), y0f = floorf(byf);
                float wx = bxf - x0f, wy = byf - y0f;
                float ax = 1.f - wx, ay = 1.f - wy;
                int x0 = (int)fminf(fmaxf(x0f, -2.f), 34.f);
                int y0 = (int)fminf(fmaxf(y0f, -2.f), 34.f);

                const unsigned short* pr = &pwlds[wav][pi * 12];
                uint2 pv0 = *(const uint2*)(pr);
                uint2 pv1 = *(const uint2*)(pr + 4);
                float a0 = bflo(pv0.x), a1 = bfhi(pv0.x), a2 = bflo(pv0.y);
                float a3 = bfhi(pv0.y), a4 = bflo(pv1.x), a5 = bfhi(pv1.x);
                float a6 = bflo(pv1.y), a7 = bfhi(pv1.y), a8 = bf2f(pr[8]);

                float bs0a, bs0b, bs1a, bs1b, bs2a, bs2b;
                {
                    float b0, b1, b2, b3;
                    b0 = a0 * ax; b1 = a0 * wx + a3 * ax; b2 = a3 * wx + a6 * ax; b3 = a6 * wx;
                    bs0a = selx ? b2 : b0; bs0b = selx ? b3 : b1;
                    b0 = a1 * ax; b1 = a1 * wx + a4 * ax; b2 = a4 * wx + a7 * ax; b3 = a7 * wx;
                    bs1a = selx ? b2 : b0; bs1b = selx ? b3 : b1;
                    b0 = a2 * ax; b1 = a2 * wx + a5 * ax; b2 = a5 * wx + a8 * ax; b3 = a8 * wx;
                    bs2a = selx ? b2 : b0; bs2b = selx ? b3 : b1;
                }
                float c00, c01, c10, c11;
                {
                    float c0 = bs0a * ay, c1 = bs0a * wy + bs1a * ay;
                    float c2 = bs1a * wy + bs2a * ay, c3 = bs2a * wy;
                    c00 = sely ? c2 : c0; c10 = sely ? c3 : c1;
                    c0 = bs0b * ay; c1 = bs0b * wy + bs1b * ay;
                    c2 = bs1b * wy + bs2b * ay; c3 = bs2b * wy;
                    c01 = sely ? c2 : c0; c11 = sely ? c3 : c1;
                }
                float cg[2][2] = {{c00, c01}, {c10, c11}};
                const unsigned short* __restrict__ vl = vm + (size_t)l * 65536;
#pragma unroll
                for (int sy = 0; sy < 2; ++sy) {
#pragma unroll
                    for (int sx = 0; sx < 2; ++sx) {
                        int dy = gdy + sy, dx = gdx + sx;
                        float pyf = y0f + (float)dy, pxf = x0f + (float)dx;
                        bool v = (pxf >= 0.f) && (pxf <= 31.f) && (pyf >= 0.f) && (pyf <= 31.f);
                        int px = min(max(x0 + dx, 0), 31);
                        int py = min(max(y0 + dy, 0), 31);
                        float c = cg[sy][sx] * (v ? 1.f : 0.f);
                        uint4 vv = *(const uint4*)(vl + (size_t)(py * 32 + px) * 8);
                        acc[0] = fmaf(c, bflo(vv.x), acc[0]);
                        acc[1] = fmaf(c, bfhi(vv.x), acc[1]);
                        acc[2] = fmaf(c, bflo(vv.y), acc[2]);
                        acc[3] = fmaf(c, bfhi(vv.y), acc[3]);
                        acc[4] = fmaf(c, bflo(vv.z), acc[4]);
                        acc[5] = fmaf(c, bfhi(vv.z), acc[5]);
                        acc[6] = fmaf(c, bflo(vv.w), acc[6]);
                        acc[7] = fmaf(c, bfhi(vv.w), acc[7]);
                    }
                }
            }
        }

#pragma unroll
        for (int dd = 0; dd < 8; ++dd) acc[dd] = wave_sum64(acc[dd]);
        if (lane == 63) {
            unsigned short* op = attn_pad + (size_t)((y + 1) * 34 + x + 1) * 192 + f * 64 + m * 8;
            ushort4 s0, s1;
            s0.x = f2bf(acc[0]); s0.y = f2bf(acc[1]); s0.z = f2bf(acc[2]); s0.w = f2bf(acc[3]);
            s1.x = f2bf(acc[4]); s1.y = f2bf(acc[5]); s1.z = f2bf(acc[6]); s1.w = f2bf(acc[7]);
            *(ushort4*)(op) = s0;
            *(ushort4*)(op + 4) = s1;
        }
    }
}

// ---------------------------------------------------------------------------
extern "C" void kernel_launch(void* const* d_in, const int* in_sizes, int n_in,
                              void* d_out, int out_size, void* d_ws, size_t ws_size,
                              hipStream_t stream) {
    const float* x      = (const float*)d_in[0];
    const float* flow_1 = (const float*)d_in[1];
    const float* flow_2 = (const float*)d_in[2];
    const float* flip_1 = (const float*)d_in[3];
    const float* flip_2 = (const float*)d_in[4];
    const float* vp0_w = (const float*)d_in[5];  const float* vp0_b = (const float*)d_in[6];
    const float* vp1_w = (const float*)d_in[7];  const float* vp1_b = (const float*)d_in[8];
    const float* so0_w = (const float*)d_in[9];  const float* so0_b = (const float*)d_in[10];
    const float* so1_w = (const float*)d_in[11]; const float* so1_b = (const float*)d_in[12];
    const float* so2_w = (const float*)d_in[13]; const float* so2_b = (const float*)d_in[14];
    const float* so3_w = (const float*)d_in[15]; const float* so3_b = (const float*)d_in[16];
    const float* aw0_w = (const float*)d_in[17]; const float* aw0_b = (const float*)d_in[18];
    const float* aw1_w = (const float*)d_in[19]; const float* aw1_b = (const float*)d_in[20];
    const float* aw2_w = (const float*)d_in[21]; const float* aw2_b = (const float*)d_in[22];
    const float* aw3_w = (const float*)d_in[23]; const float* aw3_b = (const float*)d_in[24];
    const float* op0_w = (const float*)d_in[25]; const float* op0_b = (const float*)d_in[26];
    const float* op1_w = (const float*)d_in[27]; const float* op1_b = (const float*)d_in[28];
    float* out = (float*)d_out;
    (void)ws_size; (void)in_sizes; (void)n_in; (void)out_size;

    // ---- workspace layout ----
    float* fws = (float*)d_ws;
    float* flow_cn2 = fws;
    float* flow_n2c = flow_cn2 + 2048;
    unsigned short* value_b = (unsigned short*)(flow_n2c + 2048);
    float* so_t     = (float*)(value_b + 196608);
    unsigned short* uws = (unsigned short*)(so_t + 1769472);
    unsigned short* x_pad     = uws;
    unsigned short* vp0h      = x_pad + 1156 * 192;
    unsigned short* extra_pad = vp0h + 1156 * 192;
    unsigned short* s1 = extra_pad + 1156 * 480;
    unsigned short* a1 = s1 + 1156 * 64;
    unsigned short* s2 = a1 + 1156 * 64;
    unsigned short* a2 = s2 + 1156 * 64;
    unsigned short* attn_pad = a2 + 1156 * 64;
    unsigned short* op0h     = attn_pad + 1156 * 192;
    unsigned short* aw_t = op0h + 1156 * 192;
    unsigned short* wgt  = aw_t + (size_t)3072 * 2592;

    // ---- 1. prep ----
    PrepP pp;
    pp.x = x; pp.f1 = flow_1; pp.f2 = flow_2; pp.ff1 = flip_1; pp.ff2 = flip_2;
    pp.fcn2 = flow_cn2; pp.fn2c = flow_n2c;
    pp.x_pad = x_pad; pp.extra_pad = extra_pad; pp.wgt = wgt;
    pp.wd[0]  = {vp0_w, 192, 192, 6,     0,    0};
    pp.wd[1]  = {vp1_w, 192, 192, 6,   648,   72};
    pp.wd[2]  = {so0_w,  64, 460, 15, 1296,  144};
    pp.wd[3]  = {aw0_w,  64, 460, 15, 1836,  204};
    pp.wd[4]  = {so1_w,  64,  64, 2,  2376,  264};
    pp.wd[5]  = {aw1_w,  64,  64, 2,  2448,  272};
    pp.wd[6]  = {so2_w,  64,  64, 2,  2520,  280};
    pp.wd[7]  = {aw2_w,  64,  64, 2,  2592,  288};
    pp.wd[8]  = {so3_w, 1728, 64, 2,  2664,  296};
    pp.wd[9]  = {aw3_w, 7776, 64, 2,  4608,  512};
    pp.wd[10] = {op0_w, 192, 192, 6, 13392, 1488};
    pp.wd[11] = {op1_w, 192, 192, 6, 14040, 1560};
    prep_k<<<2336, 256, 0, stream>>>(pp);

    const int BIG = 1 << 30;
    CDesc nul = {nullptr, nullptr, nullptr, nullptr, nullptr, 0, 0, 0, 0, 0, 0, BIG};

    // ---- 2. L1: vp0 + so0 + aw0 ----
    {
        CParam cp;
        cp.d[0] = {x_pad,     wgt + (size_t)0 * 512,    vp0_b, vp0h, nullptr, 192, 6,  192, 3, 192, 1, 12};
        cp.d[1] = {extra_pad, wgt + (size_t)1296 * 512, so0_b, s1,   nullptr, 480, 15, 64,  3, 64,  1, 4};
        cp.d[2] = {extra_pad, wgt + (size_t)1836 * 512, aw0_b, a1,   nullptr, 480, 15, 64,  3, 64,  1, 4};
        cp.d[3] = nul;
        conv_mfma_k<4, 16><<<dim3(20, 8), 256, 0, stream>>>(cp);
    }
    // ---- 3. L2: vp1 + so1 + aw1 ----
    {
        CParam cp;
        cp.d[0] = {vp0h, wgt + (size_t)648 * 512,  vp1_b, value_b, nullptr, 192, 6, 192, 2, 8,  0, 12};
        cp.d[1] = {s1,   wgt + (size_t)2376 * 512, so1_b, s2,      nullptr, 64,  2, 64,  3, 64, 1, 4};
        cp.d[2] = {a1,   wgt + (size_t)2448 * 512, aw1_b, a2,      nullptr, 64,  2, 64,  3, 64, 1, 4};
        cp.d[3] = nul;
        conv_mfma_k<4, 16><<<dim3(20, 8), 256, 0, stream>>>(cp);
    }
    // ---- 4. L3: so2 + aw2 ----
    {
        CParam cp;
        cp.d[0] = {s2, wgt + (size_t)2520 * 512, so2_b, s1, nullptr, 64, 2, 64, 3, 64, 1, 4};
        cp.d[1] = {a2, wgt + (size_t)2592 * 512, aw2_b, a1, nullptr, 64, 2, 64, 3, 64, 1, 4};
        cp.d[2] = nul; cp.d[3] = nul;
        conv_mfma_k<4, 16><<<dim3(8, 8), 256, 0, stream>>>(cp);
    }
    // ---- 5. L4: so3 + aw3 (dedicated read-once-weights kernel) ----
    {
        L4Param lp;
        lp.d[0] = {s1, wgt + (size_t)2664 * 512, so3_b, so_t, 1, 576,  108};
        lp.d[1] = {a1, wgt + (size_t)4608 * 512, aw3_b, aw_t, 2, 2592, 486};
        conv_l4_k<<<594, 256, 0, stream>>>(lp);
    }

    // ---- 6. deformable attention (no-LDS-value, L2-gather) ----
    deform_attn_k<<<768, 256, 0, stream>>>(value_b, so_t, aw_t,
                                           flow_1, flow_2, flip_1, flip_2,
                                           flow_cn2, flow_n2c, attn_pad);

    // ---- 7. op0 ----
    {
        CParam cp;
        cp.d[0] = {attn_pad, wgt + (size_t)13392 * 512, op0_b, op0h, nullptr, 192, 6, 192, 3, 192, 1, 12};
        cp.d[1] = nul; cp.d[2] = nul; cp.d[3] = nul;
        conv_mfma_k<4, 16><<<dim3(12, 8), 256, 0, stream>>>(cp);
    }
    // ---- 8. op1 + residual ----
    {
        CParam cp;
        cp.d[0] = {op0h, wgt + (size_t)14040 * 512, op1_b, out, x, 192, 6, 192, 0, 0, 0, 12};
        cp.d[1] = nul; cp.d[2] = nul; cp.d[3] = nul;
        conv_mfma_k<4, 16><<<dim3(12, 8), 256, 0, stream>>>(cp);
    }
}

// Round 12
// 256.011 us; speedup vs baseline: 2.8777x; 1.0160x over previous
//
#include <hip/hip_runtime.h>
#include <math.h>

#define HW 1024

typedef __attribute__((ext_vector_type(8))) short bf16x8;
typedef __attribute__((ext_vector_type(4))) float floatx4;

__device__ __forceinline__ unsigned short f2bf(float f) {
    unsigned u = __float_as_uint(f);
    u += 0x7FFF + ((u >> 16) & 1);
    return (unsigned short)(u >> 16);
}
__device__ __forceinline__ float bf2f(unsigned short u) {
    return __uint_as_float(((unsigned)u) << 16);
}
__device__ __forceinline__ float bflo(unsigned u) { return __uint_as_float(u << 16); }
__device__ __forceinline__ float bfhi(unsigned u) { return __uint_as_float(u & 0xffff0000u); }

// ---------------------------------------------------------------------------
// DPP wave-64 reductions: VALU-only. Result lands in lane 63.
// ---------------------------------------------------------------------------
template<int CTRL, int RM>
__device__ __forceinline__ float dpp_sum_step(float v) {
    int t = __builtin_amdgcn_update_dpp(0, __float_as_int(v), CTRL, RM, 0xf, true);
    return v + __int_as_float(t);
}
template<int CTRL, int RM>
__device__ __forceinline__ float dpp_max_step(float v) {
    int t = __builtin_amdgcn_update_dpp(__float_as_int(v), __float_as_int(v), CTRL, RM, 0xf, false);
    return fmaxf(v, __int_as_float(t));
}
__device__ __forceinline__ float wave_sum64(float x) {
    x = dpp_sum_step<0x111, 0xf>(x);   // row_shr:1
    x = dpp_sum_step<0x112, 0xf>(x);   // row_shr:2
    x = dpp_sum_step<0x114, 0xf>(x);   // row_shr:4
    x = dpp_sum_step<0x118, 0xf>(x);   // row_shr:8
    x = dpp_sum_step<0x142, 0xa>(x);   // row_bcast:15 -> rows 1,3
    x = dpp_sum_step<0x143, 0xc>(x);   // row_bcast:31 -> rows 2,3
    return x;
}
__device__ __forceinline__ float wave_max64(float x) {
    x = dpp_max_step<0x111, 0xf>(x);
    x = dpp_max_step<0x112, 0xf>(x);
    x = dpp_max_step<0x114, 0xf>(x);
    x = dpp_max_step<0x118, 0xf>(x);
    x = dpp_max_step<0x142, 0xa>(x);
    x = dpp_max_step<0x143, 0xc>(x);
    return x;
}
__device__ __forceinline__ float bcast_lane63(float x) {
    return __int_as_float(__builtin_amdgcn_readlane(__float_as_int(x), 63));
}

// ---------------------------------------------------------------------------
// Bilinear sample, zero padding, absolute pixel coords (matches reference).
// ---------------------------------------------------------------------------
__device__ __forceinline__ float bilin32(const float* __restrict__ img, float px, float py) {
    float x0f = floorf(px), y0f = floorf(py);
    float wx = px - x0f, wy = py - y0f;
    bool vx0 = (x0f >= 0.f) && (x0f <= 31.f);
    bool vx1 = (x0f >= -1.f) && (x0f <= 30.f);
    bool vy0 = (y0f >= 0.f) && (y0f <= 31.f);
    bool vy1 = (y0f >= -1.f) && (y0f <= 30.f);
    int ix0 = (int)fminf(fmaxf(x0f, 0.f), 31.f);
    int iy0 = (int)fminf(fmaxf(y0f, 0.f), 31.f);
    int ix1 = (int)fminf(fmaxf(x0f + 1.f, 0.f), 31.f);
    int iy1 = (int)fminf(fmaxf(y0f + 1.f, 0.f), 31.f);
    float w00 = (1.f - wx) * (1.f - wy) * ((vx0 && vy0) ? 1.f : 0.f);
    float w01 = wx * (1.f - wy) * ((vx1 && vy0) ? 1.f : 0.f);
    float w10 = (1.f - wx) * wy * ((vx0 && vy1) ? 1.f : 0.f);
    float w11 = wx * wy * ((vx1 && vy1) ? 1.f : 0.f);
    return w00 * img[iy0 * 32 + ix0] + w01 * img[iy0 * 32 + ix1] +
           w10 * img[iy1 * 32 + ix0] + w11 * img[iy1 * 32 + ix1];
}

__device__ __forceinline__ float2 comp_flow(const float* __restrict__ fa,
                                            const float* __restrict__ fb, int pix) {
    int y = pix >> 5, x = pix & 31;
    float fx = fa[pix], fy = fa[HW + pix];
    float px = (float)x + fx, py = (float)y + fy;
    float2 r;
    r.x = fx + bilin32(fb, px, py);
    r.y = fy + bilin32(fb + HW, px, py);
    return r;
}

// ---------------------------------------------------------------------------
// Prep kernel: sections by blockIdx.x (grid 2336).
//  [0,192)     xpad: x -> x_pad bf16 [34*34][192]
//  [192,672)   build_extra, 4 channels/thread (shared bilinear coords)
//  [672,688)   flow_cn2 / flow_n2c fp32
//  [688,704)   border zeroing of the 9 padded bf16 buffers
//  [704,2336)  wxform: all 12 weight tensors -> bf16 MFMA fragment order
// ---------------------------------------------------------------------------
struct WD { const float* src; int cout, Cin, nCb, wbase, beg; };
struct PrepP {
    const float *x, *f1, *f2, *ff1, *ff2;
    float *fcn2, *fn2c;
    unsigned short *x_pad, *extra_pad, *wgt;
    WD wd[12];
};

__global__ __launch_bounds__(256) void prep_k(PrepP P) {
    __shared__ float wlds[16 * 288];
    const int b = blockIdx.x, tid = threadIdx.x;
    if (b < 192) {
        int idx = b * 256 + tid;                 // < 1024*48
        int pix = idx / 48, c4 = idx - pix * 48;
        int y = pix >> 5, xx = pix & 31;
        int c0 = c4 * 4;
        ushort4 s;
        s.x = f2bf(P.x[(size_t)(c0 + 0) * HW + pix]);
        s.y = f2bf(P.x[(size_t)(c0 + 1) * HW + pix]);
        s.z = f2bf(P.x[(size_t)(c0 + 2) * HW + pix]);
        s.w = f2bf(P.x[(size_t)(c0 + 3) * HW + pix]);
        *(ushort4*)(&P.x_pad[(size_t)((y + 1) * 34 + xx + 1) * 192 + c0]) = s;
    } else if (b < 672) {
        int idx = (b - 192) * 256 + tid;         // < 1024*120
        int pix = idx / 120, c4 = idx - pix * 120;
        int y = pix >> 5, xx = pix & 31;
        int c0 = c4 * 4;
        float va[4];
        if (c0 < 64) {
#pragma unroll
            for (int k = 0; k < 4; ++k) va[k] = P.x[(size_t)(c0 + k) * HW + pix];
        } else if (c0 < 448) {
            int grp = (c0 - 64) >> 6;
            int c = (c0 - 64) & 63;
            const float* src; float fx, fy;
            if (grp == 0)      { src = P.x + 64 * HW;  fx = P.f1[pix];  fy = P.f1[HW + pix]; }
            else if (grp == 1) { src = P.x + 128 * HW; float2 r = comp_flow(P.f1, P.f2, pix);  fx = r.x; fy = r.y; }
            else if (grp == 2) { src = P.x;            fx = P.ff1[pix]; fy = P.ff1[HW + pix]; }
            else if (grp == 3) { src = P.x + 128 * HW; fx = P.f2[pix];  fy = P.f2[HW + pix]; }
            else if (grp == 4) { src = P.x + 64 * HW;  fx = P.ff2[pix]; fy = P.ff2[HW + pix]; }
            else               { src = P.x;            float2 r = comp_flow(P.ff2, P.ff1, pix); fx = r.x; fy = r.y; }
            float px = (float)xx + fx, py = (float)y + fy;
            float x0f = floorf(px), y0f = floorf(py);
            float wx = px - x0f, wy = py - y0f;
            bool vx0 = (x0f >= 0.f) && (x0f <= 31.f);
            bool vx1 = (x0f >= -1.f) && (x0f <= 30.f);
            bool vy0 = (y0f >= 0.f) && (y0f <= 31.f);
            bool vy1 = (y0f >= -1.f) && (y0f <= 30.f);
            int ix0 = (int)fminf(fmaxf(x0f, 0.f), 31.f);
            int iy0 = (int)fminf(fmaxf(y0f, 0.f), 31.f);
            int ix1 = (int)fminf(fmaxf(x0f + 1.f, 0.f), 31.f);
            int iy1 = (int)fminf(fmaxf(y0f + 1.f, 0.f), 31.f);
            float w00 = (1.f - wx) * (1.f - wy) * ((vx0 && vy0) ? 1.f : 0.f);
            float w01 = wx * (1.f - wy) * ((vx1 && vy0) ? 1.f : 0.f);
            float w10 = (1.f - wx) * wy * ((vx0 && vy1) ? 1.f : 0.f);
            float w11 = wx * wy * ((vx1 && vy1) ? 1.f : 0.f);
            int p00 = iy0 * 32 + ix0, p01 = iy0 * 32 + ix1;
            int p10 = iy1 * 32 + ix0, p11 = iy1 * 32 + ix1;
            const float* im = src + (size_t)c * HW;
#pragma unroll
            for (int k = 0; k < 4; ++k) {
                va[k] = w00 * im[p00] + w01 * im[p01] + w10 * im[p10] + w11 * im[p11];
                im += HW;
            }
        } else {
#pragma unroll
            for (int k = 0; k < 4; ++k) {
                int ch = c0 + k;
                float v = 0.f;
                if (ch < 460) {
                    int fc = ch - 448;
                    int which = fc >> 1, comp = fc & 1;
                    if (which == 0)      v = P.f1[comp * HW + pix];
                    else if (which == 1) { float2 r = comp_flow(P.f1, P.f2, pix);  v = comp ? r.y : r.x; }
                    else if (which == 2) v = P.ff1[comp * HW + pix];
                    else if (which == 3) v = P.f2[comp * HW + pix];
                    else if (which == 4) v = P.ff2[comp * HW + pix];
                    else                 { float2 r = comp_flow(P.ff2, P.ff1, pix); v = comp ? r.y : r.x; }
                }
                va[k] = v;
            }
        }
        ushort4 s;
        s.x = f2bf(va[0]); s.y = f2bf(va[1]); s.z = f2bf(va[2]); s.w = f2bf(va[3]);
        *(ushort4*)(&P.extra_pad[(size_t)((y + 1) * 34 + xx + 1) * 480 + c0]) = s;
    } else if (b < 688) {
        int idx = (b - 672) * 256 + tid;
        if (idx < 1024) {
            float2 r = comp_flow(P.f1, P.f2, idx);
            P.fcn2[idx] = r.x; P.fcn2[HW + idx] = r.y;
        } else if (idx < 2048) {
            int pix = idx - 1024;
            float2 r = comp_flow(P.ff2, P.ff1, pix);
            P.fn2c[pix] = r.x; P.fn2c[HW + pix] = r.y;
        }
    } else if (b < 704) {
        const int chans[9] = {192, 192, 480, 64, 64, 64, 64, 192, 192};
        size_t offs[9]; size_t a = 0;
        for (int i = 0; i < 9; ++i) { offs[i] = a; a += (size_t)1156 * chans[i]; }
        int bb = b - 688;
        for (int item = bb; item < 9 * 132; item += 16) {
            int buf = item / 132, i = item - buf * 132;
            int py, px;
            if (i < 34) { py = 0; px = i; }
            else if (i < 68) { py = 33; px = i - 34; }
            else { int j = i - 68; py = 1 + (j >> 1); px = (j & 1) ? 33 : 0; }
            int C = chans[buf];
            unsigned short* p = P.x_pad + offs[buf] + (size_t)(py * 34 + px) * C;
            for (int c = tid; c < C; c += 256) p[c] = 0;
        }
    } else {
        int blk = b - 704;                       // < 1632
        int di = 0;
        while (di < 11 && blk >= P.wd[di + 1].beg) ++di;
        WD w = P.wd[di];
        int local = blk - w.beg;
        int co16 = local / w.nCb, cb = local - co16 * w.nCb;
        int cr0 = co16 * 16, ci0 = cb * 32;
        for (int i = tid; i < 16 * 288; i += 256) {
            int cr = i / 288, o = i - cr * 288;
            int crg = cr0 + cr, ci = ci0 + o / 9;
            float v = (crg < w.cout && ci < w.Cin)
                ? w.src[((size_t)crg * w.Cin + ci0) * 9 + o] : 0.f;
            wlds[i] = v;
        }
        __syncthreads();
        for (int e = tid; e < 9 * 512; e += 256) {
            int t = e >> 9, idx = e & 511;
            int j = idx & 7, lane = idx >> 3, q = lane >> 4, mm = lane & 15;
            P.wgt[((size_t)w.wbase + ((size_t)co16 * 9 + t) * w.nCb + cb) * 512 + idx] =
                f2bf(wlds[mm * 288 + (q * 8 + j) * 9 + t]);
        }
    }
}

// ---------------------------------------------------------------------------
// MFMA 3x3 conv, multi-descriptor, register-prefetch double-buffered.
// ---------------------------------------------------------------------------
struct CDesc {
    const unsigned short* in;
    const unsigned short* wgt;
    const float* bias;
    void* out;
    const float* residual;
    int Cpad, nCb, Cout, mode, cmod, relu, Mblocks;
};
struct CParam { CDesc d[4]; };

template<int PIXROWS, int COBLK>
__global__ __launch_bounds__(256) void conv_mfma_k(CParam P) {
    constexpr int TROWS = PIXROWS + 2;
    constexpr int TC = TROWS * 34 * 4;
    constexpr int ITRIPS = (TC + 255) / 256;
    constexpr int NTY = PIXROWS / 4;
    constexpr int NACC = NTY * 2;
    constexpr int MT = COBLK / 16;
    constexpr int WN = MT * 9 * 64;
    constexpr int WTRIPS = (WN + 255) / 256;
    __shared__ unsigned short blds[TROWS * 34 * 40];
    __shared__ unsigned short wlds[MT * 9 * 512];

    int bx = blockIdx.x;
    int di = 0;
    while (bx >= P.d[di].Mblocks) { bx -= P.d[di].Mblocks; ++di; }
    const CDesc d = P.d[di];

    const int tid = threadIdx.x;
    const int w = tid >> 6, lane = tid & 63;
    const int lq = lane >> 4, ln = lane & 15;
    const int co0 = bx * COBLK;
    const int by = blockIdx.y, y0 = by * PIXROWS;
    const unsigned short* __restrict__ in = d.in;
    const unsigned short* __restrict__ wg = d.wgt;
    const int Cpad = d.Cpad, nCb = d.nCb;

    floatx4 acc[MT][NACC];
#pragma unroll
    for (int mt = 0; mt < MT; ++mt)
#pragma unroll
        for (int nt = 0; nt < NACC; ++nt)
            acc[mt][nt] = (floatx4){0.f, 0.f, 0.f, 0.f};

    bf16x8 ireg[ITRIPS];
    bf16x8 wreg[WTRIPS];

    auto load_regs = [&](int cb) {
        const int ci0 = cb << 5;
#pragma unroll
        for (int k = 0; k < ITRIPS; ++k) {
            int i = tid + k * 256;
            if (i < TC) {
                int r = i / 136, rem = i - r * 136, c = rem >> 2, g = rem & 3;
                ireg[k] = *(const bf16x8*)(in + (size_t)((y0 + r) * 34 + c) * Cpad + ci0 + g * 8);
            }
        }
#pragma unroll
        for (int k = 0; k < WTRIPS; ++k) {
            int i = tid + k * 256;
            if (i < WN) {
                int chunk = i >> 6, l16 = i & 63;
                int mt = chunk / 9, t = chunk - mt * 9;
                wreg[k] = *(const bf16x8*)(wg + ((size_t)(((co0 >> 4) + mt) * 9 + t) * nCb + cb) * 512 + l16 * 8);
            }
        }
    };

    load_regs(0);

    for (int cb = 0; cb < nCb; ++cb) {
        __syncthreads();
#pragma unroll
        for (int k = 0; k < ITRIPS; ++k) {
            int i = tid + k * 256;
            if (i < TC) {
                int r = i / 136, rem = i - r * 136, c = rem >> 2, g = rem & 3;
                *(bf16x8*)(&blds[(r * 34 + c) * 40 + g * 8]) = ireg[k];
            }
        }
#pragma unroll
        for (int k = 0; k < WTRIPS; ++k) {
            int i = tid + k * 256;
            if (i < WN) {
                int chunk = i >> 6, l16 = i & 63;
                *(bf16x8*)(&wlds[chunk * 512 + l16 * 8]) = wreg[k];
            }
        }
        __syncthreads();
        if (cb + 1 < nCb) load_regs(cb + 1);
        for (int t = 0; t < 9; ++t) {
            const int dy = t / 3, dx = t - dy * 3;
            bf16x8 bfr[NACC];
#pragma unroll
            for (int ty = 0; ty < NTY; ++ty)
#pragma unroll
                for (int tx = 0; tx < 2; ++tx) {
                    int yy = w * NTY + ty + dy;
                    int xx = tx * 16 + ln + dx;
                    bfr[ty * 2 + tx] = *(const bf16x8*)(&blds[(yy * 34 + xx) * 40 + lq * 8]);
                }
#pragma unroll
            for (int mt = 0; mt < MT; ++mt) {
                bf16x8 afr = *(const bf16x8*)(&wlds[(mt * 9 + t) * 512 + lane * 8]);
#pragma unroll
                for (int nt = 0; nt < NACC; ++nt)
                    acc[mt][nt] = __builtin_amdgcn_mfma_f32_16x16x32_bf16(afr, bfr[nt], acc[mt][nt], 0, 0, 0);
            }
        }
    }

#pragma unroll
    for (int mt = 0; mt < MT; ++mt) {
        const int co = co0 + mt * 16 + lq * 4;
        if (co >= d.Cout) continue;
        float bv[4];
#pragma unroll
        for (int r = 0; r < 4; ++r) bv[r] = d.bias[co + r];
#pragma unroll
        for (int nt = 0; nt < NACC; ++nt) {
            const int ty = nt >> 1, tx = nt & 1;
            const int pix = by * (PIXROWS * 32) + (w * NTY + ty) * 32 + tx * 16 + ln;
            float v[4];
#pragma unroll
            for (int r = 0; r < 4; ++r) {
                float vv = acc[mt][nt][r] + bv[r];
                if (d.relu) vv = (vv >= 0.f) ? vv : 0.1f * vv;
                v[r] = vv;
            }
            if (d.mode == 0) {
                float* o = (float*)d.out;
#pragma unroll
                for (int r = 0; r < 4; ++r) {
                    float vv = v[r];
                    if (d.residual) vv += d.residual[(size_t)(co + r) * HW + pix];
                    o[(size_t)(co + r) * HW + pix] = vv;
                }
            } else if (d.mode == 1) {
                int fq = co / d.cmod, cc = co - fq * d.cmod;
                *(float4*)((float*)d.out + ((size_t)fq * HW + pix) * d.cmod + cc) =
                    make_float4(v[0], v[1], v[2], v[3]);
            } else if (d.mode == 2) {
                int fq = co / d.cmod, cc = co - fq * d.cmod;
                ushort4 s4;
                s4.x = f2bf(v[0]); s4.y = f2bf(v[1]); s4.z = f2bf(v[2]); s4.w = f2bf(v[3]);
                *(ushort4*)((unsigned short*)d.out + ((size_t)fq * HW + pix) * d.cmod + cc) = s4;
            } else {
                int yy = (pix >> 5) + 1, xx = (pix & 31) + 1;
                ushort4 s4;
                s4.x = f2bf(v[0]); s4.y = f2bf(v[1]); s4.z = f2bf(v[2]); s4.w = f2bf(v[3]);
                *(ushort4*)((unsigned short*)d.out + (size_t)(yy * 34 + xx) * d.cmod + co) = s4;
            }
        }
    }
}

// ---------------------------------------------------------------------------
// L4 conv (so3 + aw3): weight-dominant layer (10.9 MB weights, Cin=64).
// Each block owns 16 output channels for the WHOLE image: both cb weight
// slices loaded to LDS exactly once, then 4 y-strips x 2 cb with register-
// prefetched input staging. LDS 45632 B -> 3 blocks/CU. Grid 594.
// ---------------------------------------------------------------------------
struct L4Desc {
    const unsigned short* in;
    const unsigned short* wgt;
    const float* bias;
    void* out;
    int mode, cmod, Mblocks;   // mode 1 = f32 strided, 2 = bf16 strided
};
struct L4Param { L4Desc d[2]; };

__global__ __launch_bounds__(256) void conv_l4_k(L4Param P) {
    __shared__ unsigned short blds[10 * 34 * 40];   // 27200 B (one cb slice)
    __shared__ unsigned short wlds[9 * 2 * 512];    // 18432 B (both cb slices)

    int bx = blockIdx.x;
    int di = 0;
    if (bx >= P.d[0].Mblocks) { bx -= P.d[0].Mblocks; di = 1; }
    const L4Desc d = P.d[di];

    const int tid = threadIdx.x;
    const int w = tid >> 6, lane = tid & 63;
    const int lq = lane >> 4, ln = lane & 15;
    const int co0 = bx * 16;
    const unsigned short* __restrict__ in = d.in;
    const unsigned short* __restrict__ wg = d.wgt;

    bf16x8 wreg[5];
#pragma unroll
    for (int k = 0; k < 5; ++k) {
        int i = tid + k * 256;
        if (i < 1152) {
            int chunk = i >> 6, l16 = i & 63;
            int t = chunk >> 1, cb = chunk & 1;
            wreg[k] = *(const bf16x8*)(wg + (((size_t)bx * 9 + t) * 2 + cb) * 512 + l16 * 8);
        }
    }

    bf16x8 ireg[6];
    auto load_in = [&](int y0, int cb) {
        const int ci0 = cb << 5;
#pragma unroll
        for (int k = 0; k < 6; ++k) {
            int i = tid + k * 256;
            if (i < 1360) {
                int r = i / 136, rem = i - r * 136, c = rem >> 2, g = rem & 3;
                ireg[k] = *(const bf16x8*)(in + (size_t)((y0 + r) * 34 + c) * 64 + ci0 + g * 8);
            }
        }
    };
    load_in(0, 0);

#pragma unroll
    for (int k = 0; k < 5; ++k) {
        int i = tid + k * 256;
        if (i < 1152) *(bf16x8*)(&wlds[(i >> 6) * 512 + (i & 63) * 8]) = wreg[k];
    }

    floatx4 acc[4];
#pragma unroll
    for (int nt = 0; nt < 4; ++nt) acc[nt] = (floatx4){0.f, 0.f, 0.f, 0.f};

    for (int p = 0; p < 8; ++p) {
        const int y = p >> 1, cb = p & 1;
        __syncthreads();
#pragma unroll
        for (int k = 0; k < 6; ++k) {
            int i = tid + k * 256;
            if (i < 1360) {
                int r = i / 136, rem = i - r * 136, c = rem >> 2, g = rem & 3;
                *(bf16x8*)(&blds[(r * 34 + c) * 40 + g * 8]) = ireg[k];
            }
        }
        __syncthreads();
        if (p < 7) { int pn = p + 1; load_in((pn >> 1) * 8, pn & 1); }
#pragma unroll
        for (int t = 0; t < 9; ++t) {
            const int dy = t / 3, dx = t - dy * 3;
            bf16x8 afr = *(const bf16x8*)(&wlds[(t * 2 + cb) * 512 + lane * 8]);
#pragma unroll
            for (int ty = 0; ty < 2; ++ty)
#pragma unroll
                for (int tx = 0; tx < 2; ++tx) {
                    int yy = w * 2 + ty + dy;
                    int xx = tx * 16 + ln + dx;
                    bf16x8 bfr = *(const bf16x8*)(&blds[(yy * 34 + xx) * 40 + lq * 8]);
                    acc[ty * 2 + tx] =
                        __builtin_amdgcn_mfma_f32_16x16x32_bf16(afr, bfr, acc[ty * 2 + tx], 0, 0, 0);
                }
        }
        if (cb == 1) {
            const int co = co0 + lq * 4;
            float bv[4];
#pragma unroll
            for (int r2 = 0; r2 < 4; ++r2) bv[r2] = d.bias[co + r2];
            int fq = co / d.cmod, cc = co - fq * d.cmod;
#pragma unroll
            for (int nt = 0; nt < 4; ++nt) {
                const int ty = nt >> 1, tx = nt & 1;
                const int pix = y * 256 + (w * 2 + ty) * 32 + tx * 16 + ln;
                float v0 = acc[nt][0] + bv[0], v1 = acc[nt][1] + bv[1];
                float v2 = acc[nt][2] + bv[2], v3 = acc[nt][3] + bv[3];
                if (d.mode == 1) {
                    *(float4*)((float*)d.out + ((size_t)fq * HW + pix) * d.cmod + cc) =
                        make_float4(v0, v1, v2, v3);
                } else {
                    ushort4 s4;
                    s4.x = f2bf(v0); s4.y = f2bf(v1); s4.z = f2bf(v2); s4.w = f2bf(v3);
                    *(ushort4*)((unsigned short*)d.out + ((size_t)fq * HW + pix) * d.cmod + cc) = s4;
                }
                acc[nt] = (floatx4){0.f, 0.f, 0.f, 0.f};
            }
        }
    }
}

// ---------------------------------------------------------------------------
// Deformable attention, no-LDS-value variant. Grid 1536 (was 768): each block
// now handles 16 queries (r<4) instead of 32 — occupancy was GRID-limited at
// 3 blocks/CU (12 waves); 1536 blocks -> 6 blocks/CU (24 waves) since LDS is
// only 3.4 KB and VGPR ~66 allows 7 waves/SIMD. Wave-level code unchanged.
// DPP reductions; lane 63 stores. value_b layout [l][m][pix][8ch]: level
// stride 65536 shorts, head m*8192.
// ---------------------------------------------------------------------------
__global__ __launch_bounds__(256) void deform_attn_k(
    const unsigned short* __restrict__ value_b, const float* __restrict__ so_t,
    const unsigned short* __restrict__ aw_t,
    const float* __restrict__ flow_1, const float* __restrict__ flow_2,
    const float* __restrict__ flip_flow_1, const float* __restrict__ flip_flow_2,
    const float* __restrict__ flow_cn2, const float* __restrict__ flow_n2c,
    unsigned short* __restrict__ attn_pad)
{
    __shared__ unsigned short pwlds[4][432];
    const int tid = threadIdx.x;
    const int wav = tid >> 6, lane = tid & 63;
    const int m = blockIdx.x & 7, qc = blockIdx.x >> 3;   // qc in [0,192)

    const int pp = lane & 15, gq = lane >> 4;
    const int gdy = (gq >> 1) * 2 - 1;
    const int gdx = (gq & 1) * 2 - 1;
    const bool selx = (gq & 1);
    const bool sely = (gq >> 1);

    // per-head base of the value image ([l][m][pix][8]: head offset m*8192)
    const unsigned short* __restrict__ vm = value_b + (size_t)m * 8192;

    for (int r = 0; r < 4; ++r) {
        const int q = qc * 16 + r * 4 + wav;
        const int f = q >> 10, pix = q & 1023;
        const int y = pix >> 5, x = pix & 31;

        // logits for this query
        float av[6];
        {
            const unsigned short* awp = aw_t + (size_t)q * 2592 + m * 324;
#pragma unroll
            for (int it = 0; it < 6; ++it) {
                int j = lane + it * 64;
                av[it] = (j < 324) ? bf2f(awp[j]) : -1e30f;
            }
        }

        float vmax = -1e30f;
#pragma unroll
        for (int it = 0; it < 6; ++it) vmax = fmaxf(vmax, av[it]);
        vmax = bcast_lane63(wave_max64(vmax));
        float ssum = 0.f;
#pragma unroll
        for (int it = 0; it < 6; ++it) {
            int j = lane + it * 64;
            float e = (j < 324) ? __expf(av[it] - vmax) : 0.f;
            av[it] = e;
            ssum += e;
        }
        ssum = bcast_lane63(wave_sum64(ssum));
        const float inv = 1.f / ssum;

#pragma unroll
        for (int it = 0; it < 6; ++it) {
            int j = lane + it * 64;
            if (j < 324) {
                int pi = j / 9, k = j - pi * 9;
                pwlds[wav][pi * 12 + k] = f2bf(av[it] * inv);
            }
        }

        const float* sop = so_t + (size_t)q * 576 + m * 72;

        float flx0 = 0.f, fly0 = 0.f, flx1 = 0.f, fly1 = 0.f, flx2 = 0.f, fly2 = 0.f;
        if (f == 0) {
            flx1 = flow_1[pix];      fly1 = flow_1[HW + pix];
            flx2 = flow_cn2[pix];    fly2 = flow_cn2[HW + pix];
        } else if (f == 1) {
            flx0 = flip_flow_1[pix]; fly0 = flip_flow_1[HW + pix];
            flx2 = flow_2[pix];      fly2 = flow_2[HW + pix];
        } else {
            flx0 = flow_n2c[pix];    fly0 = flow_n2c[HW + pix];
            flx1 = flip_flow_2[pix]; fly1 = flip_flow_2[HW + pix];
        }

        float acc[8];
#pragma unroll
        for (int dd = 0; dd < 8; ++dd) acc[dd] = 0.f;

#pragma unroll
        for (int pt = 0; pt < 3; ++pt) {
            int pi = pt * 16 + pp;
            if (pi < 36) {
                int l = pi / 12;
                // so-offset loaded here (L1-hot row)
                float2 so2 = *(const float2*)(sop + pi * 2);
                float fx = (l == 0) ? flx0 : (l == 1) ? flx1 : flx2;
                float fy = (l == 0) ? fly0 : (l == 1) ? fly1 : fly2;
                float bxf = (float)x + so2.x + fx;
                float byf = (float)y + so2.y + fy;
                float x0f = floorf(bxf), y0f = floorf(byf);
                float wx = bxf - x0f, wy = byf - y0f;
                float ax = 1.f - wx, ay = 1.f - wy;
                int x0 = (int)fminf(fmaxf(x0f, -2.f), 34.f);
                int y0 = (int)fminf(fmaxf(y0f, -2.f), 34.f);

                const unsigned short* pr = &pwlds[wav][pi * 12];
                uint2 pv0 = *(const uint2*)(pr);
                uint2 pv1 = *(const uint2*)(pr + 4);
                float a0 = bflo(pv0.x), a1 = bfhi(pv0.x), a2 = bflo(pv0.y);
                float a3 = bfhi(pv0.y), a4 = bflo(pv1.x), a5 = bfhi(pv1.x);
                float a6 = bflo(pv1.y), a7 = bfhi(pv1.y), a8 = bf2f(pr[8]);

                float bs0a, bs0b, bs1a, bs1b, bs2a, bs2b;
                {
                    float b0, b1, b2, b3;
                    b0 = a0 * ax; b1 = a0 * wx + a3 * ax; b2 = a3 * wx + a6 * ax; b3 = a6 * wx;
                    bs0a = selx ? b2 : b0; bs0b = selx ? b3 : b1;
                    b0 = a1 * ax; b1 = a1 * wx + a4 * ax; b2 = a4 * wx + a7 * ax; b3 = a7 * wx;
                    bs1a = selx ? b2 : b0; bs1b = selx ? b3 : b1;
                    b0 = a2 * ax; b1 = a2 * wx + a5 * ax; b2 = a5 * wx + a8 * ax; b3 = a8 * wx;
                    bs2a = selx ? b2 : b0; bs2b = selx ? b3 : b1;
                }
                float c00, c01, c10, c11;
                {
                    float c0 = bs0a * ay, c1 = bs0a * wy + bs1a * ay;
                    float c2 = bs1a * wy + bs2a * ay, c3 = bs2a * wy;
                    c00 = sely ? c2 : c0; c10 = sely ? c3 : c1;
                    c0 = bs0b * ay; c1 = bs0b * wy + bs1b * ay;
                    c2 = bs1b * wy + bs2b * ay; c3 = bs2b * wy;
                    c01 = sely ? c2 : c0; c11 = sely ? c3 : c1;
                }
                float cg[2][2] = {{c00, c01}, {c10, c11}};
                const unsigned short* __restrict__ vl = vm + (size_t)l * 65536;
#pragma unroll
                for (int sy = 0; sy < 2; ++sy) {
#pragma unroll
                    for (int sx = 0; sx < 2; ++sx) {
                        int dy = gdy + sy, dx = gdx + sx;
                        float pyf = y0f + (float)dy, pxf = x0f + (float)dx;
                        bool v = (pxf >= 0.f) && (pxf <= 31.f) && (pyf >= 0.f) && (pyf <= 31.f);
                        int px = min(max(x0 + dx, 0), 31);
                        int py = min(max(y0 + dy, 0), 31);
                        float c = cg[sy][sx] * (v ? 1.f : 0.f);
                        uint4 vv = *(const uint4*)(vl + (size_t)(py * 32 + px) * 8);
                        acc[0] = fmaf(c, bflo(vv.x), acc[0]);
                        acc[1] = fmaf(c, bfhi(vv.x), acc[1]);
                        acc[2] = fmaf(c, bflo(vv.y), acc[2]);
                        acc[3] = fmaf(c, bfhi(vv.y), acc[3]);
                        acc[4] = fmaf(c, bflo(vv.z), acc[4]);
                        acc[5] = fmaf(c, bfhi(vv.z), acc[5]);
                        acc[6] = fmaf(c, bflo(vv.w), acc[6]);
                        acc[7] = fmaf(c, bfhi(vv.w), acc[7]);
                    }
                }
            }
        }

#pragma unroll
        for (int dd = 0; dd < 8; ++dd) acc[dd] = wave_sum64(acc[dd]);
        if (lane == 63) {
            unsigned short* op = attn_pad + (size_t)((y + 1) * 34 + x + 1) * 192 + f * 64 + m * 8;
            ushort4 s0, s1;
            s0.x = f2bf(acc[0]); s0.y = f2bf(acc[1]); s0.z = f2bf(acc[2]); s0.w = f2bf(acc[3]);
            s1.x = f2bf(acc[4]); s1.y = f2bf(acc[5]); s1.z = f2bf(acc[6]); s1.w = f2bf(acc[7]);
            *(ushort4*)(op) = s0;
            *(ushort4*)(op + 4) = s1;
        }
    }
}

// ---------------------------------------------------------------------------
extern "C" void kernel_launch(void* const* d_in, const int* in_sizes, int n_in,
                              void* d_out, int out_size, void* d_ws, size_t ws_size,
                              hipStream_t stream) {
    const float* x      = (const float*)d_in[0];
    const float* flow_1 = (const float*)d_in[1];
    const float* flow_2 = (const float*)d_in[2];
    const float* flip_1 = (const float*)d_in[3];
    const float* flip_2 = (const float*)d_in[4];
    const float* vp0_w = (const float*)d_in[5];  const float* vp0_b = (const float*)d_in[6];
    const float* vp1_w = (const float*)d_in[7];  const float* vp1_b = (const float*)d_in[8];
    const float* so0_w = (const float*)d_in[9];  const float* so0_b = (const float*)d_in[10];
    const float* so1_w = (const float*)d_in[11]; const float* so1_b = (const float*)d_in[12];
    const float* so2_w = (const float*)d_in[13]; const float* so2_b = (const float*)d_in[14];
    const float* so3_w = (const float*)d_in[15]; const float* so3_b = (const float*)d_in[16];
    const float* aw0_w = (const float*)d_in[17]; const float* aw0_b = (const float*)d_in[18];
    const float* aw1_w = (const float*)d_in[19]; const float* aw1_b = (const float*)d_in[20];
    const float* aw2_w = (const float*)d_in[21]; const float* aw2_b = (const float*)d_in[22];
    const float* aw3_w = (const float*)d_in[23]; const float* aw3_b = (const float*)d_in[24];
    const float* op0_w = (const float*)d_in[25]; const float* op0_b = (const float*)d_in[26];
    const float* op1_w = (const float*)d_in[27]; const float* op1_b = (const float*)d_in[28];
    float* out = (float*)d_out;
    (void)ws_size; (void)in_sizes; (void)n_in; (void)out_size;

    // ---- workspace layout ----
    float* fws = (float*)d_ws;
    float* flow_cn2 = fws;
    float* flow_n2c = flow_cn2 + 2048;
    unsigned short* value_b = (unsigned short*)(flow_n2c + 2048);
    float* so_t     = (float*)(value_b + 196608);
    unsigned short* uws = (unsigned short*)(so_t + 1769472);
    unsigned short* x_pad     = uws;
    unsigned short* vp0h      = x_pad + 1156 * 192;
    unsigned short* extra_pad = vp0h + 1156 * 192;
    unsigned short* s1 = extra_pad + 1156 * 480;
    unsigned short* a1 = s1 + 1156 * 64;
    unsigned short* s2 = a1 + 1156 * 64;
    unsigned short* a2 = s2 + 1156 * 64;
    unsigned short* attn_pad = a2 + 1156 * 64;
    unsigned short* op0h     = attn_pad + 1156 * 192;
    unsigned short* aw_t = op0h + 1156 * 192;
    unsigned short* wgt  = aw_t + (size_t)3072 * 2592;

    // ---- 1. prep ----
    PrepP pp;
    pp.x = x; pp.f1 = flow_1; pp.f2 = flow_2; pp.ff1 = flip_1; pp.ff2 = flip_2;
    pp.fcn2 = flow_cn2; pp.fn2c = flow_n2c;
    pp.x_pad = x_pad; pp.extra_pad = extra_pad; pp.wgt = wgt;
    pp.wd[0]  = {vp0_w, 192, 192, 6,     0,    0};
    pp.wd[1]  = {vp1_w, 192, 192, 6,   648,   72};
    pp.wd[2]  = {so0_w,  64, 460, 15, 1296,  144};
    pp.wd[3]  = {aw0_w,  64, 460, 15, 1836,  204};
    pp.wd[4]  = {so1_w,  64,  64, 2,  2376,  264};
    pp.wd[5]  = {aw1_w,  64,  64, 2,  2448,  272};
    pp.wd[6]  = {so2_w,  64,  64, 2,  2520,  280};
    pp.wd[7]  = {aw2_w,  64,  64, 2,  2592,  288};
    pp.wd[8]  = {so3_w, 1728, 64, 2,  2664,  296};
    pp.wd[9]  = {aw3_w, 7776, 64, 2,  4608,  512};
    pp.wd[10] = {op0_w, 192, 192, 6, 13392, 1488};
    pp.wd[11] = {op1_w, 192, 192, 6, 14040, 1560};
    prep_k<<<2336, 256, 0, stream>>>(pp);

    const int BIG = 1 << 30;
    CDesc nul = {nullptr, nullptr, nullptr, nullptr, nullptr, 0, 0, 0, 0, 0, 0, BIG};

    // ---- 2. L1: vp0 + so0 + aw0 ----
    {
        CParam cp;
        cp.d[0] = {x_pad,     wgt + (size_t)0 * 512,    vp0_b, vp0h, nullptr, 192, 6,  192, 3, 192, 1, 12};
        cp.d[1] = {extra_pad, wgt + (size_t)1296 * 512, so0_b, s1,   nullptr, 480, 15, 64,  3, 64,  1, 4};
        cp.d[2] = {extra_pad, wgt + (size_t)1836 * 512, aw0_b, a1,   nullptr, 480, 15, 64,  3, 64,  1, 4};
        cp.d[3] = nul;
        conv_mfma_k<4, 16><<<dim3(20, 8), 256, 0, stream>>>(cp);
    }
    // ---- 3. L2: vp1 + so1 + aw1 ----
    {
        CParam cp;
        cp.d[0] = {vp0h, wgt + (size_t)648 * 512,  vp1_b, value_b, nullptr, 192, 6, 192, 2, 8,  0, 12};
        cp.d[1] = {s1,   wgt + (size_t)2376 * 512, so1_b, s2,      nullptr, 64,  2, 64,  3, 64, 1, 4};
        cp.d[2] = {a1,   wgt + (size_t)2448 * 512, aw1_b, a2,      nullptr, 64,  2, 64,  3, 64, 1, 4};
        cp.d[3] = nul;
        conv_mfma_k<4, 16><<<dim3(20, 8), 256, 0, stream>>>(cp);
    }
    // ---- 4. L3: so2 + aw2 ----
    {
        CParam cp;
        cp.d[0] = {s2, wgt + (size_t)2520 * 512, so2_b, s1, nullptr, 64, 2, 64, 3, 64, 1, 4};
        cp.d[1] = {a2, wgt + (size_t)2592 * 512, aw2_b, a1, nullptr, 64, 2, 64, 3, 64, 1, 4};
        cp.d[2] = nul; cp.d[3] = nul;
        conv_mfma_k<4, 16><<<dim3(8, 8), 256, 0, stream>>>(cp);
    }
    // ---- 5. L4: so3 + aw3 (dedicated read-once-weights kernel) ----
    {
        L4Param lp;
        lp.d[0] = {s1, wgt + (size_t)2664 * 512, so3_b, so_t, 1, 576,  108};
        lp.d[1] = {a1, wgt + (size_t)4608 * 512, aw3_b, aw_t, 2, 2592, 486};
        conv_l4_k<<<594, 256, 0, stream>>>(lp);
    }

    // ---- 6. deformable attention (no-LDS-value, L2-gather, grid 1536) ----
    deform_attn_k<<<1536, 256, 0, stream>>>(value_b, so_t, aw_t,
                                            flow_1, flow_2, flip_1, flip_2,
                                            flow_cn2, flow_n2c, attn_pad);

    // ---- 7. op0 ----
    {
        CParam cp;
        cp.d[0] = {attn_pad, wgt + (size_t)13392 * 512, op0_b, op0h, nullptr, 192, 6, 192, 3, 192, 1, 12};
        cp.d[1] = nul; cp.d[2] = nul; cp.d[3] = nul;
        conv_mfma_k<4, 16><<<dim3(12, 8), 256, 0, stream>>>(cp);
    }
    // ---- 8. op1 + residual ----
    {
        CParam cp;
        cp.d[0] = {op0h, wgt + (size_t)14040 * 512, op1_b, out, x, 192, 6, 192, 0, 0, 0, 12};
        cp.d[1] = nul; cp.d[2] = nul; cp.d[3] = nul;
        conv_mfma_k<4, 16><<<dim3(12, 8), 256, 0, stream>>>(cp);
    }
}

// Round 13
// 246.095 us; speedup vs baseline: 2.9936x; 1.0403x over previous
//
#include <hip/hip_runtime.h>
#include <math.h>

#define HW 1024

typedef __attribute__((ext_vector_type(8))) short bf16x8;
typedef __attribute__((ext_vector_type(4))) float floatx4;

__device__ __forceinline__ unsigned short f2bf(float f) {
    unsigned u = __float_as_uint(f);
    u += 0x7FFF + ((u >> 16) & 1);
    return (unsigned short)(u >> 16);
}
__device__ __forceinline__ float bf2f(unsigned short u) {
    return __uint_as_float(((unsigned)u) << 16);
}
__device__ __forceinline__ float bflo(unsigned u) { return __uint_as_float(u << 16); }
__device__ __forceinline__ float bfhi(unsigned u) { return __uint_as_float(u & 0xffff0000u); }

// ---------------------------------------------------------------------------
// DPP wave-64 reductions: VALU-only. Result lands in lane 63.
// ---------------------------------------------------------------------------
template<int CTRL, int RM>
__device__ __forceinline__ float dpp_sum_step(float v) {
    int t = __builtin_amdgcn_update_dpp(0, __float_as_int(v), CTRL, RM, 0xf, true);
    return v + __int_as_float(t);
}
template<int CTRL, int RM>
__device__ __forceinline__ float dpp_max_step(float v) {
    int t = __builtin_amdgcn_update_dpp(__float_as_int(v), __float_as_int(v), CTRL, RM, 0xf, false);
    return fmaxf(v, __int_as_float(t));
}
__device__ __forceinline__ float wave_sum64(float x) {
    x = dpp_sum_step<0x111, 0xf>(x);   // row_shr:1
    x = dpp_sum_step<0x112, 0xf>(x);   // row_shr:2
    x = dpp_sum_step<0x114, 0xf>(x);   // row_shr:4
    x = dpp_sum_step<0x118, 0xf>(x);   // row_shr:8
    x = dpp_sum_step<0x142, 0xa>(x);   // row_bcast:15 -> rows 1,3
    x = dpp_sum_step<0x143, 0xc>(x);   // row_bcast:31 -> rows 2,3
    return x;
}
__device__ __forceinline__ float wave_max64(float x) {
    x = dpp_max_step<0x111, 0xf>(x);
    x = dpp_max_step<0x112, 0xf>(x);
    x = dpp_max_step<0x114, 0xf>(x);
    x = dpp_max_step<0x118, 0xf>(x);
    x = dpp_max_step<0x142, 0xa>(x);
    x = dpp_max_step<0x143, 0xc>(x);
    return x;
}
__device__ __forceinline__ float bcast_lane63(float x) {
    return __int_as_float(__builtin_amdgcn_readlane(__float_as_int(x), 63));
}

// ---------------------------------------------------------------------------
// Bilinear sample, zero padding, absolute pixel coords (matches reference).
// ---------------------------------------------------------------------------
__device__ __forceinline__ float bilin32(const float* __restrict__ img, float px, float py) {
    float x0f = floorf(px), y0f = floorf(py);
    float wx = px - x0f, wy = py - y0f;
    bool vx0 = (x0f >= 0.f) && (x0f <= 31.f);
    bool vx1 = (x0f >= -1.f) && (x0f <= 30.f);
    bool vy0 = (y0f >= 0.f) && (y0f <= 31.f);
    bool vy1 = (y0f >= -1.f) && (y0f <= 30.f);
    int ix0 = (int)fminf(fmaxf(x0f, 0.f), 31.f);
    int iy0 = (int)fminf(fmaxf(y0f, 0.f), 31.f);
    int ix1 = (int)fminf(fmaxf(x0f + 1.f, 0.f), 31.f);
    int iy1 = (int)fminf(fmaxf(y0f + 1.f, 0.f), 31.f);
    float w00 = (1.f - wx) * (1.f - wy) * ((vx0 && vy0) ? 1.f : 0.f);
    float w01 = wx * (1.f - wy) * ((vx1 && vy0) ? 1.f : 0.f);
    float w10 = (1.f - wx) * wy * ((vx0 && vy1) ? 1.f : 0.f);
    float w11 = wx * wy * ((vx1 && vy1) ? 1.f : 0.f);
    return w00 * img[iy0 * 32 + ix0] + w01 * img[iy0 * 32 + ix1] +
           w10 * img[iy1 * 32 + ix0] + w11 * img[iy1 * 32 + ix1];
}

__device__ __forceinline__ float2 comp_flow(const float* __restrict__ fa,
                                            const float* __restrict__ fb, int pix) {
    int y = pix >> 5, x = pix & 31;
    float fx = fa[pix], fy = fa[HW + pix];
    float px = (float)x + fx, py = (float)y + fy;
    float2 r;
    r.x = fx + bilin32(fb, px, py);
    r.y = fy + bilin32(fb + HW, px, py);
    return r;
}

// ---------------------------------------------------------------------------
// Prep kernel: sections by blockIdx.x (grid 2336).
// ---------------------------------------------------------------------------
struct WD { const float* src; int cout, Cin, nCb, wbase, beg; };
struct PrepP {
    const float *x, *f1, *f2, *ff1, *ff2;
    float *fcn2, *fn2c;
    unsigned short *x_pad, *extra_pad, *wgt;
    WD wd[12];
};

__global__ __launch_bounds__(256) void prep_k(PrepP P) {
    __shared__ float wlds[16 * 288];
    const int b = blockIdx.x, tid = threadIdx.x;
    if (b < 192) {
        int idx = b * 256 + tid;                 // < 1024*48
        int pix = idx / 48, c4 = idx - pix * 48;
        int y = pix >> 5, xx = pix & 31;
        int c0 = c4 * 4;
        ushort4 s;
        s.x = f2bf(P.x[(size_t)(c0 + 0) * HW + pix]);
        s.y = f2bf(P.x[(size_t)(c0 + 1) * HW + pix]);
        s.z = f2bf(P.x[(size_t)(c0 + 2) * HW + pix]);
        s.w = f2bf(P.x[(size_t)(c0 + 3) * HW + pix]);
        *(ushort4*)(&P.x_pad[(size_t)((y + 1) * 34 + xx + 1) * 192 + c0]) = s;
    } else if (b < 672) {
        int idx = (b - 192) * 256 + tid;         // < 1024*120
        int pix = idx / 120, c4 = idx - pix * 120;
        int y = pix >> 5, xx = pix & 31;
        int c0 = c4 * 4;
        float va[4];
        if (c0 < 64) {
#pragma unroll
            for (int k = 0; k < 4; ++k) va[k] = P.x[(size_t)(c0 + k) * HW + pix];
        } else if (c0 < 448) {
            int grp = (c0 - 64) >> 6;
            int c = (c0 - 64) & 63;
            const float* src; float fx, fy;
            if (grp == 0)      { src = P.x + 64 * HW;  fx = P.f1[pix];  fy = P.f1[HW + pix]; }
            else if (grp == 1) { src = P.x + 128 * HW; float2 r = comp_flow(P.f1, P.f2, pix);  fx = r.x; fy = r.y; }
            else if (grp == 2) { src = P.x;            fx = P.ff1[pix]; fy = P.ff1[HW + pix]; }
            else if (grp == 3) { src = P.x + 128 * HW; fx = P.f2[pix];  fy = P.f2[HW + pix]; }
            else if (grp == 4) { src = P.x + 64 * HW;  fx = P.ff2[pix]; fy = P.ff2[HW + pix]; }
            else               { src = P.x;            float2 r = comp_flow(P.ff2, P.ff1, pix); fx = r.x; fy = r.y; }
            float px = (float)xx + fx, py = (float)y + fy;
            float x0f = floorf(px), y0f = floorf(py);
            float wx = px - x0f, wy = py - y0f;
            bool vx0 = (x0f >= 0.f) && (x0f <= 31.f);
            bool vx1 = (x0f >= -1.f) && (x0f <= 30.f);
            bool vy0 = (y0f >= 0.f) && (y0f <= 31.f);
            bool vy1 = (y0f >= -1.f) && (y0f <= 30.f);
            int ix0 = (int)fminf(fmaxf(x0f, 0.f), 31.f);
            int iy0 = (int)fminf(fmaxf(y0f, 0.f), 31.f);
            int ix1 = (int)fminf(fmaxf(x0f + 1.f, 0.f), 31.f);
            int iy1 = (int)fminf(fmaxf(y0f + 1.f, 0.f), 31.f);
            float w00 = (1.f - wx) * (1.f - wy) * ((vx0 && vy0) ? 1.f : 0.f);
            float w01 = wx * (1.f - wy) * ((vx1 && vy0) ? 1.f : 0.f);
            float w10 = (1.f - wx) * wy * ((vx0 && vy1) ? 1.f : 0.f);
            float w11 = wx * wy * ((vx1 && vy1) ? 1.f : 0.f);
            int p00 = iy0 * 32 + ix0, p01 = iy0 * 32 + ix1;
            int p10 = iy1 * 32 + ix0, p11 = iy1 * 32 + ix1;
            const float* im = src + (size_t)c * HW;
#pragma unroll
            for (int k = 0; k < 4; ++k) {
                va[k] = w00 * im[p00] + w01 * im[p01] + w10 * im[p10] + w11 * im[p11];
                im += HW;
            }
        } else {
#pragma unroll
            for (int k = 0; k < 4; ++k) {
                int ch = c0 + k;
                float v = 0.f;
                if (ch < 460) {
                    int fc = ch - 448;
                    int which = fc >> 1, comp = fc & 1;
                    if (which == 0)      v = P.f1[comp * HW + pix];
                    else if (which == 1) { float2 r = comp_flow(P.f1, P.f2, pix);  v = comp ? r.y : r.x; }
                    else if (which == 2) v = P.ff1[comp * HW + pix];
                    else if (which == 3) v = P.f2[comp * HW + pix];
                    else if (which == 4) v = P.ff2[comp * HW + pix];
                    else                 { float2 r = comp_flow(P.ff2, P.ff1, pix); v = comp ? r.y : r.x; }
                }
                va[k] = v;
            }
        }
        ushort4 s;
        s.x = f2bf(va[0]); s.y = f2bf(va[1]); s.z = f2bf(va[2]); s.w = f2bf(va[3]);
        *(ushort4*)(&P.extra_pad[(size_t)((y + 1) * 34 + xx + 1) * 480 + c0]) = s;
    } else if (b < 688) {
        int idx = (b - 672) * 256 + tid;
        if (idx < 1024) {
            float2 r = comp_flow(P.f1, P.f2, idx);
            P.fcn2[idx] = r.x; P.fcn2[HW + idx] = r.y;
        } else if (idx < 2048) {
            int pix = idx - 1024;
            float2 r = comp_flow(P.ff2, P.ff1, pix);
            P.fn2c[pix] = r.x; P.fn2c[HW + pix] = r.y;
        }
    } else if (b < 704) {
        const int chans[9] = {192, 192, 480, 64, 64, 64, 64, 192, 192};
        size_t offs[9]; size_t a = 0;
        for (int i = 0; i < 9; ++i) { offs[i] = a; a += (size_t)1156 * chans[i]; }
        int bb = b - 688;
        for (int item = bb; item < 9 * 132; item += 16) {
            int buf = item / 132, i = item - buf * 132;
            int py, px;
            if (i < 34) { py = 0; px = i; }
            else if (i < 68) { py = 33; px = i - 34; }
            else { int j = i - 68; py = 1 + (j >> 1); px = (j & 1) ? 33 : 0; }
            int C = chans[buf];
            unsigned short* p = P.x_pad + offs[buf] + (size_t)(py * 34 + px) * C;
            for (int c = tid; c < C; c += 256) p[c] = 0;
        }
    } else {
        int blk = b - 704;                       // < 1632
        int di = 0;
        while (di < 11 && blk >= P.wd[di + 1].beg) ++di;
        WD w = P.wd[di];
        int local = blk - w.beg;
        int co16 = local / w.nCb, cb = local - co16 * w.nCb;
        int cr0 = co16 * 16, ci0 = cb * 32;
        for (int i = tid; i < 16 * 288; i += 256) {
            int cr = i / 288, o = i - cr * 288;
            int crg = cr0 + cr, ci = ci0 + o / 9;
            float v = (crg < w.cout && ci < w.Cin)
                ? w.src[((size_t)crg * w.Cin + ci0) * 9 + o] : 0.f;
            wlds[i] = v;
        }
        __syncthreads();
        for (int e = tid; e < 9 * 512; e += 256) {
            int t = e >> 9, idx = e & 511;
            int j = idx & 7, lane = idx >> 3, q = lane >> 4, mm = lane & 15;
            P.wgt[((size_t)w.wbase + ((size_t)co16 * 9 + t) * w.nCb + cb) * 512 + idx] =
                f2bf(wlds[mm * 288 + (q * 8 + j) * 9 + t]);
        }
    }
}

// ---------------------------------------------------------------------------
// Conv descriptors.
// ---------------------------------------------------------------------------
struct CDesc {
    const unsigned short* in;
    const unsigned short* wgt;
    const float* bias;
    void* out;
    const float* residual;
    int Cpad, nCb, Cout, mode, cmod, relu, Mblocks;
};
struct CParam { CDesc d[4]; };

// ---------------------------------------------------------------------------
// conv2_k: 2 output rows per block (was 4). Wave w -> row (w>>1), col-half
// (w&1), ONE 16x16 accumulator per wave. Same MFMA count and numerics as
// conv_mfma_k<4,16>, but 2x the grid: the conv layers were GRID-limited
// (160/64/96 blocks on 256 CUs -> most CUs idle, latency-bound).
// LDS 10880+9216 = 20096 B.
// ---------------------------------------------------------------------------
__global__ __launch_bounds__(256) void conv2_k(CParam P) {
    constexpr int TROWS = 4;
    constexpr int TC = TROWS * 34 * 4;   // 544
    constexpr int ITRIPS = 3;
    constexpr int WN = 9 * 64;           // 576
    constexpr int WTRIPS = 3;
    __shared__ unsigned short blds[TROWS * 34 * 40];
    __shared__ unsigned short wlds[9 * 512];

    int bx = blockIdx.x;
    int di = 0;
    while (bx >= P.d[di].Mblocks) { bx -= P.d[di].Mblocks; ++di; }
    const CDesc d = P.d[di];

    const int tid = threadIdx.x;
    const int w = tid >> 6, lane = tid & 63;
    const int lq = lane >> 4, ln = lane & 15;
    const int co0 = bx * 16;
    const int by = blockIdx.y, y0 = by * 2;
    const int wr = w >> 1, wc = w & 1;       // wave's row / col-half
    const unsigned short* __restrict__ in = d.in;
    const unsigned short* __restrict__ wg = d.wgt;
    const int Cpad = d.Cpad, nCb = d.nCb;

    floatx4 acc = (floatx4){0.f, 0.f, 0.f, 0.f};

    bf16x8 ireg[ITRIPS];
    bf16x8 wreg[WTRIPS];

    auto load_regs = [&](int cb) {
        const int ci0 = cb << 5;
#pragma unroll
        for (int k = 0; k < ITRIPS; ++k) {
            int i = tid + k * 256;
            if (i < TC) {
                int r = i / 136, rem = i - r * 136, c = rem >> 2, g = rem & 3;
                ireg[k] = *(const bf16x8*)(in + (size_t)((y0 + r) * 34 + c) * Cpad + ci0 + g * 8);
            }
        }
#pragma unroll
        for (int k = 0; k < WTRIPS; ++k) {
            int i = tid + k * 256;
            if (i < WN) {
                int t = i >> 6, l16 = i & 63;
                wreg[k] = *(const bf16x8*)(wg + ((size_t)((co0 >> 4) * 9 + t) * nCb + cb) * 512 + l16 * 8);
            }
        }
    };

    load_regs(0);

    for (int cb = 0; cb < nCb; ++cb) {
        __syncthreads();
#pragma unroll
        for (int k = 0; k < ITRIPS; ++k) {
            int i = tid + k * 256;
            if (i < TC) {
                int r = i / 136, rem = i - r * 136, c = rem >> 2, g = rem & 3;
                *(bf16x8*)(&blds[(r * 34 + c) * 40 + g * 8]) = ireg[k];
            }
        }
#pragma unroll
        for (int k = 0; k < WTRIPS; ++k) {
            int i = tid + k * 256;
            if (i < WN) {
                int t = i >> 6, l16 = i & 63;
                *(bf16x8*)(&wlds[t * 512 + l16 * 8]) = wreg[k];
            }
        }
        __syncthreads();
        if (cb + 1 < nCb) load_regs(cb + 1);
        for (int t = 0; t < 9; ++t) {
            const int dy = t / 3, dx = t - dy * 3;
            const int yy = wr + dy;
            const int xx = wc * 16 + ln + dx;
            bf16x8 bfr = *(const bf16x8*)(&blds[(yy * 34 + xx) * 40 + lq * 8]);
            bf16x8 afr = *(const bf16x8*)(&wlds[t * 512 + lane * 8]);
            acc = __builtin_amdgcn_mfma_f32_16x16x32_bf16(afr, bfr, acc, 0, 0, 0);
        }
    }

    const int co = co0 + lq * 4;
    if (co < d.Cout) {
        float bv[4];
#pragma unroll
        for (int r = 0; r < 4; ++r) bv[r] = d.bias[co + r];
        const int pix = (y0 + wr) * 32 + wc * 16 + ln;
        float v[4];
#pragma unroll
        for (int r = 0; r < 4; ++r) {
            float vv = acc[r] + bv[r];
            if (d.relu) vv = (vv >= 0.f) ? vv : 0.1f * vv;
            v[r] = vv;
        }
        if (d.mode == 0) {
            float* o = (float*)d.out;
#pragma unroll
            for (int r = 0; r < 4; ++r) {
                float vv = v[r];
                if (d.residual) vv += d.residual[(size_t)(co + r) * HW + pix];
                o[(size_t)(co + r) * HW + pix] = vv;
            }
        } else if (d.mode == 1) {
            int fq = co / d.cmod, cc = co - fq * d.cmod;
            *(float4*)((float*)d.out + ((size_t)fq * HW + pix) * d.cmod + cc) =
                make_float4(v[0], v[1], v[2], v[3]);
        } else if (d.mode == 2) {
            int fq = co / d.cmod, cc = co - fq * d.cmod;
            ushort4 s4;
            s4.x = f2bf(v[0]); s4.y = f2bf(v[1]); s4.z = f2bf(v[2]); s4.w = f2bf(v[3]);
            *(ushort4*)((unsigned short*)d.out + ((size_t)fq * HW + pix) * d.cmod + cc) = s4;
        } else {
            int yy = (pix >> 5) + 1, xx = (pix & 31) + 1;
            ushort4 s4;
            s4.x = f2bf(v[0]); s4.y = f2bf(v[1]); s4.z = f2bf(v[2]); s4.w = f2bf(v[3]);
            *(ushort4*)((unsigned short*)d.out + (size_t)(yy * 34 + xx) * d.cmod + co) = s4;
        }
    }
}

// ---------------------------------------------------------------------------
// L4 conv (so3 + aw3): weight-dominant layer. Read-once weights; grid 594.
// ---------------------------------------------------------------------------
struct L4Desc {
    const unsigned short* in;
    const unsigned short* wgt;
    const float* bias;
    void* out;
    int mode, cmod, Mblocks;   // mode 1 = f32 strided, 2 = bf16 strided
};
struct L4Param { L4Desc d[2]; };

__global__ __launch_bounds__(256) void conv_l4_k(L4Param P) {
    __shared__ unsigned short blds[10 * 34 * 40];   // 27200 B (one cb slice)
    __shared__ unsigned short wlds[9 * 2 * 512];    // 18432 B (both cb slices)

    int bx = blockIdx.x;
    int di = 0;
    if (bx >= P.d[0].Mblocks) { bx -= P.d[0].Mblocks; di = 1; }
    const L4Desc d = P.d[di];

    const int tid = threadIdx.x;
    const int w = tid >> 6, lane = tid & 63;
    const int lq = lane >> 4, ln = lane & 15;
    const int co0 = bx * 16;
    const unsigned short* __restrict__ in = d.in;
    const unsigned short* __restrict__ wg = d.wgt;

    bf16x8 wreg[5];
#pragma unroll
    for (int k = 0; k < 5; ++k) {
        int i = tid + k * 256;
        if (i < 1152) {
            int chunk = i >> 6, l16 = i & 63;
            int t = chunk >> 1, cb = chunk & 1;
            wreg[k] = *(const bf16x8*)(wg + (((size_t)bx * 9 + t) * 2 + cb) * 512 + l16 * 8);
        }
    }

    bf16x8 ireg[6];
    auto load_in = [&](int y0, int cb) {
        const int ci0 = cb << 5;
#pragma unroll
        for (int k = 0; k < 6; ++k) {
            int i = tid + k * 256;
            if (i < 1360) {
                int r = i / 136, rem = i - r * 136, c = rem >> 2, g = rem & 3;
                ireg[k] = *(const bf16x8*)(in + (size_t)((y0 + r) * 34 + c) * 64 + ci0 + g * 8);
            }
        }
    };
    load_in(0, 0);

#pragma unroll
    for (int k = 0; k < 5; ++k) {
        int i = tid + k * 256;
        if (i < 1152) *(bf16x8*)(&wlds[(i >> 6) * 512 + (i & 63) * 8]) = wreg[k];
    }

    floatx4 acc[4];
#pragma unroll
    for (int nt = 0; nt < 4; ++nt) acc[nt] = (floatx4){0.f, 0.f, 0.f, 0.f};

    for (int p = 0; p < 8; ++p) {
        const int y = p >> 1, cb = p & 1;
        __syncthreads();
#pragma unroll
        for (int k = 0; k < 6; ++k) {
            int i = tid + k * 256;
            if (i < 1360) {
                int r = i / 136, rem = i - r * 136, c = rem >> 2, g = rem & 3;
                *(bf16x8*)(&blds[(r * 34 + c) * 40 + g * 8]) = ireg[k];
            }
        }
        __syncthreads();
        if (p < 7) { int pn = p + 1; load_in((pn >> 1) * 8, pn & 1); }
#pragma unroll
        for (int t = 0; t < 9; ++t) {
            const int dy = t / 3, dx = t - dy * 3;
            bf16x8 afr = *(const bf16x8*)(&wlds[(t * 2 + cb) * 512 + lane * 8]);
#pragma unroll
            for (int ty = 0; ty < 2; ++ty)
#pragma unroll
                for (int tx = 0; tx < 2; ++tx) {
                    int yy = w * 2 + ty + dy;
                    int xx = tx * 16 + ln + dx;
                    bf16x8 bfr = *(const bf16x8*)(&blds[(yy * 34 + xx) * 40 + lq * 8]);
                    acc[ty * 2 + tx] =
                        __builtin_amdgcn_mfma_f32_16x16x32_bf16(afr, bfr, acc[ty * 2 + tx], 0, 0, 0);
                }
        }
        if (cb == 1) {
            const int co = co0 + lq * 4;
            float bv[4];
#pragma unroll
            for (int r2 = 0; r2 < 4; ++r2) bv[r2] = d.bias[co + r2];
            int fq = co / d.cmod, cc = co - fq * d.cmod;
#pragma unroll
            for (int nt = 0; nt < 4; ++nt) {
                const int ty = nt >> 1, tx = nt & 1;
                const int pix = y * 256 + (w * 2 + ty) * 32 + tx * 16 + ln;
                float v0 = acc[nt][0] + bv[0], v1 = acc[nt][1] + bv[1];
                float v2 = acc[nt][2] + bv[2], v3 = acc[nt][3] + bv[3];
                if (d.mode == 1) {
                    *(float4*)((float*)d.out + ((size_t)fq * HW + pix) * d.cmod + cc) =
                        make_float4(v0, v1, v2, v3);
                } else {
                    ushort4 s4;
                    s4.x = f2bf(v0); s4.y = f2bf(v1); s4.z = f2bf(v2); s4.w = f2bf(v3);
                    *(ushort4*)((unsigned short*)d.out + ((size_t)fq * HW + pix) * d.cmod + cc) = s4;
                }
                acc[nt] = (floatx4){0.f, 0.f, 0.f, 0.f};
            }
        }
    }
}

// ---------------------------------------------------------------------------
// Deformable attention, no-LDS-value variant. Grid 1536 (16 queries/block).
// DPP reductions; lane 63 stores. value_b layout [l][m][pix][8ch]: level
// stride 65536 shorts, head m*8192.
// ---------------------------------------------------------------------------
__global__ __launch_bounds__(256) void deform_attn_k(
    const unsigned short* __restrict__ value_b, const float* __restrict__ so_t,
    const unsigned short* __restrict__ aw_t,
    const float* __restrict__ flow_1, const float* __restrict__ flow_2,
    const float* __restrict__ flip_flow_1, const float* __restrict__ flip_flow_2,
    const float* __restrict__ flow_cn2, const float* __restrict__ flow_n2c,
    unsigned short* __restrict__ attn_pad)
{
    __shared__ unsigned short pwlds[4][432];
    const int tid = threadIdx.x;
    const int wav = tid >> 6, lane = tid & 63;
    const int m = blockIdx.x & 7, qc = blockIdx.x >> 3;   // qc in [0,192)

    const int pp = lane & 15, gq = lane >> 4;
    const int gdy = (gq >> 1) * 2 - 1;
    const int gdx = (gq & 1) * 2 - 1;
    const bool selx = (gq & 1);
    const bool sely = (gq >> 1);

    const unsigned short* __restrict__ vm = value_b + (size_t)m * 8192;

    for (int r = 0; r < 4; ++r) {
        const int q = qc * 16 + r * 4 + wav;
        const int f = q >> 10, pix = q & 1023;
        const int y = pix >> 5, x = pix & 31;

        float av[6];
        {
            const unsigned short* awp = aw_t + (size_t)q * 2592 + m * 324;
#pragma unroll
            for (int it = 0; it < 6; ++it) {
                int j = lane + it * 64;
                av[it] = (j < 324) ? bf2f(awp[j]) : -1e30f;
            }
        }

        float vmax = -1e30f;
#pragma unroll
        for (int it = 0; it < 6; ++it) vmax = fmaxf(vmax, av[it]);
        vmax = bcast_lane63(wave_max64(vmax));
        float ssum = 0.f;
#pragma unroll
        for (int it = 0; it < 6; ++it) {
            int j = lane + it * 64;
            float e = (j < 324) ? __expf(av[it] - vmax) : 0.f;
            av[it] = e;
            ssum += e;
        }
        ssum = bcast_lane63(wave_sum64(ssum));
        const float inv = 1.f / ssum;

#pragma unroll
        for (int it = 0; it < 6; ++it) {
            int j = lane + it * 64;
            if (j < 324) {
                int pi = j / 9, k = j - pi * 9;
                pwlds[wav][pi * 12 + k] = f2bf(av[it] * inv);
            }
        }

        const float* sop = so_t + (size_t)q * 576 + m * 72;

        float flx0 = 0.f, fly0 = 0.f, flx1 = 0.f, fly1 = 0.f, flx2 = 0.f, fly2 = 0.f;
        if (f == 0) {
            flx1 = flow_1[pix];      fly1 = flow_1[HW + pix];
            flx2 = flow_cn2[pix];    fly2 = flow_cn2[HW + pix];
        } else if (f == 1) {
            flx0 = flip_flow_1[pix]; fly0 = flip_flow_1[HW + pix];
            flx2 = flow_2[pix];      fly2 = flow_2[HW + pix];
        } else {
            flx0 = flow_n2c[pix];    fly0 = flow_n2c[HW + pix];
            flx1 = flip_flow_2[pix]; fly1 = flip_flow_2[HW + pix];
        }

        float acc[8];
#pragma unroll
        for (int dd = 0; dd < 8; ++dd) acc[dd] = 0.f;

#pragma unroll
        for (int pt = 0; pt < 3; ++pt) {
            int pi = pt * 16 + pp;
            if (pi < 36) {
                int l = pi / 12;
                float2 so2 = *(const float2*)(sop + pi * 2);
                float fx = (l == 0) ? flx0 : (l == 1) ? flx1 : flx2;
                float fy = (l == 0) ? fly0 : (l == 1) ? fly1 : fly2;
                float bxf = (float)x + so2.x + fx;
                float byf = (float)y + so2.y + fy;
                float x0f = floorf(bxf), y0f = floorf(byf);
                float wx = bxf - x0f, wy = byf - y0f;
                float ax = 1.f - wx, ay = 1.f - wy;
                int x0 = (int)fminf(fmaxf(x0f, -2.f), 34.f);
                int y0 = (int)fminf(fmaxf(y0f, -2.f), 34.f);

                const unsigned short* pr = &pwlds[wav][pi * 12];
                uint2 pv0 = *(const uint2*)(pr);
                uint2 pv1 = *(const uint2*)(pr + 4);
                float a0 = bflo(pv0.x), a1 = bfhi(pv0.x), a2 = bflo(pv0.y);
                float a3 = bfhi(pv0.y), a4 = bflo(pv1.x), a5 = bfhi(pv1.x);
                float a6 = bflo(pv1.y), a7 = bfhi(pv1.y), a8 = bf2f(pr[8]);

                float bs0a, bs0b, bs1a, bs1b, bs2a, bs2b;
                {
                    float b0, b1, b2, b3;
                    b0 = a0 * ax; b1 = a0 * wx + a3 * ax; b2 = a3 * wx + a6 * ax; b3 = a6 * wx;
                    bs0a = selx ? b2 : b0; bs0b = selx ? b3 : b1;
                    b0 = a1 * ax; b1 = a1 * wx + a4 * ax; b2 = a4 * wx + a7 * ax; b3 = a7 * wx;
                    bs1a = selx ? b2 : b0; bs1b = selx ? b3 : b1;
                    b0 = a2 * ax; b1 = a2 * wx + a5 * ax; b2 = a5 * wx + a8 * ax; b3 = a8 * wx;
                    bs2a = selx ? b2 : b0; bs2b = selx ? b3 : b1;
                }
                float c00, c01, c10, c11;
                {
                    float c0 = bs0a * ay, c1 = bs0a * wy + bs1a * ay;
                    float c2 = bs1a * wy + bs2a * ay, c3 = bs2a * wy;
                    c00 = sely ? c2 : c0; c10 = sely ? c3 : c1;
                    c0 = bs0b * ay; c1 = bs0b * wy + bs1b * ay;
                    c2 = bs1b * wy + bs2b * ay; c3 = bs2b * wy;
                    c01 = sely ? c2 : c0; c11 = sely ? c3 : c1;
                }
                float cg[2][2] = {{c00, c01}, {c10, c11}};
                const unsigned short* __restrict__ vl = vm + (size_t)l * 65536;
#pragma unroll
                for (int sy = 0; sy < 2; ++sy) {
#pragma unroll
                    for (int sx = 0; sx < 2; ++sx) {
                        int dy = gdy + sy, dx = gdx + sx;
                        float pyf = y0f + (float)dy, pxf = x0f + (float)dx;
                        bool v = (pxf >= 0.f) && (pxf <= 31.f) && (pyf >= 0.f) && (pyf <= 31.f);
                        int px = min(max(x0 + dx, 0), 31);
                        int py = min(max(y0 + dy, 0), 31);
                        float c = cg[sy][sx] * (v ? 1.f : 0.f);
                        uint4 vv = *(const uint4*)(vl + (size_t)(py * 32 + px) * 8);
                        acc[0] = fmaf(c, bflo(vv.x), acc[0]);
                        acc[1] = fmaf(c, bfhi(vv.x), acc[1]);
                        acc[2] = fmaf(c, bflo(vv.y), acc[2]);
                        acc[3] = fmaf(c, bfhi(vv.y), acc[3]);
                        acc[4] = fmaf(c, bflo(vv.z), acc[4]);
                        acc[5] = fmaf(c, bfhi(vv.z), acc[5]);
                        acc[6] = fmaf(c, bflo(vv.w), acc[6]);
                        acc[7] = fmaf(c, bfhi(vv.w), acc[7]);
                    }
                }
            }
        }

#pragma unroll
        for (int dd = 0; dd < 8; ++dd) acc[dd] = wave_sum64(acc[dd]);
        if (lane == 63) {
            unsigned short* op = attn_pad + (size_t)((y + 1) * 34 + x + 1) * 192 + f * 64 + m * 8;
            ushort4 s0, s1;
            s0.x = f2bf(acc[0]); s0.y = f2bf(acc[1]); s0.z = f2bf(acc[2]); s0.w = f2bf(acc[3]);
            s1.x = f2bf(acc[4]); s1.y = f2bf(acc[5]); s1.z = f2bf(acc[6]); s1.w = f2bf(acc[7]);
            *(ushort4*)(op) = s0;
            *(ushort4*)(op + 4) = s1;
        }
    }
}

// ---------------------------------------------------------------------------
extern "C" void kernel_launch(void* const* d_in, const int* in_sizes, int n_in,
                              void* d_out, int out_size, void* d_ws, size_t ws_size,
                              hipStream_t stream) {
    const float* x      = (const float*)d_in[0];
    const float* flow_1 = (const float*)d_in[1];
    const float* flow_2 = (const float*)d_in[2];
    const float* flip_1 = (const float*)d_in[3];
    const float* flip_2 = (const float*)d_in[4];
    const float* vp0_w = (const float*)d_in[5];  const float* vp0_b = (const float*)d_in[6];
    const float* vp1_w = (const float*)d_in[7];  const float* vp1_b = (const float*)d_in[8];
    const float* so0_w = (const float*)d_in[9];  const float* so0_b = (const float*)d_in[10];
    const float* so1_w = (const float*)d_in[11]; const float* so1_b = (const float*)d_in[12];
    const float* so2_w = (const float*)d_in[13]; const float* so2_b = (const float*)d_in[14];
    const float* so3_w = (const float*)d_in[15]; const float* so3_b = (const float*)d_in[16];
    const float* aw0_w = (const float*)d_in[17]; const float* aw0_b = (const float*)d_in[18];
    const float* aw1_w = (const float*)d_in[19]; const float* aw1_b = (const float*)d_in[20];
    const float* aw2_w = (const float*)d_in[21]; const float* aw2_b = (const float*)d_in[22];
    const float* aw3_w = (const float*)d_in[23]; const float* aw3_b = (const float*)d_in[24];
    const float* op0_w = (const float*)d_in[25]; const float* op0_b = (const float*)d_in[26];
    const float* op1_w = (const float*)d_in[27]; const float* op1_b = (const float*)d_in[28];
    float* out = (float*)d_out;
    (void)ws_size; (void)in_sizes; (void)n_in; (void)out_size;

    // ---- workspace layout ----
    float* fws = (float*)d_ws;
    float* flow_cn2 = fws;
    float* flow_n2c = flow_cn2 + 2048;
    unsigned short* value_b = (unsigned short*)(flow_n2c + 2048);
    float* so_t     = (float*)(value_b + 196608);
    unsigned short* uws = (unsigned short*)(so_t + 1769472);
    unsigned short* x_pad     = uws;
    unsigned short* vp0h      = x_pad + 1156 * 192;
    unsigned short* extra_pad = vp0h + 1156 * 192;
    unsigned short* s1 = extra_pad + 1156 * 480;
    unsigned short* a1 = s1 + 1156 * 64;
    unsigned short* s2 = a1 + 1156 * 64;
    unsigned short* a2 = s2 + 1156 * 64;
    unsigned short* attn_pad = a2 + 1156 * 64;
    unsigned short* op0h     = attn_pad + 1156 * 192;
    unsigned short* aw_t = op0h + 1156 * 192;
    unsigned short* wgt  = aw_t + (size_t)3072 * 2592;

    // ---- 1. prep ----
    PrepP pp;
    pp.x = x; pp.f1 = flow_1; pp.f2 = flow_2; pp.ff1 = flip_1; pp.ff2 = flip_2;
    pp.fcn2 = flow_cn2; pp.fn2c = flow_n2c;
    pp.x_pad = x_pad; pp.extra_pad = extra_pad; pp.wgt = wgt;
    pp.wd[0]  = {vp0_w, 192, 192, 6,     0,    0};
    pp.wd[1]  = {vp1_w, 192, 192, 6,   648,   72};
    pp.wd[2]  = {so0_w,  64, 460, 15, 1296,  144};
    pp.wd[3]  = {aw0_w,  64, 460, 15, 1836,  204};
    pp.wd[4]  = {so1_w,  64,  64, 2,  2376,  264};
    pp.wd[5]  = {aw1_w,  64,  64, 2,  2448,  272};
    pp.wd[6]  = {so2_w,  64,  64, 2,  2520,  280};
    pp.wd[7]  = {aw2_w,  64,  64, 2,  2592,  288};
    pp.wd[8]  = {so3_w, 1728, 64, 2,  2664,  296};
    pp.wd[9]  = {aw3_w, 7776, 64, 2,  4608,  512};
    pp.wd[10] = {op0_w, 192, 192, 6, 13392, 1488};
    pp.wd[11] = {op1_w, 192, 192, 6, 14040, 1560};
    prep_k<<<2336, 256, 0, stream>>>(pp);

    const int BIG = 1 << 30;
    CDesc nul = {nullptr, nullptr, nullptr, nullptr, nullptr, 0, 0, 0, 0, 0, 0, BIG};

    // ---- 2. L1: vp0 + so0 + aw0 (2-row blocks, grid (20,16)) ----
    {
        CParam cp;
        cp.d[0] = {x_pad,     wgt + (size_t)0 * 512,    vp0_b, vp0h, nullptr, 192, 6,  192, 3, 192, 1, 12};
        cp.d[1] = {extra_pad, wgt + (size_t)1296 * 512, so0_b, s1,   nullptr, 480, 15, 64,  3, 64,  1, 4};
        cp.d[2] = {extra_pad, wgt + (size_t)1836 * 512, aw0_b, a1,   nullptr, 480, 15, 64,  3, 64,  1, 4};
        cp.d[3] = nul;
        conv2_k<<<dim3(20, 16), 256, 0, stream>>>(cp);
    }
    // ---- 3. L2: vp1 + so1 + aw1 ----
    {
        CParam cp;
        cp.d[0] = {vp0h, wgt + (size_t)648 * 512,  vp1_b, value_b, nullptr, 192, 6, 192, 2, 8,  0, 12};
        cp.d[1] = {s1,   wgt + (size_t)2376 * 512, so1_b, s2,      nullptr, 64,  2, 64,  3, 64, 1, 4};
        cp.d[2] = {a1,   wgt + (size_t)2448 * 512, aw1_b, a2,      nullptr, 64,  2, 64,  3, 64, 1, 4};
        cp.d[3] = nul;
        conv2_k<<<dim3(20, 16), 256, 0, stream>>>(cp);
    }
    // ---- 4. L3: so2 + aw2 ----
    {
        CParam cp;
        cp.d[0] = {s2, wgt + (size_t)2520 * 512, so2_b, s1, nullptr, 64, 2, 64, 3, 64, 1, 4};
        cp.d[1] = {a2, wgt + (size_t)2592 * 512, aw2_b, a1, nullptr, 64, 2, 64, 3, 64, 1, 4};
        cp.d[2] = nul; cp.d[3] = nul;
        conv2_k<<<dim3(8, 16), 256, 0, stream>>>(cp);
    }
    // ---- 5. L4: so3 + aw3 (dedicated read-once-weights kernel) ----
    {
        L4Param lp;
        lp.d[0] = {s1, wgt + (size_t)2664 * 512, so3_b, so_t, 1, 576,  108};
        lp.d[1] = {a1, wgt + (size_t)4608 * 512, aw3_b, aw_t, 2, 2592, 486};
        conv_l4_k<<<594, 256, 0, stream>>>(lp);
    }

    // ---- 6. deformable attention (no-LDS-value, L2-gather, grid 1536) ----
    deform_attn_k<<<1536, 256, 0, stream>>>(value_b, so_t, aw_t,
                                            flow_1, flow_2, flip_1, flip_2,
                                            flow_cn2, flow_n2c, attn_pad);

    // ---- 7. op0 ----
    {
        CParam cp;
        cp.d[0] = {attn_pad, wgt + (size_t)13392 * 512, op0_b, op0h, nullptr, 192, 6, 192, 3, 192, 1, 12};
        cp.d[1] = nul; cp.d[2] = nul; cp.d[3] = nul;
        conv2_k<<<dim3(12, 16), 256, 0, stream>>>(cp);
    }
    // ---- 8. op1 + residual ----
    {
        CParam cp;
        cp.d[0] = {op0h, wgt + (size_t)14040 * 512, op1_b, out, x, 192, 6, 192, 0, 0, 0, 12};
        cp.d[1] = nul; cp.d[2] = nul; cp.d[3] = nul;
        conv2_k<<<dim3(12, 16), 256, 0, stream>>>(cp);
    }
}

// Round 14
// 244.967 us; speedup vs baseline: 3.0074x; 1.0046x over previous
//
#include <hip/hip_runtime.h>
#include <math.h>

#define HW 1024

typedef __attribute__((ext_vector_type(8))) short bf16x8;
typedef __attribute__((ext_vector_type(4))) float floatx4;

__device__ __forceinline__ unsigned short f2bf(float f) {
    unsigned u = __float_as_uint(f);
    u += 0x7FFF + ((u >> 16) & 1);
    return (unsigned short)(u >> 16);
}
__device__ __forceinline__ float bf2f(unsigned short u) {
    return __uint_as_float(((unsigned)u) << 16);
}
__device__ __forceinline__ float bflo(unsigned u) { return __uint_as_float(u << 16); }
__device__ __forceinline__ float bfhi(unsigned u) { return __uint_as_float(u & 0xffff0000u); }

// ---------------------------------------------------------------------------
// DPP wave-64 reductions: VALU-only. Result lands in lane 63.
// ---------------------------------------------------------------------------
template<int CTRL, int RM>
__device__ __forceinline__ float dpp_sum_step(float v) {
    int t = __builtin_amdgcn_update_dpp(0, __float_as_int(v), CTRL, RM, 0xf, true);
    return v + __int_as_float(t);
}
template<int CTRL, int RM>
__device__ __forceinline__ float dpp_max_step(float v) {
    int t = __builtin_amdgcn_update_dpp(__float_as_int(v), __float_as_int(v), CTRL, RM, 0xf, false);
    return fmaxf(v, __int_as_float(t));
}
__device__ __forceinline__ float wave_sum64(float x) {
    x = dpp_sum_step<0x111, 0xf>(x);   // row_shr:1
    x = dpp_sum_step<0x112, 0xf>(x);   // row_shr:2
    x = dpp_sum_step<0x114, 0xf>(x);   // row_shr:4
    x = dpp_sum_step<0x118, 0xf>(x);   // row_shr:8
    x = dpp_sum_step<0x142, 0xa>(x);   // row_bcast:15 -> rows 1,3
    x = dpp_sum_step<0x143, 0xc>(x);   // row_bcast:31 -> rows 2,3
    return x;
}
__device__ __forceinline__ float wave_max64(float x) {
    x = dpp_max_step<0x111, 0xf>(x);
    x = dpp_max_step<0x112, 0xf>(x);
    x = dpp_max_step<0x114, 0xf>(x);
    x = dpp_max_step<0x118, 0xf>(x);
    x = dpp_max_step<0x142, 0xa>(x);
    x = dpp_max_step<0x143, 0xc>(x);
    return x;
}
__device__ __forceinline__ float bcast_lane63(float x) {
    return __int_as_float(__builtin_amdgcn_readlane(__float_as_int(x), 63));
}

// ---------------------------------------------------------------------------
// Bilinear sample, zero padding, absolute pixel coords (matches reference).
// ---------------------------------------------------------------------------
__device__ __forceinline__ float bilin32(const float* __restrict__ img, float px, float py) {
    float x0f = floorf(px), y0f = floorf(py);
    float wx = px - x0f, wy = py - y0f;
    bool vx0 = (x0f >= 0.f) && (x0f <= 31.f);
    bool vx1 = (x0f >= -1.f) && (x0f <= 30.f);
    bool vy0 = (y0f >= 0.f) && (y0f <= 31.f);
    bool vy1 = (y0f >= -1.f) && (y0f <= 30.f);
    int ix0 = (int)fminf(fmaxf(x0f, 0.f), 31.f);
    int iy0 = (int)fminf(fmaxf(y0f, 0.f), 31.f);
    int ix1 = (int)fminf(fmaxf(x0f + 1.f, 0.f), 31.f);
    int iy1 = (int)fminf(fmaxf(y0f + 1.f, 0.f), 31.f);
    float w00 = (1.f - wx) * (1.f - wy) * ((vx0 && vy0) ? 1.f : 0.f);
    float w01 = wx * (1.f - wy) * ((vx1 && vy0) ? 1.f : 0.f);
    float w10 = (1.f - wx) * wy * ((vx0 && vy1) ? 1.f : 0.f);
    float w11 = wx * wy * ((vx1 && vy1) ? 1.f : 0.f);
    return w00 * img[iy0 * 32 + ix0] + w01 * img[iy0 * 32 + ix1] +
           w10 * img[iy1 * 32 + ix0] + w11 * img[iy1 * 32 + ix1];
}

__device__ __forceinline__ float2 comp_flow(const float* __restrict__ fa,
                                            const float* __restrict__ fb, int pix) {
    int y = pix >> 5, x = pix & 31;
    float fx = fa[pix], fy = fa[HW + pix];
    float px = (float)x + fx, py = (float)y + fy;
    float2 r;
    r.x = fx + bilin32(fb, px, py);
    r.y = fy + bilin32(fb + HW, px, py);
    return r;
}

// ---------------------------------------------------------------------------
// Prep kernel: sections by blockIdx.x (grid 2336).
// ---------------------------------------------------------------------------
struct WD { const float* src; int cout, Cin, nCb, wbase, beg; };
struct PrepP {
    const float *x, *f1, *f2, *ff1, *ff2;
    float *fcn2, *fn2c;
    unsigned short *x_pad, *extra_pad, *wgt;
    WD wd[12];
};

__global__ __launch_bounds__(256) void prep_k(PrepP P) {
    __shared__ float wlds[16 * 288];
    const int b = blockIdx.x, tid = threadIdx.x;
    if (b < 192) {
        int idx = b * 256 + tid;                 // < 1024*48
        int pix = idx / 48, c4 = idx - pix * 48;
        int y = pix >> 5, xx = pix & 31;
        int c0 = c4 * 4;
        ushort4 s;
        s.x = f2bf(P.x[(size_t)(c0 + 0) * HW + pix]);
        s.y = f2bf(P.x[(size_t)(c0 + 1) * HW + pix]);
        s.z = f2bf(P.x[(size_t)(c0 + 2) * HW + pix]);
        s.w = f2bf(P.x[(size_t)(c0 + 3) * HW + pix]);
        *(ushort4*)(&P.x_pad[(size_t)((y + 1) * 34 + xx + 1) * 192 + c0]) = s;
    } else if (b < 672) {
        int idx = (b - 192) * 256 + tid;         // < 1024*120
        int pix = idx / 120, c4 = idx - pix * 120;
        int y = pix >> 5, xx = pix & 31;
        int c0 = c4 * 4;
        float va[4];
        if (c0 < 64) {
#pragma unroll
            for (int k = 0; k < 4; ++k) va[k] = P.x[(size_t)(c0 + k) * HW + pix];
        } else if (c0 < 448) {
            int grp = (c0 - 64) >> 6;
            int c = (c0 - 64) & 63;
            const float* src; float fx, fy;
            if (grp == 0)      { src = P.x + 64 * HW;  fx = P.f1[pix];  fy = P.f1[HW + pix]; }
            else if (grp == 1) { src = P.x + 128 * HW; float2 r = comp_flow(P.f1, P.f2, pix);  fx = r.x; fy = r.y; }
            else if (grp == 2) { src = P.x;            fx = P.ff1[pix]; fy = P.ff1[HW + pix]; }
            else if (grp == 3) { src = P.x + 128 * HW; fx = P.f2[pix];  fy = P.f2[HW + pix]; }
            else if (grp == 4) { src = P.x + 64 * HW;  fx = P.ff2[pix]; fy = P.ff2[HW + pix]; }
            else               { src = P.x;            float2 r = comp_flow(P.ff2, P.ff1, pix); fx = r.x; fy = r.y; }
            float px = (float)xx + fx, py = (float)y + fy;
            float x0f = floorf(px), y0f = floorf(py);
            float wx = px - x0f, wy = py - y0f;
            bool vx0 = (x0f >= 0.f) && (x0f <= 31.f);
            bool vx1 = (x0f >= -1.f) && (x0f <= 30.f);
            bool vy0 = (y0f >= 0.f) && (y0f <= 31.f);
            bool vy1 = (y0f >= -1.f) && (y0f <= 30.f);
            int ix0 = (int)fminf(fmaxf(x0f, 0.f), 31.f);
            int iy0 = (int)fminf(fmaxf(y0f, 0.f), 31.f);
            int ix1 = (int)fminf(fmaxf(x0f + 1.f, 0.f), 31.f);
            int iy1 = (int)fminf(fmaxf(y0f + 1.f, 0.f), 31.f);
            float w00 = (1.f - wx) * (1.f - wy) * ((vx0 && vy0) ? 1.f : 0.f);
            float w01 = wx * (1.f - wy) * ((vx1 && vy0) ? 1.f : 0.f);
            float w10 = (1.f - wx) * wy * ((vx0 && vy1) ? 1.f : 0.f);
            float w11 = wx * wy * ((vx1 && vy1) ? 1.f : 0.f);
            int p00 = iy0 * 32 + ix0, p01 = iy0 * 32 + ix1;
            int p10 = iy1 * 32 + ix0, p11 = iy1 * 32 + ix1;
            const float* im = src + (size_t)c * HW;
#pragma unroll
            for (int k = 0; k < 4; ++k) {
                va[k] = w00 * im[p00] + w01 * im[p01] + w10 * im[p10] + w11 * im[p11];
                im += HW;
            }
        } else {
#pragma unroll
            for (int k = 0; k < 4; ++k) {
                int ch = c0 + k;
                float v = 0.f;
                if (ch < 460) {
                    int fc = ch - 448;
                    int which = fc >> 1, comp = fc & 1;
                    if (which == 0)      v = P.f1[comp * HW + pix];
                    else if (which == 1) { float2 r = comp_flow(P.f1, P.f2, pix);  v = comp ? r.y : r.x; }
                    else if (which == 2) v = P.ff1[comp * HW + pix];
                    else if (which == 3) v = P.f2[comp * HW + pix];
                    else if (which == 4) v = P.ff2[comp * HW + pix];
                    else                 { float2 r = comp_flow(P.ff2, P.ff1, pix); v = comp ? r.y : r.x; }
                }
                va[k] = v;
            }
        }
        ushort4 s;
        s.x = f2bf(va[0]); s.y = f2bf(va[1]); s.z = f2bf(va[2]); s.w = f2bf(va[3]);
        *(ushort4*)(&P.extra_pad[(size_t)((y + 1) * 34 + xx + 1) * 480 + c0]) = s;
    } else if (b < 688) {
        int idx = (b - 672) * 256 + tid;
        if (idx < 1024) {
            float2 r = comp_flow(P.f1, P.f2, idx);
            P.fcn2[idx] = r.x; P.fcn2[HW + idx] = r.y;
        } else if (idx < 2048) {
            int pix = idx - 1024;
            float2 r = comp_flow(P.ff2, P.ff1, pix);
            P.fn2c[pix] = r.x; P.fn2c[HW + pix] = r.y;
        }
    } else if (b < 704) {
        const int chans[9] = {192, 192, 480, 64, 64, 64, 64, 192, 192};
        size_t offs[9]; size_t a = 0;
        for (int i = 0; i < 9; ++i) { offs[i] = a; a += (size_t)1156 * chans[i]; }
        int bb = b - 688;
        for (int item = bb; item < 9 * 132; item += 16) {
            int buf = item / 132, i = item - buf * 132;
            int py, px;
            if (i < 34) { py = 0; px = i; }
            else if (i < 68) { py = 33; px = i - 34; }
            else { int j = i - 68; py = 1 + (j >> 1); px = (j & 1) ? 33 : 0; }
            int C = chans[buf];
            unsigned short* p = P.x_pad + offs[buf] + (size_t)(py * 34 + px) * C;
            for (int c = tid; c < C; c += 256) p[c] = 0;
        }
    } else {
        int blk = b - 704;                       // < 1632
        int di = 0;
        while (di < 11 && blk >= P.wd[di + 1].beg) ++di;
        WD w = P.wd[di];
        int local = blk - w.beg;
        int co16 = local / w.nCb, cb = local - co16 * w.nCb;
        int cr0 = co16 * 16, ci0 = cb * 32;
        for (int i = tid; i < 16 * 288; i += 256) {
            int cr = i / 288, o = i - cr * 288;
            int crg = cr0 + cr, ci = ci0 + o / 9;
            float v = (crg < w.cout && ci < w.Cin)
                ? w.src[((size_t)crg * w.Cin + ci0) * 9 + o] : 0.f;
            wlds[i] = v;
        }
        __syncthreads();
        for (int e = tid; e < 9 * 512; e += 256) {
            int t = e >> 9, idx = e & 511;
            int j = idx & 7, lane = idx >> 3, q = lane >> 4, mm = lane & 15;
            P.wgt[((size_t)w.wbase + ((size_t)co16 * 9 + t) * w.nCb + cb) * 512 + idx] =
                f2bf(wlds[mm * 288 + (q * 8 + j) * 9 + t]);
        }
    }
}

// ---------------------------------------------------------------------------
// Conv descriptors.
// ---------------------------------------------------------------------------
struct CDesc {
    const unsigned short* in;
    const unsigned short* wgt;
    const float* bias;
    void* out;
    const float* residual;
    int Cpad, nCb, Cout, mode, cmod, relu, Mblocks;
};
struct CParam { CDesc d[4]; };

// ---------------------------------------------------------------------------
// conv2_k: 2 output rows per block. Wave w -> row (w>>1), col-half (w&1),
// one 16x16 accumulator. LDS 10880+9216 = 20096 B.
// ---------------------------------------------------------------------------
__global__ __launch_bounds__(256) void conv2_k(CParam P) {
    constexpr int TROWS = 4;
    constexpr int TC = TROWS * 34 * 4;   // 544
    constexpr int ITRIPS = 3;
    constexpr int WN = 9 * 64;           // 576
    constexpr int WTRIPS = 3;
    __shared__ unsigned short blds[TROWS * 34 * 40];
    __shared__ unsigned short wlds[9 * 512];

    int bx = blockIdx.x;
    int di = 0;
    while (bx >= P.d[di].Mblocks) { bx -= P.d[di].Mblocks; ++di; }
    const CDesc d = P.d[di];

    const int tid = threadIdx.x;
    const int w = tid >> 6, lane = tid & 63;
    const int lq = lane >> 4, ln = lane & 15;
    const int co0 = bx * 16;
    const int by = blockIdx.y, y0 = by * 2;
    const int wr = w >> 1, wc = w & 1;
    const unsigned short* __restrict__ in = d.in;
    const unsigned short* __restrict__ wg = d.wgt;
    const int Cpad = d.Cpad, nCb = d.nCb;

    floatx4 acc = (floatx4){0.f, 0.f, 0.f, 0.f};

    bf16x8 ireg[ITRIPS];
    bf16x8 wreg[WTRIPS];

    auto load_regs = [&](int cb) {
        const int ci0 = cb << 5;
#pragma unroll
        for (int k = 0; k < ITRIPS; ++k) {
            int i = tid + k * 256;
            if (i < TC) {
                int r = i / 136, rem = i - r * 136, c = rem >> 2, g = rem & 3;
                ireg[k] = *(const bf16x8*)(in + (size_t)((y0 + r) * 34 + c) * Cpad + ci0 + g * 8);
            }
        }
#pragma unroll
        for (int k = 0; k < WTRIPS; ++k) {
            int i = tid + k * 256;
            if (i < WN) {
                int t = i >> 6, l16 = i & 63;
                wreg[k] = *(const bf16x8*)(wg + ((size_t)((co0 >> 4) * 9 + t) * nCb + cb) * 512 + l16 * 8);
            }
        }
    };

    load_regs(0);

    for (int cb = 0; cb < nCb; ++cb) {
        __syncthreads();
#pragma unroll
        for (int k = 0; k < ITRIPS; ++k) {
            int i = tid + k * 256;
            if (i < TC) {
                int r = i / 136, rem = i - r * 136, c = rem >> 2, g = rem & 3;
                *(bf16x8*)(&blds[(r * 34 + c) * 40 + g * 8]) = ireg[k];
            }
        }
#pragma unroll
        for (int k = 0; k < WTRIPS; ++k) {
            int i = tid + k * 256;
            if (i < WN) {
                int t = i >> 6, l16 = i & 63;
                *(bf16x8*)(&wlds[t * 512 + l16 * 8]) = wreg[k];
            }
        }
        __syncthreads();
        if (cb + 1 < nCb) load_regs(cb + 1);
        for (int t = 0; t < 9; ++t) {
            const int dy = t / 3, dx = t - dy * 3;
            const int yy = wr + dy;
            const int xx = wc * 16 + ln + dx;
            bf16x8 bfr = *(const bf16x8*)(&blds[(yy * 34 + xx) * 40 + lq * 8]);
            bf16x8 afr = *(const bf16x8*)(&wlds[t * 512 + lane * 8]);
            acc = __builtin_amdgcn_mfma_f32_16x16x32_bf16(afr, bfr, acc, 0, 0, 0);
        }
    }

    const int co = co0 + lq * 4;
    if (co < d.Cout) {
        float bv[4];
#pragma unroll
        for (int r = 0; r < 4; ++r) bv[r] = d.bias[co + r];
        const int pix = (y0 + wr) * 32 + wc * 16 + ln;
        float v[4];
#pragma unroll
        for (int r = 0; r < 4; ++r) {
            float vv = acc[r] + bv[r];
            if (d.relu) vv = (vv >= 0.f) ? vv : 0.1f * vv;
            v[r] = vv;
        }
        if (d.mode == 0) {
            float* o = (float*)d.out;
#pragma unroll
            for (int r = 0; r < 4; ++r) {
                float vv = v[r];
                if (d.residual) vv += d.residual[(size_t)(co + r) * HW + pix];
                o[(size_t)(co + r) * HW + pix] = vv;
            }
        } else if (d.mode == 1) {
            int fq = co / d.cmod, cc = co - fq * d.cmod;
            *(float4*)((float*)d.out + ((size_t)fq * HW + pix) * d.cmod + cc) =
                make_float4(v[0], v[1], v[2], v[3]);
        } else if (d.mode == 2) {
            int fq = co / d.cmod, cc = co - fq * d.cmod;
            ushort4 s4;
            s4.x = f2bf(v[0]); s4.y = f2bf(v[1]); s4.z = f2bf(v[2]); s4.w = f2bf(v[3]);
            *(ushort4*)((unsigned short*)d.out + ((size_t)fq * HW + pix) * d.cmod + cc) = s4;
        } else {
            int yy = (pix >> 5) + 1, xx = (pix & 31) + 1;
            ushort4 s4;
            s4.x = f2bf(v[0]); s4.y = f2bf(v[1]); s4.z = f2bf(v[2]); s4.w = f2bf(v[3]);
            *(ushort4*)((unsigned short*)d.out + (size_t)(yy * 34 + xx) * d.cmod + co) = s4;
        }
    }
}

// ---------------------------------------------------------------------------
// L4 conv (so3 + aw3). Grid 1188 = 2 y-halves x 594: blockIdx.x&1 picks the
// y-half (strips {0,1} or {2,3}); per-block serial chain halves (4 phases).
// Weights re-read once per half (+10.9 MB, L2-absorbed) — the 594-block
// version was co-residency-limited at 29% occupancy by its serial chain.
// ---------------------------------------------------------------------------
struct L4Desc {
    const unsigned short* in;
    const unsigned short* wgt;
    const float* bias;
    void* out;
    int mode, cmod, Mblocks;   // mode 1 = f32 strided, 2 = bf16 strided
};
struct L4Param { L4Desc d[2]; };

__global__ __launch_bounds__(256) void conv_l4_k(L4Param P) {
    __shared__ unsigned short blds[10 * 34 * 40];   // 27200 B (one cb slice)
    __shared__ unsigned short wlds[9 * 2 * 512];    // 18432 B (both cb slices)

    const int half = blockIdx.x & 1;       // y-half: strips {0,1} or {2,3}
    int bx = blockIdx.x >> 1;              // 0..593
    int di = 0;
    if (bx >= P.d[0].Mblocks) { bx -= P.d[0].Mblocks; di = 1; }
    const L4Desc d = P.d[di];

    const int tid = threadIdx.x;
    const int w = tid >> 6, lane = tid & 63;
    const int lq = lane >> 4, ln = lane & 15;
    const int co0 = bx * 16;
    const unsigned short* __restrict__ in = d.in;
    const unsigned short* __restrict__ wg = d.wgt;

    bf16x8 wreg[5];
#pragma unroll
    for (int k = 0; k < 5; ++k) {
        int i = tid + k * 256;
        if (i < 1152) {
            int chunk = i >> 6, l16 = i & 63;
            int t = chunk >> 1, cb = chunk & 1;
            wreg[k] = *(const bf16x8*)(wg + (((size_t)bx * 9 + t) * 2 + cb) * 512 + l16 * 8);
        }
    }

    bf16x8 ireg[6];
    auto load_in = [&](int y0, int cb) {
        const int ci0 = cb << 5;
#pragma unroll
        for (int k = 0; k < 6; ++k) {
            int i = tid + k * 256;
            if (i < 1360) {
                int r = i / 136, rem = i - r * 136, c = rem >> 2, g = rem & 3;
                ireg[k] = *(const bf16x8*)(in + (size_t)((y0 + r) * 34 + c) * 64 + ci0 + g * 8);
            }
        }
    };
    load_in(half * 16, 0);   // first strip of this half (strip index half*2)

#pragma unroll
    for (int k = 0; k < 5; ++k) {
        int i = tid + k * 256;
        if (i < 1152) *(bf16x8*)(&wlds[(i >> 6) * 512 + (i & 63) * 8]) = wreg[k];
    }

    floatx4 acc[4];
#pragma unroll
    for (int nt = 0; nt < 4; ++nt) acc[nt] = (floatx4){0.f, 0.f, 0.f, 0.f};

    for (int p = 0; p < 4; ++p) {
        const int y = half * 2 + (p >> 1), cb = p & 1;   // global strip index
        __syncthreads();
#pragma unroll
        for (int k = 0; k < 6; ++k) {
            int i = tid + k * 256;
            if (i < 1360) {
                int r = i / 136, rem = i - r * 136, c = rem >> 2, g = rem & 3;
                *(bf16x8*)(&blds[(r * 34 + c) * 40 + g * 8]) = ireg[k];
            }
        }
        __syncthreads();
        if (p < 3) { int pn = p + 1; load_in((half * 2 + (pn >> 1)) * 8, pn & 1); }
#pragma unroll
        for (int t = 0; t < 9; ++t) {
            const int dy = t / 3, dx = t - dy * 3;
            bf16x8 afr = *(const bf16x8*)(&wlds[(t * 2 + cb) * 512 + lane * 8]);
#pragma unroll
            for (int ty = 0; ty < 2; ++ty)
#pragma unroll
                for (int tx = 0; tx < 2; ++tx) {
                    int yy = w * 2 + ty + dy;
                    int xx = tx * 16 + ln + dx;
                    bf16x8 bfr = *(const bf16x8*)(&blds[(yy * 34 + xx) * 40 + lq * 8]);
                    acc[ty * 2 + tx] =
                        __builtin_amdgcn_mfma_f32_16x16x32_bf16(afr, bfr, acc[ty * 2 + tx], 0, 0, 0);
                }
        }
        if (cb == 1) {
            const int co = co0 + lq * 4;
            float bv[4];
#pragma unroll
            for (int r2 = 0; r2 < 4; ++r2) bv[r2] = d.bias[co + r2];
            int fq = co / d.cmod, cc = co - fq * d.cmod;
#pragma unroll
            for (int nt = 0; nt < 4; ++nt) {
                const int ty = nt >> 1, tx = nt & 1;
                const int pix = y * 256 + (w * 2 + ty) * 32 + tx * 16 + ln;
                float v0 = acc[nt][0] + bv[0], v1 = acc[nt][1] + bv[1];
                float v2 = acc[nt][2] + bv[2], v3 = acc[nt][3] + bv[3];
                if (d.mode == 1) {
                    *(float4*)((float*)d.out + ((size_t)fq * HW + pix) * d.cmod + cc) =
                        make_float4(v0, v1, v2, v3);
                } else {
                    ushort4 s4;
                    s4.x = f2bf(v0); s4.y = f2bf(v1); s4.z = f2bf(v2); s4.w = f2bf(v3);
                    *(ushort4*)((unsigned short*)d.out + ((size_t)fq * HW + pix) * d.cmod + cc) = s4;
                }
                acc[nt] = (floatx4){0.f, 0.f, 0.f, 0.f};
            }
        }
    }
}

// ---------------------------------------------------------------------------
// Deformable attention, no-LDS-value variant. Grid 3072 (8 queries/block,
// r<2): grid-limit lens again — 1536 was exactly 6 blocks/CU; VGPR ~66
// allows 7. No per-block fixed cost, so the split is free.
// DPP reductions; lane 63 stores. value_b layout [l][m][pix][8ch]: level
// stride 65536 shorts, head m*8192.
// ---------------------------------------------------------------------------
__global__ __launch_bounds__(256) void deform_attn_k(
    const unsigned short* __restrict__ value_b, const float* __restrict__ so_t,
    const unsigned short* __restrict__ aw_t,
    const float* __restrict__ flow_1, const float* __restrict__ flow_2,
    const float* __restrict__ flip_flow_1, const float* __restrict__ flip_flow_2,
    const float* __restrict__ flow_cn2, const float* __restrict__ flow_n2c,
    unsigned short* __restrict__ attn_pad)
{
    __shared__ unsigned short pwlds[4][432];
    const int tid = threadIdx.x;
    const int wav = tid >> 6, lane = tid & 63;
    const int m = blockIdx.x & 7, qc = blockIdx.x >> 3;   // qc in [0,384)

    const int pp = lane & 15, gq = lane >> 4;
    const int gdy = (gq >> 1) * 2 - 1;
    const int gdx = (gq & 1) * 2 - 1;
    const bool selx = (gq & 1);
    const bool sely = (gq >> 1);

    const unsigned short* __restrict__ vm = value_b + (size_t)m * 8192;

    for (int r = 0; r < 2; ++r) {
        const int q = qc * 8 + r * 4 + wav;
        const int f = q >> 10, pix = q & 1023;
        const int y = pix >> 5, x = pix & 31;

        float av[6];
        {
            const unsigned short* awp = aw_t + (size_t)q * 2592 + m * 324;
#pragma unroll
            for (int it = 0; it < 6; ++it) {
                int j = lane + it * 64;
                av[it] = (j < 324) ? bf2f(awp[j]) : -1e30f;
            }
        }

        float vmax = -1e30f;
#pragma unroll
        for (int it = 0; it < 6; ++it) vmax = fmaxf(vmax, av[it]);
        vmax = bcast_lane63(wave_max64(vmax));
        float ssum = 0.f;
#pragma unroll
        for (int it = 0; it < 6; ++it) {
            int j = lane + it * 64;
            float e = (j < 324) ? __expf(av[it] - vmax) : 0.f;
            av[it] = e;
            ssum += e;
        }
        ssum = bcast_lane63(wave_sum64(ssum));
        const float inv = 1.f / ssum;

#pragma unroll
        for (int it = 0; it < 6; ++it) {
            int j = lane + it * 64;
            if (j < 324) {
                int pi = j / 9, k = j - pi * 9;
                pwlds[wav][pi * 12 + k] = f2bf(av[it] * inv);
            }
        }

        const float* sop = so_t + (size_t)q * 576 + m * 72;

        float flx0 = 0.f, fly0 = 0.f, flx1 = 0.f, fly1 = 0.f, flx2 = 0.f, fly2 = 0.f;
        if (f == 0) {
            flx1 = flow_1[pix];      fly1 = flow_1[HW + pix];
            flx2 = flow_cn2[pix];    fly2 = flow_cn2[HW + pix];
        } else if (f == 1) {
            flx0 = flip_flow_1[pix]; fly0 = flip_flow_1[HW + pix];
            flx2 = flow_2[pix];      fly2 = flow_2[HW + pix];
        } else {
            flx0 = flow_n2c[pix];    fly0 = flow_n2c[HW + pix];
            flx1 = flip_flow_2[pix]; fly1 = flip_flow_2[HW + pix];
        }

        float acc[8];
#pragma unroll
        for (int dd = 0; dd < 8; ++dd) acc[dd] = 0.f;

#pragma unroll
        for (int pt = 0; pt < 3; ++pt) {
            int pi = pt * 16 + pp;
            if (pi < 36) {
                int l = pi / 12;
                float2 so2 = *(const float2*)(sop + pi * 2);
                float fx = (l == 0) ? flx0 : (l == 1) ? flx1 : flx2;
                float fy = (l == 0) ? fly0 : (l == 1) ? fly1 : fly2;
                float bxf = (float)x + so2.x + fx;
                float byf = (float)y + so2.y + fy;
                float x0f = floorf(bxf), y0f = floorf(byf);
                float wx = bxf - x0f, wy = byf - y0f;
                float ax = 1.f - wx, ay = 1.f - wy;
                int x0 = (int)fminf(fmaxf(x0f, -2.f), 34.f);
                int y0 = (int)fminf(fmaxf(y0f, -2.f), 34.f);

                const unsigned short* pr = &pwlds[wav][pi * 12];
                uint2 pv0 = *(const uint2*)(pr);
                uint2 pv1 = *(const uint2*)(pr + 4);
                float a0 = bflo(pv0.x), a1 = bfhi(pv0.x), a2 = bflo(pv0.y);
                float a3 = bfhi(pv0.y), a4 = bflo(pv1.x), a5 = bfhi(pv1.x);
                float a6 = bflo(pv1.y), a7 = bfhi(pv1.y), a8 = bf2f(pr[8]);

                float bs0a, bs0b, bs1a, bs1b, bs2a, bs2b;
                {
                    float b0, b1, b2, b3;
                    b0 = a0 * ax; b1 = a0 * wx + a3 * ax; b2 = a3 * wx + a6 * ax; b3 = a6 * wx;
                    bs0a = selx ? b2 : b0; bs0b = selx ? b3 : b1;
                    b0 = a1 * ax; b1 = a1 * wx + a4 * ax; b2 = a4 * wx + a7 * ax; b3 = a7 * wx;
                    bs1a = selx ? b2 : b0; bs1b = selx ? b3 : b1;
                    b0 = a2 * ax; b1 = a2 * wx + a5 * ax; b2 = a5 * wx + a8 * ax; b3 = a8 * wx;
                    bs2a = selx ? b2 : b0; bs2b = selx ? b3 : b1;
                }
                float c00, c01, c10, c11;
                {
                    float c0 = bs0a * ay, c1 = bs0a * wy + bs1a * ay;
                    float c2 = bs1a * wy + bs2a * ay, c3 = bs2a * wy;
                    c00 = sely ? c2 : c0; c10 = sely ? c3 : c1;
                    c0 = bs0b * ay; c1 = bs0b * wy + bs1b * ay;
                    c2 = bs1b * wy + bs2b * ay; c3 = bs2b * wy;
                    c01 = sely ? c2 : c0; c11 = sely ? c3 : c1;
                }
                float cg[2][2] = {{c00, c01}, {c10, c11}};
                const unsigned short* __restrict__ vl = vm + (size_t)l * 65536;
#pragma unroll
                for (int sy = 0; sy < 2; ++sy) {
#pragma unroll
                    for (int sx = 0; sx < 2; ++sx) {
                        int dy = gdy + sy, dx = gdx + sx;
                        float pyf = y0f + (float)dy, pxf = x0f + (float)dx;
                        bool v = (pxf >= 0.f) && (pxf <= 31.f) && (pyf >= 0.f) && (pyf <= 31.f);
                        int px = min(max(x0 + dx, 0), 31);
                        int py = min(max(y0 + dy, 0), 31);
                        float c = cg[sy][sx] * (v ? 1.f : 0.f);
                        uint4 vv = *(const uint4*)(vl + (size_t)(py * 32 + px) * 8);
                        acc[0] = fmaf(c, bflo(vv.x), acc[0]);
                        acc[1] = fmaf(c, bfhi(vv.x), acc[1]);
                        acc[2] = fmaf(c, bflo(vv.y), acc[2]);
                        acc[3] = fmaf(c, bfhi(vv.y), acc[3]);
                        acc[4] = fmaf(c, bflo(vv.z), acc[4]);
                        acc[5] = fmaf(c, bfhi(vv.z), acc[5]);
                        acc[6] = fmaf(c, bflo(vv.w), acc[6]);
                        acc[7] = fmaf(c, bfhi(vv.w), acc[7]);
                    }
                }
            }
        }

#pragma unroll
        for (int dd = 0; dd < 8; ++dd) acc[dd] = wave_sum64(acc[dd]);
        if (lane == 63) {
            unsigned short* op = attn_pad + (size_t)((y + 1) * 34 + x + 1) * 192 + f * 64 + m * 8;
            ushort4 s0, s1;
            s0.x = f2bf(acc[0]); s0.y = f2bf(acc[1]); s0.z = f2bf(acc[2]); s0.w = f2bf(acc[3]);
            s1.x = f2bf(acc[4]); s1.y = f2bf(acc[5]); s1.z = f2bf(acc[6]); s1.w = f2bf(acc[7]);
            *(ushort4*)(op) = s0;
            *(ushort4*)(op + 4) = s1;
        }
    }
}

// ---------------------------------------------------------------------------
extern "C" void kernel_launch(void* const* d_in, const int* in_sizes, int n_in,
                              void* d_out, int out_size, void* d_ws, size_t ws_size,
                              hipStream_t stream) {
    const float* x      = (const float*)d_in[0];
    const float* flow_1 = (const float*)d_in[1];
    const float* flow_2 = (const float*)d_in[2];
    const float* flip_1 = (const float*)d_in[3];
    const float* flip_2 = (const float*)d_in[4];
    const float* vp0_w = (const float*)d_in[5];  const float* vp0_b = (const float*)d_in[6];
    const float* vp1_w = (const float*)d_in[7];  const float* vp1_b = (const float*)d_in[8];
    const float* so0_w = (const float*)d_in[9];  const float* so0_b = (const float*)d_in[10];
    const float* so1_w = (const float*)d_in[11]; const float* so1_b = (const float*)d_in[12];
    const float* so2_w = (const float*)d_in[13]; const float* so2_b = (const float*)d_in[14];
    const float* so3_w = (const float*)d_in[15]; const float* so3_b = (const float*)d_in[16];
    const float* aw0_w = (const float*)d_in[17]; const float* aw0_b = (const float*)d_in[18];
    const float* aw1_w = (const float*)d_in[19]; const float* aw1_b = (const float*)d_in[20];
    const float* aw2_w = (const float*)d_in[21]; const float* aw2_b = (const float*)d_in[22];
    const float* aw3_w = (const float*)d_in[23]; const float* aw3_b = (const float*)d_in[24];
    const float* op0_w = (const float*)d_in[25]; const float* op0_b = (const float*)d_in[26];
    const float* op1_w = (const float*)d_in[27]; const float* op1_b = (const float*)d_in[28];
    float* out = (float*)d_out;
    (void)ws_size; (void)in_sizes; (void)n_in; (void)out_size;

    // ---- workspace layout ----
    float* fws = (float*)d_ws;
    float* flow_cn2 = fws;
    float* flow_n2c = flow_cn2 + 2048;
    unsigned short* value_b = (unsigned short*)(flow_n2c + 2048);
    float* so_t     = (float*)(value_b + 196608);
    unsigned short* uws = (unsigned short*)(so_t + 1769472);
    unsigned short* x_pad     = uws;
    unsigned short* vp0h      = x_pad + 1156 * 192;
    unsigned short* extra_pad = vp0h + 1156 * 192;
    unsigned short* s1 = extra_pad + 1156 * 480;
    unsigned short* a1 = s1 + 1156 * 64;
    unsigned short* s2 = a1 + 1156 * 64;
    unsigned short* a2 = s2 + 1156 * 64;
    unsigned short* attn_pad = a2 + 1156 * 64;
    unsigned short* op0h     = attn_pad + 1156 * 192;
    unsigned short* aw_t = op0h + 1156 * 192;
    unsigned short* wgt  = aw_t + (size_t)3072 * 2592;

    // ---- 1. prep ----
    PrepP pp;
    pp.x = x; pp.f1 = flow_1; pp.f2 = flow_2; pp.ff1 = flip_1; pp.ff2 = flip_2;
    pp.fcn2 = flow_cn2; pp.fn2c = flow_n2c;
    pp.x_pad = x_pad; pp.extra_pad = extra_pad; pp.wgt = wgt;
    pp.wd[0]  = {vp0_w, 192, 192, 6,     0,    0};
    pp.wd[1]  = {vp1_w, 192, 192, 6,   648,   72};
    pp.wd[2]  = {so0_w,  64, 460, 15, 1296,  144};
    pp.wd[3]  = {aw0_w,  64, 460, 15, 1836,  204};
    pp.wd[4]  = {so1_w,  64,  64, 2,  2376,  264};
    pp.wd[5]  = {aw1_w,  64,  64, 2,  2448,  272};
    pp.wd[6]  = {so2_w,  64,  64, 2,  2520,  280};
    pp.wd[7]  = {aw2_w,  64,  64, 2,  2592,  288};
    pp.wd[8]  = {so3_w, 1728, 64, 2,  2664,  296};
    pp.wd[9]  = {aw3_w, 7776, 64, 2,  4608,  512};
    pp.wd[10] = {op0_w, 192, 192, 6, 13392, 1488};
    pp.wd[11] = {op1_w, 192, 192, 6, 14040, 1560};
    prep_k<<<2336, 256, 0, stream>>>(pp);

    const int BIG = 1 << 30;
    CDesc nul = {nullptr, nullptr, nullptr, nullptr, nullptr, 0, 0, 0, 0, 0, 0, BIG};

    // ---- 2. L1: vp0 + so0 + aw0 (2-row blocks, grid (20,16)) ----
    {
        CParam cp;
        cp.d[0] = {x_pad,     wgt + (size_t)0 * 512,    vp0_b, vp0h, nullptr, 192, 6,  192, 3, 192, 1, 12};
        cp.d[1] = {extra_pad, wgt + (size_t)1296 * 512, so0_b, s1,   nullptr, 480, 15, 64,  3, 64,  1, 4};
        cp.d[2] = {extra_pad, wgt + (size_t)1836 * 512, aw0_b, a1,   nullptr, 480, 15, 64,  3, 64,  1, 4};
        cp.d[3] = nul;
        conv2_k<<<dim3(20, 16), 256, 0, stream>>>(cp);
    }
    // ---- 3. L2: vp1 + so1 + aw1 ----
    {
        CParam cp;
        cp.d[0] = {vp0h, wgt + (size_t)648 * 512,  vp1_b, value_b, nullptr, 192, 6, 192, 2, 8,  0, 12};
        cp.d[1] = {s1,   wgt + (size_t)2376 * 512, so1_b, s2,      nullptr, 64,  2, 64,  3, 64, 1, 4};
        cp.d[2] = {a1,   wgt + (size_t)2448 * 512, aw1_b, a2,      nullptr, 64,  2, 64,  3, 64, 1, 4};
        cp.d[3] = nul;
        conv2_k<<<dim3(20, 16), 256, 0, stream>>>(cp);
    }
    // ---- 4. L3: so2 + aw2 ----
    {
        CParam cp;
        cp.d[0] = {s2, wgt + (size_t)2520 * 512, so2_b, s1, nullptr, 64, 2, 64, 3, 64, 1, 4};
        cp.d[1] = {a2, wgt + (size_t)2592 * 512, aw2_b, a1, nullptr, 64, 2, 64, 3, 64, 1, 4};
        cp.d[2] = nul; cp.d[3] = nul;
        conv2_k<<<dim3(8, 16), 256, 0, stream>>>(cp);
    }
    // ---- 5. L4: so3 + aw3 (read-once weights, y-half split, grid 1188) ----
    {
        L4Param lp;
        lp.d[0] = {s1, wgt + (size_t)2664 * 512, so3_b, so_t, 1, 576,  108};
        lp.d[1] = {a1, wgt + (size_t)4608 * 512, aw3_b, aw_t, 2, 2592, 486};
        conv_l4_k<<<1188, 256, 0, stream>>>(lp);
    }

    // ---- 6. deformable attention (no-LDS-value, L2-gather, grid 3072) ----
    deform_attn_k<<<3072, 256, 0, stream>>>(value_b, so_t, aw_t,
                                            flow_1, flow_2, flip_1, flip_2,
                                            flow_cn2, flow_n2c, attn_pad);

    // ---- 7. op0 ----
    {
        CParam cp;
        cp.d[0] = {attn_pad, wgt + (size_t)13392 * 512, op0_b, op0h, nullptr, 192, 6, 192, 3, 192, 1, 12};
        cp.d[1] = nul; cp.d[2] = nul; cp.d[3] = nul;
        conv2_k<<<dim3(12, 16), 256, 0, stream>>>(cp);
    }
    // ---- 8. op1 + residual ----
    {
        CParam cp;
        cp.d[0] = {op0h, wgt + (size_t)14040 * 512, op1_b, out, x, 192, 6, 192, 0, 0, 0, 12};
        cp.d[1] = nul; cp.d[2] = nul; cp.d[3] = nul;
        conv2_k<<<dim3(12, 16), 256, 0, stream>>>(cp);
    }
}